// Round 2
// baseline (1391.874 us; speedup 1.0000x reference)
//
#include <hip/hip_runtime.h>

namespace {

constexpr int NP   = 19712;   // padded tokens (Nystrom)
constexpr int NT   = 19601;   // tokens incl cls
constexpr int NPIX = 19600;   // feature tokens (140x140)
constexpr int HD   = 512;     // hidden dim
constexpr int ID   = 1024;    // input dim
constexpr int NH   = 8;       // heads
constexpr int DH   = 8;       // dim per head
constexpr int NL   = 256;     // landmarks
constexpr int PADR = 111;     // left zero-pad rows
constexpr int SIDE = 140;
constexpr int CCH  = 128;     // ppeg channel chunk
constexpr int PW   = 148;     // padded image row stride (floats)
constexpr int CKT  = NP / 4;  // attn3v token chunk = 4928

typedef __attribute__((ext_vector_type(8))) short bf16x8;
typedef __attribute__((ext_vector_type(4))) float f32x4;

#define F4MAD(a, s, v) { (a).x += (s)*(v).x; (a).y += (s)*(v).y; (a).z += (s)*(v).z; (a).w += (s)*(v).w; }

// async global->LDS, 16B per lane; LDS dest must be wave-uniform base + lane*16
#define GLOAD16(gptr, lptr) \
    __builtin_amdgcn_global_load_lds((const __attribute__((address_space(1))) void*)(gptr), \
                                     (__attribute__((address_space(3))) void*)(lptr), 16, 0, 0)

__device__ inline short f2bf(float f) {
    union { float f; unsigned u; } v; v.f = f;
    unsigned r = v.u + 0x7fffu + ((v.u >> 16) & 1u);
    return (short)(r >> 16);
}

// ------------------------------------------------------------------
// cast X fp32 -> bf16 elementwise
// ------------------------------------------------------------------
__global__ void castX(const float* __restrict__ src, short* __restrict__ dst)
{
    size_t c = (size_t)blockIdx.x * 256 + threadIdx.x;
    const float4 x0 = *(const float4*)&src[c * 8];
    const float4 x1 = *(const float4*)&src[c * 8 + 4];
    bf16x8 p;
    p[0] = f2bf(x0.x); p[1] = f2bf(x0.y); p[2] = f2bf(x0.z); p[3] = f2bf(x0.w);
    p[4] = f2bf(x1.x); p[5] = f2bf(x1.y); p[6] = f2bf(x1.z); p[7] = f2bf(x1.w);
    *(bf16x8*)&dst[c * 8] = p;
}

// ------------------------------------------------------------------
// cast+transpose: dst[c][r] = bf16(src[r][c]); grid (C/32, R/32)
// ------------------------------------------------------------------
__global__ void castT(const float* __restrict__ src, short* __restrict__ dst, int R, int C)
{
    __shared__ float t[32][33];
    const int tx = threadIdx.x & 31, ty = threadIdx.x >> 5;
    const int c0 = blockIdx.x * 32, r0 = blockIdx.y * 32;
    #pragma unroll
    for (int j = 0; j < 4; ++j)
        t[ty + 8 * j][tx] = src[(size_t)(r0 + ty + 8 * j) * C + c0 + tx];
    __syncthreads();
    #pragma unroll
    for (int j = 0; j < 4; ++j)
        dst[(size_t)(c0 + ty + 8 * j) * R + r0 + tx] = f2bf(t[tx][ty + 8 * j]);
}

// ------------------------------------------------------------------
// fc1 MFMA: out[1+m][n] = gelu(Xb[m] @ W[:,n] + b[n])
// 128x128 tile, BK=32, 2-phase double-buffered global_load_lds (T3 min
// recipe): stage tile t+1 before computing tile t; one barrier per step.
// LDS chunk swizzle g = p ^ ((row>>2)&3): frag reads 2 lanes/bank (free).
// grid (4 colblocks, 154 rowblocks) -> col-adjacent dispatch shares X panel.
// ------------------------------------------------------------------
__global__ __launch_bounds__(256) void gemm_fc1(const short* __restrict__ Xb,
                                                const short* __restrict__ Wt,
                                                const float* __restrict__ bias,
                                                float* __restrict__ out)
{
    __shared__ __align__(16) short As[2][128 * 32];
    __shared__ __align__(16) short Bs[2][128 * 32];
    const int tid  = threadIdx.x;
    const int col0 = blockIdx.x * 128;
    const int row0 = blockIdx.y * 128;
    const int wave = tid >> 6, lane = tid & 63;
    const int quad = lane >> 4, l16 = lane & 15;
    const int m_base = (wave >> 1) * 64, n_base = (wave & 1) * 64;
    const int kch = (quad ^ ((l16 >> 2) & 3)) * 8;   // swizzled k-chunk (shorts)
    f32x4 acc[4][4] = {};

    // staging map: 512 slots (128 rows x 4 chunks), 2 per thread.
    // LDS dest linear; global source chunk g = p ^ ((row>>2)&3).
    int    aldo[2];
    size_t agoff[2], bgoff[2];
    #pragma unroll
    for (int i = 0; i < 2; ++i) {
        int slot = i * 256 + wave * 64 + lane;
        int row  = slot >> 2;
        int g    = (slot & 3) ^ ((slot >> 4) & 3);
        aldo[i]  = slot * 8;
        agoff[i] = (size_t)(row0 + row) * ID + g * 8;
        bgoff[i] = (size_t)(col0 + row) * ID + g * 8;
    }
    auto stage = [&](int b, int k0) {
        #pragma unroll
        for (int i = 0; i < 2; ++i) {
            GLOAD16(&Xb[agoff[i] + k0], &As[b][aldo[i]]);
            GLOAD16(&Wt[bgoff[i] + k0], &Bs[b][aldo[i]]);
        }
    };

    stage(0, 0);
    __syncthreads();
    #pragma unroll 1
    for (int t = 0; t < 32; ++t) {
        const int cur = t & 1;
        if (t < 31) stage(cur ^ 1, (t + 1) * 32);
        bf16x8 af[4], bfr[4];
        #pragma unroll
        for (int i = 0; i < 4; ++i) {
            af[i]  = *(const bf16x8*)&As[cur][(m_base + i * 16 + l16) * 32 + kch];
            bfr[i] = *(const bf16x8*)&Bs[cur][(n_base + i * 16 + l16) * 32 + kch];
        }
        #pragma unroll
        for (int mi = 0; mi < 4; ++mi)
            #pragma unroll
            for (int ni = 0; ni < 4; ++ni)
                acc[mi][ni] = __builtin_amdgcn_mfma_f32_16x16x32_bf16(af[mi], bfr[ni], acc[mi][ni], 0, 0, 0);
        __syncthreads();
    }
    #pragma unroll
    for (int mi = 0; mi < 4; ++mi) {
        #pragma unroll
        for (int r = 0; r < 4; ++r) {
            int gr = row0 + m_base + mi * 16 + quad * 4 + r;
            if (gr >= NPIX) continue;
            #pragma unroll
            for (int ni = 0; ni < 4; ++ni) {
                int gc = col0 + n_base + ni * 16 + l16;
                float v = acc[mi][ni][r] + bias[gc];
                v = 0.5f * v * (1.f + erff(v * 0.70710678118654752f));
                out[(size_t)(gr + 1) * HD + gc] = v;
            }
        }
    }
}

// ------------------------------------------------------------------
// qkv MFMA: 128x64 tile, BK=32, same 2-phase dbuf structure.
// grid (3 colblocks, 154 rowblocks)
// ------------------------------------------------------------------
__global__ __launch_bounds__(256) void gemm_qkv(const short* __restrict__ xpB,
                                                const short* __restrict__ Wt,
                                                float* __restrict__ qh,
                                                float* __restrict__ kh,
                                                float* __restrict__ vh)
{
    __shared__ __align__(16) short As[2][128 * 32];
    __shared__ __align__(16) short Bs[2][64 * 32];
    const int tid  = threadIdx.x;
    const int col0 = blockIdx.x * 64;
    const int row0 = blockIdx.y * 128;
    const int wave = tid >> 6, lane = tid & 63;
    const int quad = lane >> 4, l16 = lane & 15;
    const int m_base = (wave >> 1) * 64, n_base = (wave & 1) * 32;
    const int kch = (quad ^ ((l16 >> 2) & 3)) * 8;
    f32x4 acc[4][2] = {};

    int    aldo[2];
    size_t agoff[2];
    #pragma unroll
    for (int i = 0; i < 2; ++i) {
        int slot = i * 256 + wave * 64 + lane;
        int row  = slot >> 2;
        int g    = (slot & 3) ^ ((slot >> 4) & 3);
        aldo[i]  = slot * 8;
        agoff[i] = (size_t)(row0 + row) * HD + g * 8;
    }
    int bldo; size_t bgoff;
    {
        int slot = wave * 64 + lane;
        int row  = slot >> 2;
        int g    = (slot & 3) ^ ((slot >> 4) & 3);
        bldo  = slot * 8;
        bgoff = (size_t)(col0 + row) * HD + g * 8;
    }
    auto stage = [&](int b, int k0) {
        #pragma unroll
        for (int i = 0; i < 2; ++i)
            GLOAD16(&xpB[agoff[i] + k0], &As[b][aldo[i]]);
        GLOAD16(&Wt[bgoff + k0], &Bs[b][bldo]);
    };

    stage(0, 0);
    __syncthreads();
    #pragma unroll 1
    for (int t = 0; t < 16; ++t) {
        const int cur = t & 1;
        if (t < 15) stage(cur ^ 1, (t + 1) * 32);
        bf16x8 af[4], bfr[2];
        #pragma unroll
        for (int i = 0; i < 4; ++i)
            af[i] = *(const bf16x8*)&As[cur][(m_base + i * 16 + l16) * 32 + kch];
        #pragma unroll
        for (int i = 0; i < 2; ++i)
            bfr[i] = *(const bf16x8*)&Bs[cur][(n_base + i * 16 + l16) * 32 + kch];
        #pragma unroll
        for (int mi = 0; mi < 4; ++mi)
            #pragma unroll
            for (int ni = 0; ni < 2; ++ni)
                acc[mi][ni] = __builtin_amdgcn_mfma_f32_16x16x32_bf16(af[mi], bfr[ni], acc[mi][ni], 0, 0, 0);
        __syncthreads();
    }
    const int which = blockIdx.x;
    float* dst = (which == 0) ? qh : (which == 1) ? kh : vh;
    const float scale = (which == 0) ? 0.35355339059327373f : 1.f;
    #pragma unroll
    for (int mi = 0; mi < 4; ++mi) {
        #pragma unroll
        for (int r = 0; r < 4; ++r) {
            int gr = row0 + m_base + mi * 16 + quad * 4 + r;
            #pragma unroll
            for (int ni = 0; ni < 2; ++ni) {
                int n = n_base + ni * 16 + l16;
                int hh = n >> 3, d = n & 7;
                dst[((size_t)hh * NP + gr) * DH + d] = acc[mi][ni][r] * scale;
            }
        }
    }
}

__global__ void cls_init(const float* __restrict__ cls, float* __restrict__ h)
{
    int t = blockIdx.x * 256 + threadIdx.x;
    if (t < HD) h[t] = cls[t];
}

__global__ void copy512(const float* __restrict__ src, float* __restrict__ dst)
{
    dst[threadIdx.x] = src[threadIdx.x];
}

// ------------------------------------------------------------------
// layernorm rows of h into xp (bf16), first 111 rows zero
// ------------------------------------------------------------------
__global__ void ln_pad(const float* __restrict__ h, const float* __restrict__ g,
                       const float* __restrict__ b, short* __restrict__ xp)
{
    const int row = blockIdx.x;
    const int tid = threadIdx.x;
    short* dst = xp + (size_t)row * HD;
    if (row < PADR) { dst[tid] = 0; dst[tid + 256] = 0; return; }
    const float* src = h + (size_t)(row - PADR) * HD;
    float v0 = src[tid], v1 = src[tid + 256];
    __shared__ float red[256];
    red[tid] = v0 + v1;
    __syncthreads();
    for (int off = 128; off > 0; off >>= 1) {
        if (tid < off) red[tid] += red[tid + off];
        __syncthreads();
    }
    float mu = red[0] * (1.f / HD);
    __syncthreads();
    float d0 = v0 - mu, d1 = v1 - mu;
    red[tid] = d0 * d0 + d1 * d1;
    __syncthreads();
    for (int off = 128; off > 0; off >>= 1) {
        if (tid < off) red[tid] += red[tid + off];
        __syncthreads();
    }
    float inv = rsqrtf(red[0] * (1.f / HD) + 1e-5f);
    dst[tid]       = f2bf(d0 * inv * g[tid] + b[tid]);
    dst[tid + 256] = f2bf(d1 * inv * g[tid + 256] + b[tid + 256]);
}

// ------------------------------------------------------------------
// landmark means
// ------------------------------------------------------------------
__global__ void landmarks(const float* __restrict__ qh, const float* __restrict__ kh,
                          float* __restrict__ ql, float* __restrict__ kl)
{
    int idx = blockIdx.x * 256 + threadIdx.x;
    int sel = idx >> 14;
    int rem = idx & 16383;
    int h = rem >> 11;
    int i = (rem >> 3) & 255;
    int d = rem & 7;
    const float* src = sel ? kh : qh;
    size_t base = ((size_t)h * NP + (size_t)i * 77) * DH + d;
    float s = 0.f;
    for (int j = 0; j < 77; ++j) s += src[base + (size_t)j * DH];
    (sel ? kl : ql)[((size_t)h * NL + i) * DH + d] = s * (1.f / 77.f);
}

// ------------------------------------------------------------------
// attn2 = softmax(q_l @ k_l^T); scores are O(1) -> no max subtraction
// ------------------------------------------------------------------
__global__ void attn2_softmax(const float* __restrict__ ql, const float* __restrict__ kl,
                              float* __restrict__ a)
{
    const int i = blockIdx.x, h = blockIdx.y, j = threadIdx.x;
    __shared__ float sq[8];
    __shared__ float red[256];
    if (j < 8) sq[j] = ql[((size_t)h * NL + i) * DH + j];
    __syncthreads();
    const float* kr = kl + ((size_t)h * NL + j) * DH;
    float s = 0.f;
    #pragma unroll
    for (int d = 0; d < 8; ++d) s += sq[d] * kr[d];
    float e = __expf(s);
    red[j] = e;
    __syncthreads();
    for (int off = 128; off > 0; off >>= 1) {
        if (j < off) red[j] += red[j + off];
        __syncthreads();
    }
    a[((size_t)h * NL + i) * NL + j] = e / red[0];
}

// ------------------------------------------------------------------
// pinv init
// ------------------------------------------------------------------
__global__ void pinv_norms(const float* __restrict__ a, float* __restrict__ part)
{
    const int h = blockIdx.x & 7;
    const int mode = blockIdx.x >> 3;
    const int tid = threadIdx.x;
    const float* ah = a + (size_t)h * NL * NL;
    float s = 0.f;
    if (mode == 0) { for (int j = 0; j < NL; ++j) s += fabsf(ah[tid * NL + j]); }
    else           { for (int i = 0; i < NL; ++i) s += fabsf(ah[i * NL + tid]); }
    __shared__ float red[256];
    red[tid] = s;
    __syncthreads();
    for (int off = 128; off > 0; off >>= 1) {
        if (tid < off) red[tid] = fmaxf(red[tid], red[tid + off]);
        __syncthreads();
    }
    if (tid == 0) part[mode * 8 + h] = red[0];
}

__global__ void z0_init(const float* __restrict__ a, const float* __restrict__ part,
                        float* __restrict__ z)
{
    float s1 = part[0], s2 = part[8];
    #pragma unroll
    for (int h = 1; h < 8; ++h) { s1 = fmaxf(s1, part[h]); s2 = fmaxf(s2, part[8 + h]); }
    float inv = 1.f / (s1 * s2);
    int idx = blockIdx.x * 256 + threadIdx.x;
    int h = idx >> 16;
    int rem = idx & 65535;
    int i = rem >> 8, j = rem & 255;
    z[idx] = a[((size_t)h * NL + j) * NL + i] * inv;
}

// ------------------------------------------------------------------
// batched 256x256x256: D = A@B   grid (8,4,8)
// ------------------------------------------------------------------
__global__ void mm256(const float* __restrict__ A, const float* __restrict__ B,
                      float* __restrict__ D)
{
    const int h = blockIdx.z;
    const float* Ah = A + (size_t)h * NL * NL;
    const float* Bh = B + (size_t)h * NL * NL;
    float* Dh = D + (size_t)h * NL * NL;
    __shared__ __align__(16) float As[16][36];
    __shared__ __align__(16) float Bs[16][68];
    const int tid = threadIdx.x;
    const int tx = tid & 15, ty = tid >> 4;
    const int row0 = blockIdx.x * 32;
    const int col0 = blockIdx.y * 64;
    float acc[2][4] = {};
    const int ar = tid >> 3;
    const int ak = (tid & 7) * 2;
    const int bk = tid >> 4;
    const int bj = (tid & 15) * 4;
    for (int k0 = 0; k0 < NL; k0 += 16) {
        float2 av = *(const float2*)&Ah[(size_t)(row0 + ar) * NL + k0 + ak];
        As[ak][ar] = av.x; As[ak + 1][ar] = av.y;
        *(float4*)&Bs[bk][bj] = *(const float4*)&Bh[(size_t)(k0 + bk) * NL + col0 + bj];
        __syncthreads();
        #pragma unroll
        for (int k = 0; k < 16; ++k) {
            float2 a = *(const float2*)&As[k][ty * 2];
            float4 b = *(const float4*)&Bs[k][tx * 4];
            acc[0][0] += a.x * b.x; acc[0][1] += a.x * b.y; acc[0][2] += a.x * b.z; acc[0][3] += a.x * b.w;
            acc[1][0] += a.y * b.x; acc[1][1] += a.y * b.y; acc[1][2] += a.y * b.z; acc[1][3] += a.y * b.w;
        }
        __syncthreads();
    }
    #pragma unroll
    for (int r = 0; r < 2; ++r) {
        int gr = row0 + ty * 2 + r;
        #pragma unroll
        for (int c = 0; c < 4; ++c)
            Dh[(size_t)gr * NL + col0 + tx * 4 + c] = acc[r][c];
    }
}

// ------------------------------------------------------------------
// fused T=S@w, U=S@S, w' = 0.25*(13w - 15S + 7T - U)   grid (8,4,8)
// ------------------------------------------------------------------
__global__ void tu_mm(const float* __restrict__ S, const float* __restrict__ w,
                      float* __restrict__ wn)
{
    const int h = blockIdx.z;
    const float* Sh = S + (size_t)h * NL * NL;
    const float* wh = w + (size_t)h * NL * NL;
    float* Dh = wn + (size_t)h * NL * NL;
    __shared__ __align__(16) float As[16][36];
    __shared__ __align__(16) float Bw[16][68];
    __shared__ __align__(16) float Bu[16][68];
    const int tid = threadIdx.x;
    const int tx = tid & 15, ty = tid >> 4;
    const int row0 = blockIdx.x * 32;
    const int col0 = blockIdx.y * 64;
    float aT[2][4] = {}, aU[2][4] = {};
    const int ar = tid >> 3;
    const int ak = (tid & 7) * 2;
    const int bk = tid >> 4;
    const int bj = (tid & 15) * 4;
    for (int k0 = 0; k0 < NL; k0 += 16) {
        float2 av = *(const float2*)&Sh[(size_t)(row0 + ar) * NL + k0 + ak];
        As[ak][ar] = av.x; As[ak + 1][ar] = av.y;
        *(float4*)&Bw[bk][bj] = *(const float4*)&wh[(size_t)(k0 + bk) * NL + col0 + bj];
        *(float4*)&Bu[bk][bj] = *(const float4*)&Sh[(size_t)(k0 + bk) * NL + col0 + bj];
        __syncthreads();
        #pragma unroll
        for (int k = 0; k < 16; ++k) {
            float2 a = *(const float2*)&As[k][ty * 2];
            float4 b1 = *(const float4*)&Bw[k][tx * 4];
            float4 b2 = *(const float4*)&Bu[k][tx * 4];
            aT[0][0] += a.x * b1.x; aT[0][1] += a.x * b1.y; aT[0][2] += a.x * b1.z; aT[0][3] += a.x * b1.w;
            aT[1][0] += a.y * b1.x; aT[1][1] += a.y * b1.y; aT[1][2] += a.y * b1.z; aT[1][3] += a.y * b1.w;
            aU[0][0] += a.x * b2.x; aU[0][1] += a.x * b2.y; aU[0][2] += a.x * b2.z; aU[0][3] += a.x * b2.w;
            aU[1][0] += a.y * b2.x; aU[1][1] += a.y * b2.y; aU[1][2] += a.y * b2.z; aU[1][3] += a.y * b2.w;
        }
        __syncthreads();
    }
    #pragma unroll
    for (int r = 0; r < 2; ++r) {
        int gr = row0 + ty * 2 + r;
        #pragma unroll
        for (int c = 0; c < 4; ++c) {
            int gc = col0 + tx * 4 + c;
            size_t o = (size_t)gr * NL + gc;
            Dh[o] = 0.25f * (13.f * wh[o] - 15.f * Sh[o] + 7.f * aT[r][c] - aU[r][c]);
        }
    }
}

// ------------------------------------------------------------------
// y <- P(w) @ y = 13y - 15*(w@y) + S@(7y - w@y); y:[8][256][8] in-place
// (all P_s commute: polynomials of the same w0 -> apply P0 first)
// grid 8 (heads), 256 threads (thread = row)
// ------------------------------------------------------------------
__global__ void yupd(const float* __restrict__ w, const float* __restrict__ S,
                     float* __restrict__ y)
{
    const int h = blockIdx.x;
    __shared__ float yL[NL * 9];
    __shared__ float uL[NL * 9];
    const int tid = threadIdx.x;
    float* yh = y + (size_t)h * NL * DH;
    #pragma unroll
    for (int i = 0; i < 8; ++i) {
        int idx = tid + 256 * i;
        yL[(idx >> 3) * 9 + (idx & 7)] = yh[idx];
    }
    __syncthreads();
    const float* wr = w + ((size_t)h * NL + tid) * NL;
    float t1[8] = {};
    for (int j = 0; j < NL; j += 4) {
        float4 wv = *(const float4*)&wr[j];
        #pragma unroll
        for (int d = 0; d < 8; ++d)
            t1[d] += wv.x * yL[j * 9 + d] + wv.y * yL[(j + 1) * 9 + d]
                   + wv.z * yL[(j + 2) * 9 + d] + wv.w * yL[(j + 3) * 9 + d];
    }
    #pragma unroll
    for (int d = 0; d < 8; ++d) uL[tid * 9 + d] = 7.f * yL[tid * 9 + d] - t1[d];
    __syncthreads();
    const float* Sr = S + ((size_t)h * NL + tid) * NL;
    float acc[8];
    #pragma unroll
    for (int d = 0; d < 8; ++d) acc[d] = 13.f * yL[tid * 9 + d] - 15.f * t1[d];
    for (int j = 0; j < NL; j += 4) {
        float4 sv = *(const float4*)&Sr[j];
        #pragma unroll
        for (int d = 0; d < 8; ++d)
            acc[d] += sv.x * uL[j * 9 + d] + sv.y * uL[(j + 1) * 9 + d]
                    + sv.z * uL[(j + 2) * 9 + d] + sv.w * uL[(j + 3) * 9 + d];
    }
    #pragma unroll
    for (int d = 0; d < 8; ++d) yh[tid * DH + d] = acc[d];
}

// ------------------------------------------------------------------
// vout[h] = scale * M[h] @ vin[h];  M: [8][256][256], v: [8][256][8]
// ------------------------------------------------------------------
__global__ void polyv(const float* __restrict__ M, const float* __restrict__ vin,
                      float* __restrict__ vout, float scale)
{
    const int h = blockIdx.y;
    __shared__ float vs[NL * DH];
    const int tid = threadIdx.x;
    const float* vh = vin + (size_t)h * NL * DH;
    #pragma unroll
    for (int i = 0; i < 8; ++i) vs[tid + 256 * i] = vh[tid + 256 * i];
    __syncthreads();
    const int row = blockIdx.x * 32 + (tid >> 3);
    const int d = tid & 7;
    const float* Mr = M + ((size_t)h * NL + row) * NL;
    float acc = 0.f;
    #pragma unroll 4
    for (int j = 0; j < NL; j += 4) {
        float4 m = *(const float4*)&Mr[j];
        acc += m.x * vs[j * 8 + d]      + m.y * vs[j * 8 + 8 + d]
             + m.z * vs[j * 8 + 16 + d] + m.w * vs[j * 8 + 24 + d];
    }
    vout[((size_t)h * NL + row) * DH + d] = acc * scale;
}

// ------------------------------------------------------------------
// attn3 @ v: no-max softmax (scores O(1)); 4 landmarks/block, 4 chunks
// ------------------------------------------------------------------
__global__ void attn3v(const float* __restrict__ kh, const float* __restrict__ vh,
                       const float* __restrict__ ql, float* __restrict__ part)
{
    const int i0 = blockIdx.x * 4, h = blockIdx.y, ck = blockIdx.z, tid = threadIdx.x;
    __shared__ float sq[4][8];
    __shared__ float wred[4][4][9];
    if (tid < 32) sq[tid >> 3][tid & 7] = ql[((size_t)h * NL + i0 + (tid >> 3)) * DH + (tid & 7)];
    __syncthreads();
    float q[4][8];
    #pragma unroll
    for (int li = 0; li < 4; ++li)
        #pragma unroll
        for (int d = 0; d < 8; ++d) q[li][d] = sq[li][d];
    const float* kb = kh + (size_t)h * NP * DH;
    const float* vb = vh + (size_t)h * NP * DH;
    float den[4] = {};
    float acc[4][8] = {};
    const int tEnd = (ck + 1) * CKT;
    for (int t = ck * CKT + tid; t < tEnd; t += 256) {
        const float4 k0 = *(const float4*)&kb[(size_t)t * 8];
        const float4 k1 = *(const float4*)&kb[(size_t)t * 8 + 4];
        const float4 v0 = *(const float4*)&vb[(size_t)t * 8];
        const float4 v1 = *(const float4*)&vb[(size_t)t * 8 + 4];
        float vv[8] = {v0.x, v0.y, v0.z, v0.w, v1.x, v1.y, v1.z, v1.w};
        float kk[8] = {k0.x, k0.y, k0.z, k0.w, k1.x, k1.y, k1.z, k1.w};
        #pragma unroll
        for (int li = 0; li < 4; ++li) {
            float s = 0.f;
            #pragma unroll
            for (int d = 0; d < 8; ++d) s += q[li][d] * kk[d];
            float e = __expf(s);
            den[li] += e;
            #pragma unroll
            for (int d = 0; d < 8; ++d) acc[li][d] += e * vv[d];
        }
    }
    #pragma unroll
    for (int off = 1; off < 64; off <<= 1) {
        #pragma unroll
        for (int li = 0; li < 4; ++li) {
            den[li] += __shfl_xor(den[li], off);
            #pragma unroll
            for (int d = 0; d < 8; ++d) acc[li][d] += __shfl_xor(acc[li][d], off);
        }
    }
    const int wave = tid >> 6, lane = tid & 63;
    if (lane == 0) {
        #pragma unroll
        for (int li = 0; li < 4; ++li) {
            wred[wave][li][0] = den[li];
            #pragma unroll
            for (int d = 0; d < 8; ++d) wred[wave][li][1 + d] = acc[li][d];
        }
    }
    __syncthreads();
    if (tid < 4) {
        const int li = tid;
        float D_ = 0.f;
        float A[8] = {};
        #pragma unroll
        for (int w = 0; w < 4; ++w) {
            D_ += wred[w][li][0];
            #pragma unroll
            for (int d = 0; d < 8; ++d) A[d] += wred[w][li][1 + d];
        }
        float* p = part + (((size_t)h * NL + i0 + li) * 4 + ck) * 10;
        p[0] = D_;
        #pragma unroll
        for (int d = 0; d < 8; ++d) p[1 + d] = A[d];
    }
}

// merge 4 chunks -> y0[h][i][d];  2048 items
__global__ void attn3v_merge(const float* __restrict__ part, float* __restrict__ wbuf)
{
    int idx = blockIdx.x * 256 + threadIdx.x;   // h*NL+i
    const float* p = part + (size_t)idx * 40;
    float D_ = 0.f;
    float A[8] = {};
    #pragma unroll
    for (int ck = 0; ck < 4; ++ck) {
        const float* q = p + ck * 10;
        D_ += q[0];
        #pragma unroll
        for (int d = 0; d < 8; ++d) A[d] += q[1 + d];
    }
    float inv = 1.f / D_;
    #pragma unroll
    for (int d = 0; d < 8; ++d) wbuf[(size_t)idx * 8 + d] = A[d] * inv;
}

// ------------------------------------------------------------------
// attn1 fused + dwconv33(v): no-max softmax; 2 lanes/token; grid (154, 8)
// ------------------------------------------------------------------
__global__ void attn1_conv(const float* __restrict__ qh, const float* __restrict__ vh,
                           const float* __restrict__ klg, const float* __restrict__ zwg,
                           const float* __restrict__ rw, float* __restrict__ aout)
{
    const int h = blockIdx.y;
    __shared__ __align__(16) float kl[NL * DH];
    __shared__ __align__(16) float zw[NL * DH];
    const int tid = threadIdx.x;
    for (int q = tid; q < NL * DH; q += 256) {
        kl[q] = klg[(size_t)h * NL * DH + q];
        zw[q] = zwg[(size_t)h * NL * DH + q];
    }
    __syncthreads();
    const int half = tid & 1;
    const int r = blockIdx.x * 128 + (tid >> 1);
    if (r >= NT) return;
    const int t = r + PADR;
    const float* qp = qh + ((size_t)h * NP + t) * DH;
    float4 q0 = *(const float4*)qp;
    float4 q1 = *(const float4*)(qp + 4);
    float den = 0.f;
    float4 acc0 = make_float4(0.f, 0.f, 0.f, 0.f);
    float4 acc1 = make_float4(0.f, 0.f, 0.f, 0.f);
    const int iBeg = half * 128, iEnd = iBeg + 128;
    for (int i = iBeg; i < iEnd; ++i) {
        float4 k0 = *(const float4*)&kl[i * 8];
        float4 k1 = *(const float4*)&kl[i * 8 + 4];
        float s = q0.x * k0.x + q0.y * k0.y + q0.z * k0.z + q0.w * k0.w
                + q1.x * k1.x + q1.y * k1.y + q1.z * k1.z + q1.w * k1.w;
        float e = __expf(s);
        den += e;
        float4 z0 = *(const float4*)&zw[i * 8];
        float4 z1 = *(const float4*)&zw[i * 8 + 4];
        F4MAD(acc0, e, z0); F4MAD(acc1, e, z1);
    }
    {
        den += __shfl_xor(den, 1);
        float a[8] = {acc0.x, acc0.y, acc0.z, acc0.w, acc1.x, acc1.y, acc1.z, acc1.w};
        #pragma unroll
        for (int d = 0; d < 8; ++d) a[d] += __shfl_xor(a[d], 1);
        float inv = 1.f / den;
        acc0 = make_float4(a[0] * inv, a[1] * inv, a[2] * inv, a[3] * inv);
        acc1 = make_float4(a[4] * inv, a[5] * inv, a[6] * inv, a[7] * inv);
    }
    const float* vb = vh + (size_t)h * NP * DH;
    float4 c0 = make_float4(0.f, 0.f, 0.f, 0.f);
    float4 c1 = make_float4(0.f, 0.f, 0.f, 0.f);
    for (int j = half; j < 33; j += 2) {
        int tp = t - 16 + j;
        if (tp >= NP) continue;
        float wv = rw[h * 33 + j];
        float4 v0 = *(const float4*)&vb[(size_t)tp * 8];
        float4 v1 = *(const float4*)&vb[(size_t)tp * 8 + 4];
        F4MAD(c0, wv, v0); F4MAD(c1, wv, v1);
    }
    c0.x += __shfl_xor(c0.x, 1); c0.y += __shfl_xor(c0.y, 1);
    c0.z += __shfl_xor(c0.z, 1); c0.w += __shfl_xor(c0.w, 1);
    c1.x += __shfl_xor(c1.x, 1); c1.y += __shfl_xor(c1.y, 1);
    c1.z += __shfl_xor(c1.z, 1); c1.w += __shfl_xor(c1.w, 1);
    if (half == 0) {
        float* op = aout + (size_t)r * 64 + h * 8;
        *(float4*)op = make_float4(acc0.x + c0.x, acc0.y + c0.y, acc0.z + c0.z, acc0.w + c0.w);
        *(float4*)(op + 4) = make_float4(acc1.x + c1.x, acc1.y + c1.y, acc1.z + c1.z, acc1.w + c1.w);
    }
}

// ------------------------------------------------------------------
// out-proj + residual: 16 rows/block
// ------------------------------------------------------------------
__global__ void outproj(const float* __restrict__ aout, const float* __restrict__ W,
                        const float* __restrict__ bias, float* __restrict__ h)
{
    const int r0 = blockIdx.x * 16;
    const int tid = threadIdx.x;   // 512
    __shared__ float ao[16][64];
    #pragma unroll
    for (int s = 0; s < 2; ++s) {
        int idx = tid + s * 512;
        int rr = idx >> 6, kk = idx & 63;
        int gr = r0 + rr;
        ao[rr][kk] = (gr < NT) ? aout[(size_t)gr * 64 + kk] : 0.f;
    }
    __syncthreads();
    float acc[16] = {};
    for (int k = 0; k < 64; ++k) {
        float wv = W[(size_t)k * HD + tid];
        #pragma unroll
        for (int r = 0; r < 16; ++r) acc[r] += ao[r][k] * wv;
    }
    float bv = bias[tid];
    #pragma unroll
    for (int r = 0; r < 16; ++r) {
        int gr = r0 + r;
        if (gr < NT) h[(size_t)gr * HD + tid] += acc[r] + bv;
    }
}

// ------------------------------------------------------------------
// PPEG
// ------------------------------------------------------------------
__global__ void ppeg_wprep(const float* __restrict__ w7, const float* __restrict__ b7,
                           const float* __restrict__ w5, const float* __restrict__ b5,
                           const float* __restrict__ w3, const float* __restrict__ b3,
                           float* __restrict__ wc, float* __restrict__ bsum)
{
    int idx = blockIdx.x * 256 + threadIdx.x;
    if (idx < HD * 49) {
        int c = idx / 49, t = idx - c * 49;
        int dy = t / 7 - 3, dx = t % 7 - 3;
        float v = w7[idx];
        if (dy >= -2 && dy <= 2 && dx >= -2 && dx <= 2) v += w5[c * 25 + (dy + 2) * 5 + (dx + 2)];
        if (dy >= -1 && dy <= 1 && dx >= -1 && dx <= 1) v += w3[c * 9 + (dy + 1) * 3 + (dx + 1)];
        if (t == 24) v += 1.f;
        wc[idx] = v;
    } else if (idx < HD * 49 + HD) {
        int c = idx - HD * 49;
        bsum[c] = b7[c] + b5[c] + b3[c];
    }
}

__global__ void ppeg_t1(const float* __restrict__ hin, float* __restrict__ plan, int ch0)
{
    __shared__ float tile[32][33];
    const int tx = threadIdx.x & 31, ty = threadIdx.x >> 5;
    const int p0 = blockIdx.x * 32;
    const int c0 = ch0 + blockIdx.y * 32;
    #pragma unroll
    for (int j = 0; j < 4; ++j) {
        int p = p0 + ty + j * 8;
        tile[ty + j * 8][tx] = (p < NPIX) ? hin[(size_t)(1 + p) * HD + c0 + tx] : 0.f;
    }
    __syncthreads();
    #pragma unroll
    for (int j = 0; j < 4; ++j) {
        int p = p0 + tx;
        int cc = ty + j * 8;
        if (p < NPIX) plan[(size_t)(blockIdx.y * 32 + cc) * NPIX + p] = tile[tx][cc];
    }
}

__global__ __launch_bounds__(256) void ppeg_conv(const float* __restrict__ plan,
                                                 const float* __restrict__ wc,
                                                 float* __restrict__ plan2, int ch0)
{
    __shared__ __align__(16) float img[41 * PW];
    const int tid = threadIdx.x;
    const int cl = blockIdx.x;
    const int yq = blockIdx.y;
    for (int i = tid; i < 41 * PW; i += 256) img[i] = 0.f;
    __syncthreads();
    const float* src = plan + (size_t)cl * NPIX;
    for (int i = tid; i < 41 * SIDE; i += 256) {
        int ly = i / SIDE, x = i - ly * SIDE;
        int y = yq * 35 - 3 + ly;
        if (y >= 0 && y < SIDE) img[ly * PW + x + 3] = src[y * SIDE + x];
    }
    const float* w = wc + (size_t)(ch0 + cl) * 49;
    float wr[49];
    #pragma unroll
    for (int t = 0; t < 49; ++t) wr[t] = w[t];
    __syncthreads();
    float* dst = plan2 + (size_t)cl * NPIX;
    for (int g = tid; g < 35 * 35; g += 256) {
        int yl = g / 35, x0 = (g - yl * 35) * 4;
        float acc0 = 0.f, acc1 = 0.f, acc2 = 0.f, acc3 = 0.f;
        #pragma unroll
        for (int a = 0; a < 7; ++a) {
            const float* row = &img[(yl + a) * PW + x0];
            float4 A = *(const float4*)(row);
            float4 B = *(const float4*)(row + 4);
            float4 C = *(const float4*)(row + 8);
            float e0 = A.x, e1 = A.y, e2 = A.z, e3 = A.w;
            float e4 = B.x, e5 = B.y, e6 = B.z, e7 = B.w;
            float e8 = C.x, e9 = C.y;
            const float w0 = wr[a*7+0], w1 = wr[a*7+1], w2 = wr[a*7+2], w3v = wr[a*7+3];
            const float w4 = wr[a*7+4], w5v = wr[a*7+5], w6 = wr[a*7+6];
            acc0 += w0*e0 + w1*e1 + w2*e2 + w3v*e3 + w4*e4 + w5v*e5 + w6*e6;
            acc1 += w0*e1 + w1*e2 + w2*e3 + w3v*e4 + w4*e5 + w5v*e6 + w6*e7;
            acc2 += w0*e2 + w1*e3 + w2*e4 + w3v*e5 + w4*e6 + w5v*e7 + w6*e8;
            acc3 += w0*e3 + w1*e4 + w2*e5 + w3v*e6 + w4*e7 + w5v*e8 + w6*e9;
        }
        *(float4*)&dst[(yq * 35 + yl) * SIDE + x0] = make_float4(acc0, acc1, acc2, acc3);
    }
}

__global__ void ppeg_t2(const float* __restrict__ plan2, const float* __restrict__ bsum,
                        float* __restrict__ hout, int ch0)
{
    __shared__ float tile[32][33];
    const int tx = threadIdx.x & 31, ty = threadIdx.x >> 5;
    const int p0 = blockIdx.x * 32;
    #pragma unroll
    for (int j = 0; j < 4; ++j) {
        int p = p0 + tx;
        int cc = ty + j * 8;
        tile[tx][cc] = (p < NPIX) ? plan2[(size_t)(blockIdx.y * 32 + cc) * NPIX + p] : 0.f;
    }
    __syncthreads();
    const int c0 = ch0 + blockIdx.y * 32;
    float bv = bsum[c0 + tx];
    #pragma unroll
    for (int j = 0; j < 4; ++j) {
        int p = p0 + ty + j * 8;
        if (p < NPIX) hout[(size_t)(1 + p) * HD + c0 + tx] = tile[ty + j * 8][tx] + bv;
    }
}

// ------------------------------------------------------------------
// final layernorm of row 0
// ------------------------------------------------------------------
__global__ void final_ln(const float* __restrict__ h, const float* __restrict__ g,
                         const float* __restrict__ b, float* __restrict__ out)
{
    const int tid = threadIdx.x;
    float v0 = h[tid], v1 = h[tid + 256];
    __shared__ float red[256];
    red[tid] = v0 + v1;
    __syncthreads();
    for (int off = 128; off > 0; off >>= 1) {
        if (tid < off) red[tid] += red[tid + off];
        __syncthreads();
    }
    float mu = red[0] * (1.f / HD);
    __syncthreads();
    float d0 = v0 - mu, d1 = v1 - mu;
    red[tid] = d0 * d0 + d1 * d1;
    __syncthreads();
    for (int off = 128; off > 0; off >>= 1) {
        if (tid < off) red[tid] += red[tid + off];
        __syncthreads();
    }
    float inv = rsqrtf(red[0] * (1.f / HD) + 1e-5f);
    out[tid]       = d0 * inv * g[tid] + b[tid];
    out[tid + 256] = d1 * inv * g[tid + 256] + b[tid + 256];
}

} // namespace

extern "C" void kernel_launch(void* const* d_in, const int* in_sizes, int n_in,
                              void* d_out, int out_size, void* d_ws, size_t ws_size,
                              hipStream_t stream)
{
    const float* x      = (const float*)d_in[0];
    const float* fc1_w  = (const float*)d_in[1];
    const float* fc1_b  = (const float*)d_in[2];
    const float* cls    = (const float*)d_in[3];
    const float* l1_g   = (const float*)d_in[4];
    const float* l1_bb  = (const float*)d_in[5];
    const float* l1_qkv = (const float*)d_in[6];
    const float* l1_ow  = (const float*)d_in[7];
    const float* l1_ob  = (const float*)d_in[8];
    const float* l1_rw  = (const float*)d_in[9];
    const float* l2_g   = (const float*)d_in[10];
    const float* l2_bb  = (const float*)d_in[11];
    const float* l2_qkv = (const float*)d_in[12];
    const float* l2_ow  = (const float*)d_in[13];
    const float* l2_ob  = (const float*)d_in[14];
    const float* l2_rw  = (const float*)d_in[15];
    const float* p7w    = (const float*)d_in[16];
    const float* p7b    = (const float*)d_in[17];
    const float* p5w    = (const float*)d_in[18];
    const float* p5b    = (const float*)d_in[19];
    const float* p3w    = (const float*)d_in[20];
    const float* p3b    = (const float*)d_in[21];
    const float* ng     = (const float*)d_in[22];
    const float* nb     = (const float*)d_in[23];
    float* out = (float*)d_out;

    char* ws = (char*)d_ws;
    size_t off = 0;
    auto alloc = [&](size_t bytes) {
        char* p = ws + off;
        off += (bytes + 255) & ~(size_t)255;
        return (void*)p;
    };
    float* bufA = (float*)alloc((size_t)NP * HD * 4);
    float* bufB = (float*)alloc((size_t)NP * HD * 4);
    float* qh   = (float*)alloc((size_t)NH * NP * DH * 4);
    float* kh   = (float*)alloc((size_t)NH * NP * DH * 4);
    float* vh   = (float*)alloc((size_t)NH * NP * DH * 4);
    float* aout = (float*)alloc((size_t)NP * 64 * 4);
    float* ql   = (float*)alloc((size_t)NH * NL * DH * 4);
    float* klm  = (float*)alloc((size_t)NH * NL * DH * 4);
    float* ybuf = (float*)alloc((size_t)NH * NL * DH * 4);
    float* zwb  = (float*)alloc((size_t)NH * NL * DH * 4);
    float* a2   = (float*)alloc((size_t)NH * NL * NL * 4);
    float* zb0  = (float*)alloc((size_t)NH * NL * NL * 4);   // z0 (kept for final)
    float* azb  = (float*)alloc((size_t)NH * NL * NL * 4);   // w ping
    float* tb   = (float*)alloc((size_t)NH * NL * NL * 4);   // w pong
    float* ub   = (float*)alloc((size_t)NH * NL * NL * 4);   // S = w@w
    float* part = (float*)alloc(256);
    float* a3p  = (float*)alloc((size_t)NH * NL * 4 * 10 * 4);
    float* plan  = (float*)alloc((size_t)CCH * NPIX * 4);
    float* plan2 = (float*)alloc((size_t)CCH * NPIX * 4);
    float* wcomb = (float*)alloc((size_t)HD * 49 * 4);
    float* bsum  = (float*)alloc((size_t)HD * 4);
    short* wt1   = (short*)alloc((size_t)HD * ID * 2);
    short* wtq   = (short*)alloc((size_t)192 * HD * 2);
    short* xb    = (short*)alloc((size_t)NP * ID * 2);   // NP rows: fc1 A-tiles may read past NPIX
    short* xpB   = (short*)alloc((size_t)NP * HD * 2);
    (void)ws_size; (void)in_sizes; (void)n_in; (void)out_size;

    castX<<<(NPIX * ID / 8) / 256, 256, 0, stream>>>(x, xb);
    castT<<<dim3(HD / 32, ID / 32), 256, 0, stream>>>(fc1_w, wt1, ID, HD);
    gemm_fc1<<<dim3(4, 154), 256, 0, stream>>>(xb, wt1, fc1_b, bufA);
    cls_init<<<2, 256, 0, stream>>>(cls, bufA);

    auto attention = [&](float* hbuf, const float* lg, const float* lb,
                         const float* qkvw, const float* ow, const float* ob,
                         const float* rw) {
        ln_pad<<<NP, 256, 0, stream>>>(hbuf, lg, lb, xpB);
        castT<<<dim3(192 / 32, HD / 32), 256, 0, stream>>>(qkvw, wtq, HD, 192);
        gemm_qkv<<<dim3(3, 154), 256, 0, stream>>>(xpB, wtq, qh, kh, vh);
        landmarks<<<128, 256, 0, stream>>>(qh, kh, ql, klm);
        attn2_softmax<<<dim3(NL, NH), 256, 0, stream>>>(ql, klm, a2);
        pinv_norms<<<16, 256, 0, stream>>>(a2, part);
        z0_init<<<2048, 256, 0, stream>>>(a2, part, zb0);
        // y0 = attn3 @ v (softmax-normalized), threaded through the chain
        attn3v<<<dim3(NL / 4, NH, 4), 256, 0, stream>>>(kh, vh, ql, a3p);
        attn3v_merge<<<8, 256, 0, stream>>>(a3p, ybuf);
        // w-space Newton-Schulz, w0 = a@z0.
        // per iter: S=w@w; w' = 0.25*(13w-15S+7*S@w - S@S) [fused tu_mm];
        // y <- P_it @ y (P's commute: polynomials of shared w0).
        mm256<<<dim3(8, 4, 8), 256, 0, stream>>>(a2, zb0, azb);
        float* wc = azb;
        float* wn = tb;
        for (int it = 0; it < 6; ++it) {
            mm256<<<dim3(8, 4, 8), 256, 0, stream>>>(wc, wc, ub);       // S
            if (it < 5) tu_mm<<<dim3(8, 4, 8), 256, 0, stream>>>(ub, wc, wn);
            yupd<<<8, 256, 0, stream>>>(wc, ub, ybuf);
            if (it < 5) { float* tmp = wc; wc = wn; wn = tmp; }
        }
        // zw = 4^-6 * z0 @ y6
        polyv<<<dim3(8, NH), 256, 0, stream>>>(zb0, ybuf, zwb, 2.44140625e-4f);
        attn1_conv<<<dim3(154, NH), 256, 0, stream>>>(qh, vh, klm, zwb, rw, aout);
        outproj<<<(NT + 15) / 16, 512, 0, stream>>>(aout, ow, ob, hbuf);
    };

    attention(bufA, l1_g, l1_bb, l1_qkv, l1_ow, l1_ob, l1_rw);

    ppeg_wprep<<<(HD * 49 + HD + 255) / 256, 256, 0, stream>>>(p7w, p7b, p5w, p5b, p3w, p3b,
                                                               wcomb, bsum);
    copy512<<<1, 512, 0, stream>>>(bufA, bufB);
    constexpr int PTILES = (NPIX + 31) / 32;
    for (int ch0 = 0; ch0 < HD; ch0 += CCH) {
        ppeg_t1<<<dim3(PTILES, CCH / 32), 256, 0, stream>>>(bufA, plan, ch0);
        ppeg_conv<<<dim3(CCH, 4), 256, 0, stream>>>(plan, wcomb, plan2, ch0);
        ppeg_t2<<<dim3(PTILES, CCH / 32), 256, 0, stream>>>(plan2, bsum, bufB, ch0);
    }

    attention(bufB, l2_g, l2_bb, l2_qkv, l2_ow, l2_ob, l2_rw);
    final_ln<<<1, 256, 0, stream>>>(bufB, ng, nb, out);
}

// Round 3
// 1327.154 us; speedup vs baseline: 1.0488x; 1.0488x over previous
//
#include <hip/hip_runtime.h>

namespace {

constexpr int NP   = 19712;   // padded tokens (Nystrom)
constexpr int NT   = 19601;   // tokens incl cls
constexpr int NPIX = 19600;   // feature tokens (140x140)
constexpr int HD   = 512;     // hidden dim
constexpr int ID   = 1024;    // input dim
constexpr int NH   = 8;       // heads
constexpr int DH   = 8;       // dim per head
constexpr int NL   = 256;     // landmarks
constexpr int PADR = 111;     // left zero-pad rows
constexpr int SIDE = 140;
constexpr int CCH  = 128;     // ppeg channel chunk
constexpr int PW   = 148;     // padded image row stride (floats)
constexpr int A3CHK = 256;    // attn3v tokens per block
constexpr int A3NB  = NP / A3CHK;   // 77 chunks

typedef __attribute__((ext_vector_type(8))) short bf16x8;
typedef __attribute__((ext_vector_type(4))) float f32x4;

#define F4MAD(a, s, v) { (a).x += (s)*(v).x; (a).y += (s)*(v).y; (a).z += (s)*(v).z; (a).w += (s)*(v).w; }

// async global->LDS, 16B per lane; LDS dest must be wave-uniform base + lane*16
#define GLOAD16(gptr, lptr) \
    __builtin_amdgcn_global_load_lds((const __attribute__((address_space(1))) void*)(gptr), \
                                     (__attribute__((address_space(3))) void*)(lptr), 16, 0, 0)

__device__ inline short f2bf(float f) {
    union { float f; unsigned u; } v; v.f = f;
    unsigned r = v.u + 0x7fffu + ((v.u >> 16) & 1u);
    return (short)(r >> 16);
}

// ------------------------------------------------------------------
// cast X fp32 -> bf16 elementwise
// ------------------------------------------------------------------
__global__ void castX(const float* __restrict__ src, short* __restrict__ dst)
{
    size_t c = (size_t)blockIdx.x * 256 + threadIdx.x;
    const float4 x0 = *(const float4*)&src[c * 8];
    const float4 x1 = *(const float4*)&src[c * 8 + 4];
    bf16x8 p;
    p[0] = f2bf(x0.x); p[1] = f2bf(x0.y); p[2] = f2bf(x0.z); p[3] = f2bf(x0.w);
    p[4] = f2bf(x1.x); p[5] = f2bf(x1.y); p[6] = f2bf(x1.z); p[7] = f2bf(x1.w);
    *(bf16x8*)&dst[c * 8] = p;
}

// ------------------------------------------------------------------
// cast+transpose: dst[c][r] = bf16(src[r][c]); grid (C/32, R/32)
// ------------------------------------------------------------------
__global__ void castT(const float* __restrict__ src, short* __restrict__ dst, int R, int C)
{
    __shared__ float t[32][33];
    const int tx = threadIdx.x & 31, ty = threadIdx.x >> 5;
    const int c0 = blockIdx.x * 32, r0 = blockIdx.y * 32;
    #pragma unroll
    for (int j = 0; j < 4; ++j)
        t[ty + 8 * j][tx] = src[(size_t)(r0 + ty + 8 * j) * C + c0 + tx];
    __syncthreads();
    #pragma unroll
    for (int j = 0; j < 4; ++j)
        dst[(size_t)(c0 + ty + 8 * j) * R + r0 + tx] = f2bf(t[tx][ty + 8 * j]);
}

// ------------------------------------------------------------------
// fc1 MFMA: 128x128 tile, BK=32, 2-phase dbuf global_load_lds.
// Swizzle: chunk g = p ^ ((row>>1)&3). Over 8 consecutive lanes the pair
// (row parity, chunk) is a bijection -> 32 distinct banks per phase group.
// ------------------------------------------------------------------
__global__ __launch_bounds__(256) void gemm_fc1(const short* __restrict__ Xb,
                                                const short* __restrict__ Wt,
                                                const float* __restrict__ bias,
                                                float* __restrict__ out)
{
    __shared__ __align__(16) short As[2][128 * 32];
    __shared__ __align__(16) short Bs[2][128 * 32];
    const int tid  = threadIdx.x;
    const int col0 = blockIdx.x * 128;
    const int row0 = blockIdx.y * 128;
    const int wave = tid >> 6, lane = tid & 63;
    const int quad = lane >> 4, l16 = lane & 15;
    const int m_base = (wave >> 1) * 64, n_base = (wave & 1) * 64;
    const int kch = (quad ^ ((l16 >> 1) & 3)) * 8;   // swizzled k-chunk (shorts)
    f32x4 acc[4][4] = {};

    int    aldo[2];
    size_t agoff[2], bgoff[2];
    #pragma unroll
    for (int i = 0; i < 2; ++i) {
        int slot = i * 256 + wave * 64 + lane;
        int row  = slot >> 2;
        int g    = (slot & 3) ^ ((slot >> 3) & 3);
        aldo[i]  = slot * 8;
        agoff[i] = (size_t)(row0 + row) * ID + g * 8;
        bgoff[i] = (size_t)(col0 + row) * ID + g * 8;
    }
    auto stage = [&](int b, int k0) {
        #pragma unroll
        for (int i = 0; i < 2; ++i) {
            GLOAD16(&Xb[agoff[i] + k0], &As[b][aldo[i]]);
            GLOAD16(&Wt[bgoff[i] + k0], &Bs[b][aldo[i]]);
        }
    };

    stage(0, 0);
    __syncthreads();
    #pragma unroll 1
    for (int t = 0; t < 32; ++t) {
        const int cur = t & 1;
        if (t < 31) stage(cur ^ 1, (t + 1) * 32);
        bf16x8 af[4], bfr[4];
        #pragma unroll
        for (int i = 0; i < 4; ++i) {
            af[i]  = *(const bf16x8*)&As[cur][(m_base + i * 16 + l16) * 32 + kch];
            bfr[i] = *(const bf16x8*)&Bs[cur][(n_base + i * 16 + l16) * 32 + kch];
        }
        #pragma unroll
        for (int mi = 0; mi < 4; ++mi)
            #pragma unroll
            for (int ni = 0; ni < 4; ++ni)
                acc[mi][ni] = __builtin_amdgcn_mfma_f32_16x16x32_bf16(af[mi], bfr[ni], acc[mi][ni], 0, 0, 0);
        __syncthreads();
    }
    #pragma unroll
    for (int mi = 0; mi < 4; ++mi) {
        #pragma unroll
        for (int r = 0; r < 4; ++r) {
            int gr = row0 + m_base + mi * 16 + quad * 4 + r;
            if (gr >= NPIX) continue;
            #pragma unroll
            for (int ni = 0; ni < 4; ++ni) {
                int gc = col0 + n_base + ni * 16 + l16;
                float v = acc[mi][ni][r] + bias[gc];
                v = 0.5f * v * (1.f + erff(v * 0.70710678118654752f));
                out[(size_t)(gr + 1) * HD + gc] = v;
            }
        }
    }
}

// ------------------------------------------------------------------
// qkv MFMA: 128x64 tile, BK=32, same 2-phase dbuf + fixed swizzle.
// grid (3 colblocks, 154 rowblocks)
// ------------------------------------------------------------------
__global__ __launch_bounds__(256) void gemm_qkv(const short* __restrict__ xpB,
                                                const short* __restrict__ Wt,
                                                float* __restrict__ qh,
                                                float* __restrict__ kh,
                                                float* __restrict__ vh)
{
    __shared__ __align__(16) short As[2][128 * 32];
    __shared__ __align__(16) short Bs[2][64 * 32];
    const int tid  = threadIdx.x;
    const int col0 = blockIdx.x * 64;
    const int row0 = blockIdx.y * 128;
    const int wave = tid >> 6, lane = tid & 63;
    const int quad = lane >> 4, l16 = lane & 15;
    const int m_base = (wave >> 1) * 64, n_base = (wave & 1) * 32;
    const int kch = (quad ^ ((l16 >> 1) & 3)) * 8;
    f32x4 acc[4][2] = {};

    int    aldo[2];
    size_t agoff[2];
    #pragma unroll
    for (int i = 0; i < 2; ++i) {
        int slot = i * 256 + wave * 64 + lane;
        int row  = slot >> 2;
        int g    = (slot & 3) ^ ((slot >> 3) & 3);
        aldo[i]  = slot * 8;
        agoff[i] = (size_t)(row0 + row) * HD + g * 8;
    }
    int bldo; size_t bgoff;
    {
        int slot = wave * 64 + lane;
        int row  = slot >> 2;
        int g    = (slot & 3) ^ ((slot >> 3) & 3);
        bldo  = slot * 8;
        bgoff = (size_t)(col0 + row) * HD + g * 8;
    }
    auto stage = [&](int b, int k0) {
        #pragma unroll
        for (int i = 0; i < 2; ++i)
            GLOAD16(&xpB[agoff[i] + k0], &As[b][aldo[i]]);
        GLOAD16(&Wt[bgoff + k0], &Bs[b][bldo]);
    };

    stage(0, 0);
    __syncthreads();
    #pragma unroll 1
    for (int t = 0; t < 16; ++t) {
        const int cur = t & 1;
        if (t < 15) stage(cur ^ 1, (t + 1) * 32);
        bf16x8 af[4], bfr[2];
        #pragma unroll
        for (int i = 0; i < 4; ++i)
            af[i] = *(const bf16x8*)&As[cur][(m_base + i * 16 + l16) * 32 + kch];
        #pragma unroll
        for (int i = 0; i < 2; ++i)
            bfr[i] = *(const bf16x8*)&Bs[cur][(n_base + i * 16 + l16) * 32 + kch];
        #pragma unroll
        for (int mi = 0; mi < 4; ++mi)
            #pragma unroll
            for (int ni = 0; ni < 2; ++ni)
                acc[mi][ni] = __builtin_amdgcn_mfma_f32_16x16x32_bf16(af[mi], bfr[ni], acc[mi][ni], 0, 0, 0);
        __syncthreads();
    }
    const int which = blockIdx.x;
    float* dst = (which == 0) ? qh : (which == 1) ? kh : vh;
    const float scale = (which == 0) ? 0.35355339059327373f : 1.f;
    #pragma unroll
    for (int mi = 0; mi < 4; ++mi) {
        #pragma unroll
        for (int r = 0; r < 4; ++r) {
            int gr = row0 + m_base + mi * 16 + quad * 4 + r;
            #pragma unroll
            for (int ni = 0; ni < 2; ++ni) {
                int n = n_base + ni * 16 + l16;
                int hh = n >> 3, d = n & 7;
                dst[((size_t)hh * NP + gr) * DH + d] = acc[mi][ni][r] * scale;
            }
        }
    }
}

__global__ void cls_init(const float* __restrict__ cls, float* __restrict__ h)
{
    int t = blockIdx.x * 256 + threadIdx.x;
    if (t < HD) h[t] = cls[t];
}

__global__ void copy512(const float* __restrict__ src, float* __restrict__ dst)
{
    dst[threadIdx.x] = src[threadIdx.x];
}

// ------------------------------------------------------------------
// layernorm rows of h into xp (bf16), first 111 rows zero
// ------------------------------------------------------------------
__global__ void ln_pad(const float* __restrict__ h, const float* __restrict__ g,
                       const float* __restrict__ b, short* __restrict__ xp)
{
    const int row = blockIdx.x;
    const int tid = threadIdx.x;
    short* dst = xp + (size_t)row * HD;
    if (row < PADR) { dst[tid] = 0; dst[tid + 256] = 0; return; }
    const float* src = h + (size_t)(row - PADR) * HD;
    float v0 = src[tid], v1 = src[tid + 256];
    __shared__ float red[256];
    red[tid] = v0 + v1;
    __syncthreads();
    for (int off = 128; off > 0; off >>= 1) {
        if (tid < off) red[tid] += red[tid + off];
        __syncthreads();
    }
    float mu = red[0] * (1.f / HD);
    __syncthreads();
    float d0 = v0 - mu, d1 = v1 - mu;
    red[tid] = d0 * d0 + d1 * d1;
    __syncthreads();
    for (int off = 128; off > 0; off >>= 1) {
        if (tid < off) red[tid] += red[tid + off];
        __syncthreads();
    }
    float inv = rsqrtf(red[0] * (1.f / HD) + 1e-5f);
    dst[tid]       = f2bf(d0 * inv * g[tid] + b[tid]);
    dst[tid + 256] = f2bf(d1 * inv * g[tid + 256] + b[tid + 256]);
}

// ------------------------------------------------------------------
// landmark means
// ------------------------------------------------------------------
__global__ void landmarks(const float* __restrict__ qh, const float* __restrict__ kh,
                          float* __restrict__ ql, float* __restrict__ kl)
{
    int idx = blockIdx.x * 256 + threadIdx.x;
    int sel = idx >> 14;
    int rem = idx & 16383;
    int h = rem >> 11;
    int i = (rem >> 3) & 255;
    int d = rem & 7;
    const float* src = sel ? kh : qh;
    size_t base = ((size_t)h * NP + (size_t)i * 77) * DH + d;
    float s = 0.f;
    for (int j = 0; j < 77; ++j) s += src[base + (size_t)j * DH];
    (sel ? kl : ql)[((size_t)h * NL + i) * DH + d] = s * (1.f / 77.f);
}

// ------------------------------------------------------------------
// attn2 = softmax(q_l @ k_l^T); scores are O(1) -> no max subtraction
// ------------------------------------------------------------------
__global__ void attn2_softmax(const float* __restrict__ ql, const float* __restrict__ kl,
                              float* __restrict__ a)
{
    const int i = blockIdx.x, h = blockIdx.y, j = threadIdx.x;
    __shared__ float sq[8];
    __shared__ float red[256];
    if (j < 8) sq[j] = ql[((size_t)h * NL + i) * DH + j];
    __syncthreads();
    const float* kr = kl + ((size_t)h * NL + j) * DH;
    float s = 0.f;
    #pragma unroll
    for (int d = 0; d < 8; ++d) s += sq[d] * kr[d];
    float e = __expf(s);
    red[j] = e;
    __syncthreads();
    for (int off = 128; off > 0; off >>= 1) {
        if (j < off) red[j] += red[j + off];
        __syncthreads();
    }
    a[((size_t)h * NL + i) * NL + j] = e / red[0];
}

// ------------------------------------------------------------------
// pinv init
// ------------------------------------------------------------------
__global__ void pinv_norms(const float* __restrict__ a, float* __restrict__ part)
{
    const int h = blockIdx.x & 7;
    const int mode = blockIdx.x >> 3;
    const int tid = threadIdx.x;
    const float* ah = a + (size_t)h * NL * NL;
    float s = 0.f;
    if (mode == 0) { for (int j = 0; j < NL; ++j) s += fabsf(ah[tid * NL + j]); }
    else           { for (int i = 0; i < NL; ++i) s += fabsf(ah[i * NL + tid]); }
    __shared__ float red[256];
    red[tid] = s;
    __syncthreads();
    for (int off = 128; off > 0; off >>= 1) {
        if (tid < off) red[tid] = fmaxf(red[tid], red[tid + off]);
        __syncthreads();
    }
    if (tid == 0) part[mode * 8 + h] = red[0];
}

__global__ void z0_init(const float* __restrict__ a, const float* __restrict__ part,
                        float* __restrict__ z)
{
    float s1 = part[0], s2 = part[8];
    #pragma unroll
    for (int h = 1; h < 8; ++h) { s1 = fmaxf(s1, part[h]); s2 = fmaxf(s2, part[8 + h]); }
    float inv = 1.f / (s1 * s2);
    int idx = blockIdx.x * 256 + threadIdx.x;
    int h = idx >> 16;
    int rem = idx & 65535;
    int i = rem >> 8, j = rem & 255;
    z[idx] = a[((size_t)h * NL + j) * NL + i] * inv;
}

// ------------------------------------------------------------------
// batched 256x256x256: D = A@B   grid (8,4,8)
// ------------------------------------------------------------------
__global__ void mm256(const float* __restrict__ A, const float* __restrict__ B,
                      float* __restrict__ D)
{
    const int h = blockIdx.z;
    const float* Ah = A + (size_t)h * NL * NL;
    const float* Bh = B + (size_t)h * NL * NL;
    float* Dh = D + (size_t)h * NL * NL;
    __shared__ __align__(16) float As[16][36];
    __shared__ __align__(16) float Bs[16][68];
    const int tid = threadIdx.x;
    const int tx = tid & 15, ty = tid >> 4;
    const int row0 = blockIdx.x * 32;
    const int col0 = blockIdx.y * 64;
    float acc[2][4] = {};
    const int ar = tid >> 3;
    const int ak = (tid & 7) * 2;
    const int bk = tid >> 4;
    const int bj = (tid & 15) * 4;
    for (int k0 = 0; k0 < NL; k0 += 16) {
        float2 av = *(const float2*)&Ah[(size_t)(row0 + ar) * NL + k0 + ak];
        As[ak][ar] = av.x; As[ak + 1][ar] = av.y;
        *(float4*)&Bs[bk][bj] = *(const float4*)&Bh[(size_t)(k0 + bk) * NL + col0 + bj];
        __syncthreads();
        #pragma unroll
        for (int k = 0; k < 16; ++k) {
            float2 a = *(const float2*)&As[k][ty * 2];
            float4 b = *(const float4*)&Bs[k][tx * 4];
            acc[0][0] += a.x * b.x; acc[0][1] += a.x * b.y; acc[0][2] += a.x * b.z; acc[0][3] += a.x * b.w;
            acc[1][0] += a.y * b.x; acc[1][1] += a.y * b.y; acc[1][2] += a.y * b.z; acc[1][3] += a.y * b.w;
        }
        __syncthreads();
    }
    #pragma unroll
    for (int r = 0; r < 2; ++r) {
        int gr = row0 + ty * 2 + r;
        #pragma unroll
        for (int c = 0; c < 4; ++c)
            Dh[(size_t)gr * NL + col0 + tx * 4 + c] = acc[r][c];
    }
}

// ------------------------------------------------------------------
// fused T=S@w, U=S@S, w' = 0.25*(13w - 15S + 7T - U)   grid (8,4,8)
// ------------------------------------------------------------------
__global__ void tu_mm(const float* __restrict__ S, const float* __restrict__ w,
                      float* __restrict__ wn)
{
    const int h = blockIdx.z;
    const float* Sh = S + (size_t)h * NL * NL;
    const float* wh = w + (size_t)h * NL * NL;
    float* Dh = wn + (size_t)h * NL * NL;
    __shared__ __align__(16) float As[16][36];
    __shared__ __align__(16) float Bw[16][68];
    __shared__ __align__(16) float Bu[16][68];
    const int tid = threadIdx.x;
    const int tx = tid & 15, ty = tid >> 4;
    const int row0 = blockIdx.x * 32;
    const int col0 = blockIdx.y * 64;
    float aT[2][4] = {}, aU[2][4] = {};
    const int ar = tid >> 3;
    const int ak = (tid & 7) * 2;
    const int bk = tid >> 4;
    const int bj = (tid & 15) * 4;
    for (int k0 = 0; k0 < NL; k0 += 16) {
        float2 av = *(const float2*)&Sh[(size_t)(row0 + ar) * NL + k0 + ak];
        As[ak][ar] = av.x; As[ak + 1][ar] = av.y;
        *(float4*)&Bw[bk][bj] = *(const float4*)&wh[(size_t)(k0 + bk) * NL + col0 + bj];
        *(float4*)&Bu[bk][bj] = *(const float4*)&Sh[(size_t)(k0 + bk) * NL + col0 + bj];
        __syncthreads();
        #pragma unroll
        for (int k = 0; k < 16; ++k) {
            float2 a = *(const float2*)&As[k][ty * 2];
            float4 b1 = *(const float4*)&Bw[k][tx * 4];
            float4 b2 = *(const float4*)&Bu[k][tx * 4];
            aT[0][0] += a.x * b1.x; aT[0][1] += a.x * b1.y; aT[0][2] += a.x * b1.z; aT[0][3] += a.x * b1.w;
            aT[1][0] += a.y * b1.x; aT[1][1] += a.y * b1.y; aT[1][2] += a.y * b1.z; aT[1][3] += a.y * b1.w;
            aU[0][0] += a.x * b2.x; aU[0][1] += a.x * b2.y; aU[0][2] += a.x * b2.z; aU[0][3] += a.x * b2.w;
            aU[1][0] += a.y * b2.x; aU[1][1] += a.y * b2.y; aU[1][2] += a.y * b2.z; aU[1][3] += a.y * b2.w;
        }
        __syncthreads();
    }
    #pragma unroll
    for (int r = 0; r < 2; ++r) {
        int gr = row0 + ty * 2 + r;
        #pragma unroll
        for (int c = 0; c < 4; ++c) {
            int gc = col0 + tx * 4 + c;
            size_t o = (size_t)gr * NL + gc;
            Dh[o] = 0.25f * (13.f * wh[o] - 15.f * Sh[o] + 7.f * aT[r][c] - aU[r][c]);
        }
    }
}

// ------------------------------------------------------------------
// y' = P(w)y = 13y - 15*t1 + S@(7y - t1), t1 = w@y.
// grid (8 slices, 8 heads): phase A computes full t1 (redundant per slice,
// 64-block parallelism); phase B does the block's 32-row slice.
// yin/yout distinct (no intra-launch race).
// ------------------------------------------------------------------
__global__ __launch_bounds__(256) void yiter(const float* __restrict__ w,
                                             const float* __restrict__ S,
                                             const float* __restrict__ yin,
                                             float* __restrict__ yout)
{
    const int s = blockIdx.x, h = blockIdx.y, tid = threadIdx.x;
    __shared__ float yL[NL * 9];
    __shared__ float tL[NL * 9];
    __shared__ float uL[NL * 9];
    const float* yh = yin + (size_t)h * NL * DH;
    #pragma unroll
    for (int i = 0; i < 8; ++i) {
        int idx = tid + 256 * i;
        yL[(idx >> 3) * 9 + (idx & 7)] = yh[idx];
    }
    __syncthreads();
    // phase A: t1[tid][:] = w[tid,:] @ y  (all 256 rows per block)
    const float* wr = w + ((size_t)h * NL + tid) * NL;
    float t1[8] = {};
    for (int j = 0; j < NL; j += 4) {
        float4 wv = *(const float4*)&wr[j];
        #pragma unroll
        for (int d = 0; d < 8; ++d)
            t1[d] += wv.x * yL[j * 9 + d] + wv.y * yL[(j + 1) * 9 + d]
                   + wv.z * yL[(j + 2) * 9 + d] + wv.w * yL[(j + 3) * 9 + d];
    }
    #pragma unroll
    for (int d = 0; d < 8; ++d) {
        tL[tid * 9 + d] = t1[d];
        uL[tid * 9 + d] = 7.f * yL[tid * 9 + d] - t1[d];
    }
    __syncthreads();
    // phase B: this block's 32 rows
    const int r = s * 32 + (tid >> 3), d = tid & 7;
    const float* Sr = S + ((size_t)h * NL + r) * NL;
    float acc = 13.f * yL[r * 9 + d] - 15.f * tL[r * 9 + d];
    for (int j = 0; j < NL; j += 4) {
        float4 sv = *(const float4*)&Sr[j];
        acc += sv.x * uL[j * 9 + d] + sv.y * uL[(j + 1) * 9 + d]
             + sv.z * uL[(j + 2) * 9 + d] + sv.w * uL[(j + 3) * 9 + d];
    }
    yout[((size_t)h * NL + r) * DH + d] = acc;
}

// ------------------------------------------------------------------
// vout[h] = scale * M[h] @ vin[h];  M: [8][256][256], v: [8][256][8]
// ------------------------------------------------------------------
__global__ void polyv(const float* __restrict__ M, const float* __restrict__ vin,
                      float* __restrict__ vout, float scale)
{
    const int h = blockIdx.y;
    __shared__ float vs[NL * DH];
    const int tid = threadIdx.x;
    const float* vh = vin + (size_t)h * NL * DH;
    #pragma unroll
    for (int i = 0; i < 8; ++i) vs[tid + 256 * i] = vh[tid + 256 * i];
    __syncthreads();
    const int row = blockIdx.x * 32 + (tid >> 3);
    const int d = tid & 7;
    const float* Mr = M + ((size_t)h * NL + row) * NL;
    float acc = 0.f;
    #pragma unroll 4
    for (int j = 0; j < NL; j += 4) {
        float4 m = *(const float4*)&Mr[j];
        acc += m.x * vs[j * 8 + d]      + m.y * vs[j * 8 + 8 + d]
             + m.z * vs[j * 8 + 16 + d] + m.w * vs[j * 8 + 24 + d];
    }
    vout[((size_t)h * NL + row) * DH + d] = acc * scale;
}

// ------------------------------------------------------------------
// attn3 @ v, single K/V pass: grid (77 chunks, 8 heads).
// Block stages 256 tokens of K,V in LDS (broadcast reads);
// thread = landmark. Partials (den, acc[8]) merged by attn3v_merge.
// ------------------------------------------------------------------
__global__ __launch_bounds__(256) void attn3v(const float* __restrict__ kh,
                                              const float* __restrict__ vh,
                                              const float* __restrict__ ql,
                                              float* __restrict__ part)
{
    const int ck = blockIdx.x, h = blockIdx.y, tid = threadIdx.x;
    __shared__ __align__(16) float4 kv[A3CHK][4];   // [t]: k0 k1 v0 v1
    const float* kb = kh + ((size_t)h * NP + (size_t)ck * A3CHK) * DH;
    const float* vb = vh + ((size_t)h * NP + (size_t)ck * A3CHK) * DH;
    #pragma unroll
    for (int i = 0; i < 2; ++i) {
        int idx = tid + 256 * i;          // 0..511
        int t = idx >> 1, p = idx & 1;
        kv[t][p]     = *(const float4*)&kb[t * 8 + p * 4];
        kv[t][2 + p] = *(const float4*)&vb[t * 8 + p * 4];
    }
    float q[8];
    const float* qp = ql + ((size_t)h * NL + tid) * DH;
    #pragma unroll
    for (int d = 0; d < 8; ++d) q[d] = qp[d];
    __syncthreads();
    float den = 0.f;
    float4 a0 = make_float4(0.f, 0.f, 0.f, 0.f);
    float4 a1 = make_float4(0.f, 0.f, 0.f, 0.f);
    #pragma unroll 4
    for (int t = 0; t < A3CHK; ++t) {
        float4 k0 = kv[t][0], k1 = kv[t][1];
        float s = q[0] * k0.x + q[1] * k0.y + q[2] * k0.z + q[3] * k0.w
                + q[4] * k1.x + q[5] * k1.y + q[6] * k1.z + q[7] * k1.w;
        float e = __expf(s);
        den += e;
        float4 v0 = kv[t][2], v1 = kv[t][3];
        F4MAD(a0, e, v0); F4MAD(a1, e, v1);
    }
    float* p = part + (((size_t)h * A3NB + ck) * NL + tid) * 9;
    p[0] = den;
    p[1] = a0.x; p[2] = a0.y; p[3] = a0.z; p[4] = a0.w;
    p[5] = a1.x; p[6] = a1.y; p[7] = a1.z; p[8] = a1.w;
}

// merge 77 chunks -> y0[h][i][d]; grid 8 (heads), thread = landmark
__global__ void attn3v_merge(const float* __restrict__ part, float* __restrict__ y)
{
    const int h = blockIdx.x, i = threadIdx.x;
    float den = 0.f;
    float acc[8] = {};
    for (int ck = 0; ck < A3NB; ++ck) {
        const float* p = part + (((size_t)h * A3NB + ck) * NL + i) * 9;
        den += p[0];
        #pragma unroll
        for (int d = 0; d < 8; ++d) acc[d] += p[1 + d];
    }
    float inv = 1.f / den;
    #pragma unroll
    for (int d = 0; d < 8; ++d) y[((size_t)h * NL + i) * DH + d] = acc[d] * inv;
}

// ------------------------------------------------------------------
// attn1 fused + dwconv33(v): no-max softmax; 2 lanes/token; grid (154, 8)
// ------------------------------------------------------------------
__global__ void attn1_conv(const float* __restrict__ qh, const float* __restrict__ vh,
                           const float* __restrict__ klg, const float* __restrict__ zwg,
                           const float* __restrict__ rw, float* __restrict__ aout)
{
    const int h = blockIdx.y;
    __shared__ __align__(16) float kl[NL * DH];
    __shared__ __align__(16) float zw[NL * DH];
    const int tid = threadIdx.x;
    for (int q = tid; q < NL * DH; q += 256) {
        kl[q] = klg[(size_t)h * NL * DH + q];
        zw[q] = zwg[(size_t)h * NL * DH + q];
    }
    __syncthreads();
    const int half = tid & 1;
    const int r = blockIdx.x * 128 + (tid >> 1);
    if (r >= NT) return;
    const int t = r + PADR;
    const float* qp = qh + ((size_t)h * NP + t) * DH;
    float4 q0 = *(const float4*)qp;
    float4 q1 = *(const float4*)(qp + 4);
    float den = 0.f;
    float4 acc0 = make_float4(0.f, 0.f, 0.f, 0.f);
    float4 acc1 = make_float4(0.f, 0.f, 0.f, 0.f);
    const int iBeg = half * 128, iEnd = iBeg + 128;
    for (int i = iBeg; i < iEnd; ++i) {
        float4 k0 = *(const float4*)&kl[i * 8];
        float4 k1 = *(const float4*)&kl[i * 8 + 4];
        float s = q0.x * k0.x + q0.y * k0.y + q0.z * k0.z + q0.w * k0.w
                + q1.x * k1.x + q1.y * k1.y + q1.z * k1.z + q1.w * k1.w;
        float e = __expf(s);
        den += e;
        float4 z0 = *(const float4*)&zw[i * 8];
        float4 z1 = *(const float4*)&zw[i * 8 + 4];
        F4MAD(acc0, e, z0); F4MAD(acc1, e, z1);
    }
    {
        den += __shfl_xor(den, 1);
        float a[8] = {acc0.x, acc0.y, acc0.z, acc0.w, acc1.x, acc1.y, acc1.z, acc1.w};
        #pragma unroll
        for (int d = 0; d < 8; ++d) a[d] += __shfl_xor(a[d], 1);
        float inv = 1.f / den;
        acc0 = make_float4(a[0] * inv, a[1] * inv, a[2] * inv, a[3] * inv);
        acc1 = make_float4(a[4] * inv, a[5] * inv, a[6] * inv, a[7] * inv);
    }
    const float* vb = vh + (size_t)h * NP * DH;
    float4 c0 = make_float4(0.f, 0.f, 0.f, 0.f);
    float4 c1 = make_float4(0.f, 0.f, 0.f, 0.f);
    for (int j = half; j < 33; j += 2) {
        int tp = t - 16 + j;
        if (tp >= NP) continue;
        float wv = rw[h * 33 + j];
        float4 v0 = *(const float4*)&vb[(size_t)tp * 8];
        float4 v1 = *(const float4*)&vb[(size_t)tp * 8 + 4];
        F4MAD(c0, wv, v0); F4MAD(c1, wv, v1);
    }
    c0.x += __shfl_xor(c0.x, 1); c0.y += __shfl_xor(c0.y, 1);
    c0.z += __shfl_xor(c0.z, 1); c0.w += __shfl_xor(c0.w, 1);
    c1.x += __shfl_xor(c1.x, 1); c1.y += __shfl_xor(c1.y, 1);
    c1.z += __shfl_xor(c1.z, 1); c1.w += __shfl_xor(c1.w, 1);
    if (half == 0) {
        float* op = aout + (size_t)r * 64 + h * 8;
        *(float4*)op = make_float4(acc0.x + c0.x, acc0.y + c0.y, acc0.z + c0.z, acc0.w + c0.w);
        *(float4*)(op + 4) = make_float4(acc1.x + c1.x, acc1.y + c1.y, acc1.z + c1.z, acc1.w + c1.w);
    }
}

// ------------------------------------------------------------------
// out-proj + residual: 16 rows/block
// ------------------------------------------------------------------
__global__ void outproj(const float* __restrict__ aout, const float* __restrict__ W,
                        const float* __restrict__ bias, float* __restrict__ h)
{
    const int r0 = blockIdx.x * 16;
    const int tid = threadIdx.x;   // 512
    __shared__ float ao[16][64];
    #pragma unroll
    for (int s = 0; s < 2; ++s) {
        int idx = tid + s * 512;
        int rr = idx >> 6, kk = idx & 63;
        int gr = r0 + rr;
        ao[rr][kk] = (gr < NT) ? aout[(size_t)gr * 64 + kk] : 0.f;
    }
    __syncthreads();
    float acc[16] = {};
    for (int k = 0; k < 64; ++k) {
        float wv = W[(size_t)k * HD + tid];
        #pragma unroll
        for (int r = 0; r < 16; ++r) acc[r] += ao[r][k] * wv;
    }
    float bv = bias[tid];
    #pragma unroll
    for (int r = 0; r < 16; ++r) {
        int gr = r0 + r;
        if (gr < NT) h[(size_t)gr * HD + tid] += acc[r] + bv;
    }
}

// ------------------------------------------------------------------
// PPEG
// ------------------------------------------------------------------
__global__ void ppeg_wprep(const float* __restrict__ w7, const float* __restrict__ b7,
                           const float* __restrict__ w5, const float* __restrict__ b5,
                           const float* __restrict__ w3, const float* __restrict__ b3,
                           float* __restrict__ wc, float* __restrict__ bsum)
{
    int idx = blockIdx.x * 256 + threadIdx.x;
    if (idx < HD * 49) {
        int c = idx / 49, t = idx - c * 49;
        int dy = t / 7 - 3, dx = t % 7 - 3;
        float v = w7[idx];
        if (dy >= -2 && dy <= 2 && dx >= -2 && dx <= 2) v += w5[c * 25 + (dy + 2) * 5 + (dx + 2)];
        if (dy >= -1 && dy <= 1 && dx >= -1 && dx <= 1) v += w3[c * 9 + (dy + 1) * 3 + (dx + 1)];
        if (t == 24) v += 1.f;
        wc[idx] = v;
    } else if (idx < HD * 49 + HD) {
        int c = idx - HD * 49;
        bsum[c] = b7[c] + b5[c] + b3[c];
    }
}

__global__ void ppeg_t1(const float* __restrict__ hin, float* __restrict__ plan, int ch0)
{
    __shared__ float tile[32][33];
    const int tx = threadIdx.x & 31, ty = threadIdx.x >> 5;
    const int p0 = blockIdx.x * 32;
    const int c0 = ch0 + blockIdx.y * 32;
    #pragma unroll
    for (int j = 0; j < 4; ++j) {
        int p = p0 + ty + j * 8;
        tile[ty + j * 8][tx] = (p < NPIX) ? hin[(size_t)(1 + p) * HD + c0 + tx] : 0.f;
    }
    __syncthreads();
    #pragma unroll
    for (int j = 0; j < 4; ++j) {
        int p = p0 + tx;
        int cc = ty + j * 8;
        if (p < NPIX) plan[(size_t)(blockIdx.y * 32 + cc) * NPIX + p] = tile[tx][cc];
    }
}

__global__ __launch_bounds__(256) void ppeg_conv(const float* __restrict__ plan,
                                                 const float* __restrict__ wc,
                                                 float* __restrict__ plan2, int ch0)
{
    __shared__ __align__(16) float img[41 * PW];
    const int tid = threadIdx.x;
    const int cl = blockIdx.x;
    const int yq = blockIdx.y;
    for (int i = tid; i < 41 * PW; i += 256) img[i] = 0.f;
    __syncthreads();
    const float* src = plan + (size_t)cl * NPIX;
    for (int i = tid; i < 41 * SIDE; i += 256) {
        int ly = i / SIDE, x = i - ly * SIDE;
        int y = yq * 35 - 3 + ly;
        if (y >= 0 && y < SIDE) img[ly * PW + x + 3] = src[y * SIDE + x];
    }
    const float* w = wc + (size_t)(ch0 + cl) * 49;
    float wr[49];
    #pragma unroll
    for (int t = 0; t < 49; ++t) wr[t] = w[t];
    __syncthreads();
    float* dst = plan2 + (size_t)cl * NPIX;
    for (int g = tid; g < 35 * 35; g += 256) {
        int yl = g / 35, x0 = (g - yl * 35) * 4;
        float acc0 = 0.f, acc1 = 0.f, acc2 = 0.f, acc3 = 0.f;
        #pragma unroll
        for (int a = 0; a < 7; ++a) {
            const float* row = &img[(yl + a) * PW + x0];
            float4 A = *(const float4*)(row);
            float4 B = *(const float4*)(row + 4);
            float4 C = *(const float4*)(row + 8);
            float e0 = A.x, e1 = A.y, e2 = A.z, e3 = A.w;
            float e4 = B.x, e5 = B.y, e6 = B.z, e7 = B.w;
            float e8 = C.x, e9 = C.y;
            const float w0 = wr[a*7+0], w1 = wr[a*7+1], w2 = wr[a*7+2], w3v = wr[a*7+3];
            const float w4 = wr[a*7+4], w5v = wr[a*7+5], w6 = wr[a*7+6];
            acc0 += w0*e0 + w1*e1 + w2*e2 + w3v*e3 + w4*e4 + w5v*e5 + w6*e6;
            acc1 += w0*e1 + w1*e2 + w2*e3 + w3v*e4 + w4*e5 + w5v*e6 + w6*e7;
            acc2 += w0*e2 + w1*e3 + w2*e4 + w3v*e5 + w4*e6 + w5v*e7 + w6*e8;
            acc3 += w0*e3 + w1*e4 + w2*e5 + w3v*e6 + w4*e7 + w5v*e8 + w6*e9;
        }
        *(float4*)&dst[(yq * 35 + yl) * SIDE + x0] = make_float4(acc0, acc1, acc2, acc3);
    }
}

__global__ void ppeg_t2(const float* __restrict__ plan2, const float* __restrict__ bsum,
                        float* __restrict__ hout, int ch0)
{
    __shared__ float tile[32][33];
    const int tx = threadIdx.x & 31, ty = threadIdx.x >> 5;
    const int p0 = blockIdx.x * 32;
    #pragma unroll
    for (int j = 0; j < 4; ++j) {
        int p = p0 + tx;
        int cc = ty + j * 8;
        tile[tx][cc] = (p < NPIX) ? plan2[(size_t)(blockIdx.y * 32 + cc) * NPIX + p] : 0.f;
    }
    __syncthreads();
    const int c0 = ch0 + blockIdx.y * 32;
    float bv = bsum[c0 + tx];
    #pragma unroll
    for (int j = 0; j < 4; ++j) {
        int p = p0 + ty + j * 8;
        if (p < NPIX) hout[(size_t)(1 + p) * HD + c0 + tx] = tile[ty + j * 8][tx] + bv;
    }
}

// ------------------------------------------------------------------
// final layernorm of row 0
// ------------------------------------------------------------------
__global__ void final_ln(const float* __restrict__ h, const float* __restrict__ g,
                         const float* __restrict__ b, float* __restrict__ out)
{
    const int tid = threadIdx.x;
    float v0 = h[tid], v1 = h[tid + 256];
    __shared__ float red[256];
    red[tid] = v0 + v1;
    __syncthreads();
    for (int off = 128; off > 0; off >>= 1) {
        if (tid < off) red[tid] += red[tid + off];
        __syncthreads();
    }
    float mu = red[0] * (1.f / HD);
    __syncthreads();
    float d0 = v0 - mu, d1 = v1 - mu;
    red[tid] = d0 * d0 + d1 * d1;
    __syncthreads();
    for (int off = 128; off > 0; off >>= 1) {
        if (tid < off) red[tid] += red[tid + off];
        __syncthreads();
    }
    float inv = rsqrtf(red[0] * (1.f / HD) + 1e-5f);
    out[tid]       = d0 * inv * g[tid] + b[tid];
    out[tid + 256] = d1 * inv * g[tid + 256] + b[tid + 256];
}

} // namespace

extern "C" void kernel_launch(void* const* d_in, const int* in_sizes, int n_in,
                              void* d_out, int out_size, void* d_ws, size_t ws_size,
                              hipStream_t stream)
{
    const float* x      = (const float*)d_in[0];
    const float* fc1_w  = (const float*)d_in[1];
    const float* fc1_b  = (const float*)d_in[2];
    const float* cls    = (const float*)d_in[3];
    const float* l1_g   = (const float*)d_in[4];
    const float* l1_bb  = (const float*)d_in[5];
    const float* l1_qkv = (const float*)d_in[6];
    const float* l1_ow  = (const float*)d_in[7];
    const float* l1_ob  = (const float*)d_in[8];
    const float* l1_rw  = (const float*)d_in[9];
    const float* l2_g   = (const float*)d_in[10];
    const float* l2_bb  = (const float*)d_in[11];
    const float* l2_qkv = (const float*)d_in[12];
    const float* l2_ow  = (const float*)d_in[13];
    const float* l2_ob  = (const float*)d_in[14];
    const float* l2_rw  = (const float*)d_in[15];
    const float* p7w    = (const float*)d_in[16];
    const float* p7b    = (const float*)d_in[17];
    const float* p5w    = (const float*)d_in[18];
    const float* p5b    = (const float*)d_in[19];
    const float* p3w    = (const float*)d_in[20];
    const float* p3b    = (const float*)d_in[21];
    const float* ng     = (const float*)d_in[22];
    const float* nb     = (const float*)d_in[23];
    float* out = (float*)d_out;

    char* ws = (char*)d_ws;
    size_t off = 0;
    auto alloc = [&](size_t bytes) {
        char* p = ws + off;
        off += (bytes + 255) & ~(size_t)255;
        return (void*)p;
    };
    float* bufA = (float*)alloc((size_t)NP * HD * 4);
    float* bufB = (float*)alloc((size_t)NP * HD * 4);
    float* qh   = (float*)alloc((size_t)NH * NP * DH * 4);
    float* kh   = (float*)alloc((size_t)NH * NP * DH * 4);
    float* vh   = (float*)alloc((size_t)NH * NP * DH * 4);
    float* aout = (float*)alloc((size_t)NP * 64 * 4);
    float* ql   = (float*)alloc((size_t)NH * NL * DH * 4);
    float* klm  = (float*)alloc((size_t)NH * NL * DH * 4);
    float* ybuf = (float*)alloc((size_t)NH * NL * DH * 4);
    float* ybuf2= (float*)alloc((size_t)NH * NL * DH * 4);
    float* zwb  = (float*)alloc((size_t)NH * NL * DH * 4);
    float* a2   = (float*)alloc((size_t)NH * NL * NL * 4);
    float* zb0  = (float*)alloc((size_t)NH * NL * NL * 4);   // z0 (kept for final)
    float* azb  = (float*)alloc((size_t)NH * NL * NL * 4);   // w ping
    float* tb   = (float*)alloc((size_t)NH * NL * NL * 4);   // w pong
    float* ub   = (float*)alloc((size_t)NH * NL * NL * 4);   // S = w@w
    float* part = (float*)alloc(256);
    float* a3p  = (float*)alloc((size_t)NH * A3NB * NL * 9 * 4);
    float* plan  = (float*)alloc((size_t)CCH * NPIX * 4);
    float* plan2 = (float*)alloc((size_t)CCH * NPIX * 4);
    float* wcomb = (float*)alloc((size_t)HD * 49 * 4);
    float* bsum  = (float*)alloc((size_t)HD * 4);
    short* wt1   = (short*)alloc((size_t)HD * ID * 2);
    short* wtq   = (short*)alloc((size_t)192 * HD * 2);
    short* xb    = (short*)alloc((size_t)NP * ID * 2);   // NP rows: fc1 A-tiles may read past NPIX
    short* xpB   = (short*)alloc((size_t)NP * HD * 2);
    (void)ws_size; (void)in_sizes; (void)n_in; (void)out_size;

    castX<<<(NPIX * ID / 8) / 256, 256, 0, stream>>>(x, xb);
    castT<<<dim3(HD / 32, ID / 32), 256, 0, stream>>>(fc1_w, wt1, ID, HD);
    gemm_fc1<<<dim3(4, 154), 256, 0, stream>>>(xb, wt1, fc1_b, bufA);
    cls_init<<<2, 256, 0, stream>>>(cls, bufA);

    auto attention = [&](float* hbuf, const float* lg, const float* lb,
                         const float* qkvw, const float* ow, const float* ob,
                         const float* rw) {
        ln_pad<<<NP, 256, 0, stream>>>(hbuf, lg, lb, xpB);
        castT<<<dim3(192 / 32, HD / 32), 256, 0, stream>>>(qkvw, wtq, HD, 192);
        gemm_qkv<<<dim3(3, 154), 256, 0, stream>>>(xpB, wtq, qh, kh, vh);
        landmarks<<<128, 256, 0, stream>>>(qh, kh, ql, klm);
        attn2_softmax<<<dim3(NL, NH), 256, 0, stream>>>(ql, klm, a2);
        pinv_norms<<<16, 256, 0, stream>>>(a2, part);
        z0_init<<<2048, 256, 0, stream>>>(a2, part, zb0);
        // y0 = attn3 @ v (single K/V pass + merge)
        attn3v<<<dim3(A3NB, NH), 256, 0, stream>>>(kh, vh, ql, a3p);
        attn3v_merge<<<NH, 256, 0, stream>>>(a3p, ybuf);
        // w-space Newton-Schulz, w0 = a@z0.
        // per iter: S=w@w; w' = 0.25*(13w-15S+7*S@w - S@S) [tu_mm];
        // y <- P_it @ y (P's commute: polynomials of shared w0) [yiter].
        mm256<<<dim3(8, 4, 8), 256, 0, stream>>>(a2, zb0, azb);
        float* wc = azb;
        float* wn = tb;
        float* yc = ybuf;
        float* yn = ybuf2;
        for (int it = 0; it < 6; ++it) {
            mm256<<<dim3(8, 4, 8), 256, 0, stream>>>(wc, wc, ub);       // S
            if (it < 5) tu_mm<<<dim3(8, 4, 8), 256, 0, stream>>>(ub, wc, wn);
            yiter<<<dim3(8, 8), 256, 0, stream>>>(wc, ub, yc, yn);
            { float* t = yc; yc = yn; yn = t; }
            if (it < 5) { float* t = wc; wc = wn; wn = t; }
        }
        // zw = 4^-6 * z0 @ y6
        polyv<<<dim3(8, NH), 256, 0, stream>>>(zb0, yc, zwb, 2.44140625e-4f);
        attn1_conv<<<dim3(154, NH), 256, 0, stream>>>(qh, vh, klm, zwb, rw, aout);
        outproj<<<(NT + 15) / 16, 512, 0, stream>>>(aout, ow, ob, hbuf);
    };

    attention(bufA, l1_g, l1_bb, l1_qkv, l1_ow, l1_ob, l1_rw);

    ppeg_wprep<<<(HD * 49 + HD + 255) / 256, 256, 0, stream>>>(p7w, p7b, p5w, p5b, p3w, p3b,
                                                               wcomb, bsum);
    copy512<<<1, 512, 0, stream>>>(bufA, bufB);
    constexpr int PTILES = (NPIX + 31) / 32;
    for (int ch0 = 0; ch0 < HD; ch0 += CCH) {
        ppeg_t1<<<dim3(PTILES, CCH / 32), 256, 0, stream>>>(bufA, plan, ch0);
        ppeg_conv<<<dim3(CCH, 4), 256, 0, stream>>>(plan, wcomb, plan2, ch0);
        ppeg_t2<<<dim3(PTILES, CCH / 32), 256, 0, stream>>>(plan2, bsum, bufB, ch0);
    }

    attention(bufB, l2_g, l2_bb, l2_qkv, l2_ow, l2_ob, l2_rw);
    final_ln<<<1, 256, 0, stream>>>(bufB, ng, nb, out);
}

// Round 4
// 1284.838 us; speedup vs baseline: 1.0833x; 1.0329x over previous
//
#include <hip/hip_runtime.h>

namespace {

constexpr int NP   = 19712;   // padded tokens (Nystrom)
constexpr int NT   = 19601;   // tokens incl cls
constexpr int NPIX = 19600;   // feature tokens (140x140)
constexpr int HD   = 512;     // hidden dim
constexpr int ID   = 1024;    // input dim
constexpr int NH   = 8;       // heads
constexpr int DH   = 8;       // dim per head
constexpr int NL   = 256;     // landmarks
constexpr int PADR = 111;     // left zero-pad rows
constexpr int SIDE = 140;
constexpr int CCH  = 128;     // ppeg channel chunk
constexpr int PW   = 148;     // padded image row stride (floats)
constexpr int A3CHK = 256;    // attn3v tokens per block
constexpr int A3NB  = NP / A3CHK;   // 77 chunks

typedef __attribute__((ext_vector_type(8))) short bf16x8;
typedef __attribute__((ext_vector_type(4))) float f32x4;

#define F4MAD(a, s, v) { (a).x += (s)*(v).x; (a).y += (s)*(v).y; (a).z += (s)*(v).z; (a).w += (s)*(v).w; }

// async global->LDS, 16B per lane; LDS dest must be wave-uniform base + lane*16
#define GLOAD16(gptr, lptr) \
    __builtin_amdgcn_global_load_lds((const __attribute__((address_space(1))) void*)(gptr), \
                                     (__attribute__((address_space(3))) void*)(lptr), 16, 0, 0)

__device__ inline short f2bf(float f) {
    union { float f; unsigned u; } v; v.f = f;
    unsigned r = v.u + 0x7fffu + ((v.u >> 16) & 1u);
    return (short)(r >> 16);
}

// ------------------------------------------------------------------
// cast X fp32 -> bf16 elementwise
// ------------------------------------------------------------------
__global__ void castX(const float* __restrict__ src, short* __restrict__ dst)
{
    size_t c = (size_t)blockIdx.x * 256 + threadIdx.x;
    const float4 x0 = *(const float4*)&src[c * 8];
    const float4 x1 = *(const float4*)&src[c * 8 + 4];
    bf16x8 p;
    p[0] = f2bf(x0.x); p[1] = f2bf(x0.y); p[2] = f2bf(x0.z); p[3] = f2bf(x0.w);
    p[4] = f2bf(x1.x); p[5] = f2bf(x1.y); p[6] = f2bf(x1.z); p[7] = f2bf(x1.w);
    *(bf16x8*)&dst[c * 8] = p;
}

// ------------------------------------------------------------------
// cast+transpose: dst[c][r] = bf16(src[r][c]); grid (C/32, R/32)
// ------------------------------------------------------------------
__global__ void castT(const float* __restrict__ src, short* __restrict__ dst, int R, int C)
{
    __shared__ float t[32][33];
    const int tx = threadIdx.x & 31, ty = threadIdx.x >> 5;
    const int c0 = blockIdx.x * 32, r0 = blockIdx.y * 32;
    #pragma unroll
    for (int j = 0; j < 4; ++j)
        t[ty + 8 * j][tx] = src[(size_t)(r0 + ty + 8 * j) * C + c0 + tx];
    __syncthreads();
    #pragma unroll
    for (int j = 0; j < 4; ++j)
        dst[(size_t)(c0 + ty + 8 * j) * R + r0 + tx] = f2bf(t[tx][ty + 8 * j]);
}

// ------------------------------------------------------------------
// fc1 MFMA: 128x128 tile, BK=32, 2-phase dbuf global_load_lds.
// XCD-aware remap: grid (8, 80); XCD = blockIdx.x (assumes wgid%8 RR);
// within an XCD the 4 col-blocks of one 128-row X panel are consecutive
// -> X panel served from that XCD's private L2 (FETCH ~2x -> ~1x).
// ------------------------------------------------------------------
__global__ __launch_bounds__(256) void gemm_fc1(const short* __restrict__ Xb,
                                                const short* __restrict__ Wt,
                                                const float* __restrict__ bias,
                                                float* __restrict__ out)
{
    const int rowblk = blockIdx.x + (blockIdx.y >> 2) * 8;
    if (rowblk >= 154) return;
    __shared__ __align__(16) short As[2][128 * 32];
    __shared__ __align__(16) short Bs[2][128 * 32];
    const int tid  = threadIdx.x;
    const int col0 = (blockIdx.y & 3) * 128;
    const int row0 = rowblk * 128;
    const int wave = tid >> 6, lane = tid & 63;
    const int quad = lane >> 4, l16 = lane & 15;
    const int m_base = (wave >> 1) * 64, n_base = (wave & 1) * 64;
    const int kch = (quad ^ ((l16 >> 1) & 3)) * 8;   // swizzled k-chunk (shorts)
    f32x4 acc[4][4] = {};

    int    aldo[2];
    size_t agoff[2], bgoff[2];
    #pragma unroll
    for (int i = 0; i < 2; ++i) {
        int slot = i * 256 + wave * 64 + lane;
        int row  = slot >> 2;
        int g    = (slot & 3) ^ ((slot >> 3) & 3);
        aldo[i]  = slot * 8;
        agoff[i] = (size_t)(row0 + row) * ID + g * 8;
        bgoff[i] = (size_t)(col0 + row) * ID + g * 8;
    }
    auto stage = [&](int b, int k0) {
        #pragma unroll
        for (int i = 0; i < 2; ++i) {
            GLOAD16(&Xb[agoff[i] + k0], &As[b][aldo[i]]);
            GLOAD16(&Wt[bgoff[i] + k0], &Bs[b][aldo[i]]);
        }
    };

    stage(0, 0);
    __syncthreads();
    #pragma unroll 1
    for (int t = 0; t < 32; ++t) {
        const int cur = t & 1;
        if (t < 31) stage(cur ^ 1, (t + 1) * 32);
        bf16x8 af[4], bfr[4];
        #pragma unroll
        for (int i = 0; i < 4; ++i) {
            af[i]  = *(const bf16x8*)&As[cur][(m_base + i * 16 + l16) * 32 + kch];
            bfr[i] = *(const bf16x8*)&Bs[cur][(n_base + i * 16 + l16) * 32 + kch];
        }
        #pragma unroll
        for (int mi = 0; mi < 4; ++mi)
            #pragma unroll
            for (int ni = 0; ni < 4; ++ni)
                acc[mi][ni] = __builtin_amdgcn_mfma_f32_16x16x32_bf16(af[mi], bfr[ni], acc[mi][ni], 0, 0, 0);
        __syncthreads();
    }
    #pragma unroll
    for (int mi = 0; mi < 4; ++mi) {
        #pragma unroll
        for (int r = 0; r < 4; ++r) {
            int gr = row0 + m_base + mi * 16 + quad * 4 + r;
            if (gr >= NPIX) continue;
            #pragma unroll
            for (int ni = 0; ni < 4; ++ni) {
                int gc = col0 + n_base + ni * 16 + l16;
                float v = acc[mi][ni][r] + bias[gc];
                v = 0.5f * v * (1.f + erff(v * 0.70710678118654752f));
                out[(size_t)(gr + 1) * HD + gc] = v;
            }
        }
    }
}

// ------------------------------------------------------------------
// qkv MFMA: 128x64 tile, BK=32, same 2-phase dbuf + fixed swizzle.
// grid (3 colblocks, 154 rowblocks)
// ------------------------------------------------------------------
__global__ __launch_bounds__(256) void gemm_qkv(const short* __restrict__ xpB,
                                                const short* __restrict__ Wt,
                                                float* __restrict__ qh,
                                                float* __restrict__ kh,
                                                float* __restrict__ vh)
{
    __shared__ __align__(16) short As[2][128 * 32];
    __shared__ __align__(16) short Bs[2][64 * 32];
    const int tid  = threadIdx.x;
    const int col0 = blockIdx.x * 64;
    const int row0 = blockIdx.y * 128;
    const int wave = tid >> 6, lane = tid & 63;
    const int quad = lane >> 4, l16 = lane & 15;
    const int m_base = (wave >> 1) * 64, n_base = (wave & 1) * 32;
    const int kch = (quad ^ ((l16 >> 1) & 3)) * 8;
    f32x4 acc[4][2] = {};

    int    aldo[2];
    size_t agoff[2];
    #pragma unroll
    for (int i = 0; i < 2; ++i) {
        int slot = i * 256 + wave * 64 + lane;
        int row  = slot >> 2;
        int g    = (slot & 3) ^ ((slot >> 3) & 3);
        aldo[i]  = slot * 8;
        agoff[i] = (size_t)(row0 + row) * HD + g * 8;
    }
    int bldo; size_t bgoff;
    {
        int slot = wave * 64 + lane;
        int row  = slot >> 2;
        int g    = (slot & 3) ^ ((slot >> 3) & 3);
        bldo  = slot * 8;
        bgoff = (size_t)(col0 + row) * HD + g * 8;
    }
    auto stage = [&](int b, int k0) {
        #pragma unroll
        for (int i = 0; i < 2; ++i)
            GLOAD16(&xpB[agoff[i] + k0], &As[b][aldo[i]]);
        GLOAD16(&Wt[bgoff + k0], &Bs[b][bldo]);
    };

    stage(0, 0);
    __syncthreads();
    #pragma unroll 1
    for (int t = 0; t < 16; ++t) {
        const int cur = t & 1;
        if (t < 15) stage(cur ^ 1, (t + 1) * 32);
        bf16x8 af[4], bfr[2];
        #pragma unroll
        for (int i = 0; i < 4; ++i)
            af[i] = *(const bf16x8*)&As[cur][(m_base + i * 16 + l16) * 32 + kch];
        #pragma unroll
        for (int i = 0; i < 2; ++i)
            bfr[i] = *(const bf16x8*)&Bs[cur][(n_base + i * 16 + l16) * 32 + kch];
        #pragma unroll
        for (int mi = 0; mi < 4; ++mi)
            #pragma unroll
            for (int ni = 0; ni < 2; ++ni)
                acc[mi][ni] = __builtin_amdgcn_mfma_f32_16x16x32_bf16(af[mi], bfr[ni], acc[mi][ni], 0, 0, 0);
        __syncthreads();
    }
    const int which = blockIdx.x;
    float* dst = (which == 0) ? qh : (which == 1) ? kh : vh;
    const float scale = (which == 0) ? 0.35355339059327373f : 1.f;
    #pragma unroll
    for (int mi = 0; mi < 4; ++mi) {
        #pragma unroll
        for (int r = 0; r < 4; ++r) {
            int gr = row0 + m_base + mi * 16 + quad * 4 + r;
            #pragma unroll
            for (int ni = 0; ni < 2; ++ni) {
                int n = n_base + ni * 16 + l16;
                int hh = n >> 3, d = n & 7;
                dst[((size_t)hh * NP + gr) * DH + d] = acc[mi][ni][r] * scale;
            }
        }
    }
}

__global__ void cls_init(const float* __restrict__ cls, float* __restrict__ h)
{
    int t = blockIdx.x * 256 + threadIdx.x;
    if (t < HD) h[t] = cls[t];
}

__global__ void copy512(const float* __restrict__ src, float* __restrict__ dst)
{
    dst[threadIdx.x] = src[threadIdx.x];
}

// ------------------------------------------------------------------
// layernorm rows of h into xp (bf16): wave-per-row, shfl reduce.
// grid NP/4, 256 threads (4 waves = 4 rows)
// ------------------------------------------------------------------
__global__ __launch_bounds__(256) void ln_pad(const float* __restrict__ h,
                                              const float* __restrict__ g,
                                              const float* __restrict__ b,
                                              short* __restrict__ xp)
{
    const int wave = threadIdx.x >> 6, lane = threadIdx.x & 63;
    const int row = blockIdx.x * 4 + wave;
    short* dst = xp + (size_t)row * HD + lane * 8;
    if (row < PADR) {
        bf16x8 z = {};
        *(bf16x8*)dst = z;
        return;
    }
    const float* src = h + (size_t)(row - PADR) * HD + lane * 8;
    float4 v0 = *(const float4*)src;
    float4 v1 = *(const float4*)(src + 4);
    float v[8] = {v0.x, v0.y, v0.z, v0.w, v1.x, v1.y, v1.z, v1.w};
    float s = 0.f;
    #pragma unroll
    for (int i = 0; i < 8; ++i) s += v[i];
    #pragma unroll
    for (int o = 1; o < 64; o <<= 1) s += __shfl_xor(s, o);
    float mu = s * (1.f / HD);
    float ss = 0.f;
    #pragma unroll
    for (int i = 0; i < 8; ++i) { float d = v[i] - mu; ss += d * d; }
    #pragma unroll
    for (int o = 1; o < 64; o <<= 1) ss += __shfl_xor(ss, o);
    float inv = rsqrtf(ss * (1.f / HD) + 1e-5f);
    float4 g0 = *(const float4*)&g[lane * 8];
    float4 g1 = *(const float4*)&g[lane * 8 + 4];
    float4 b0 = *(const float4*)&b[lane * 8];
    float4 b1 = *(const float4*)&b[lane * 8 + 4];
    float gg[8] = {g0.x, g0.y, g0.z, g0.w, g1.x, g1.y, g1.z, g1.w};
    float bb[8] = {b0.x, b0.y, b0.z, b0.w, b1.x, b1.y, b1.z, b1.w};
    bf16x8 o;
    #pragma unroll
    for (int i = 0; i < 8; ++i) o[i] = f2bf((v[i] - mu) * inv * gg[i] + bb[i]);
    *(bf16x8*)dst = o;
}

// ------------------------------------------------------------------
// landmark means
// ------------------------------------------------------------------
__global__ void landmarks(const float* __restrict__ qh, const float* __restrict__ kh,
                          float* __restrict__ ql, float* __restrict__ kl)
{
    int idx = blockIdx.x * 256 + threadIdx.x;
    int sel = idx >> 14;
    int rem = idx & 16383;
    int h = rem >> 11;
    int i = (rem >> 3) & 255;
    int d = rem & 7;
    const float* src = sel ? kh : qh;
    size_t base = ((size_t)h * NP + (size_t)i * 77) * DH + d;
    float s = 0.f;
    for (int j = 0; j < 77; ++j) s += src[base + (size_t)j * DH];
    (sel ? kl : ql)[((size_t)h * NL + i) * DH + d] = s * (1.f / 77.f);
}

// ------------------------------------------------------------------
// attn2 = softmax(q_l @ k_l^T); scores are O(1) -> no max subtraction
// ------------------------------------------------------------------
__global__ void attn2_softmax(const float* __restrict__ ql, const float* __restrict__ kl,
                              float* __restrict__ a)
{
    const int i = blockIdx.x, h = blockIdx.y, j = threadIdx.x;
    __shared__ float sq[8];
    __shared__ float red[256];
    if (j < 8) sq[j] = ql[((size_t)h * NL + i) * DH + j];
    __syncthreads();
    const float* kr = kl + ((size_t)h * NL + j) * DH;
    float s = 0.f;
    #pragma unroll
    for (int d = 0; d < 8; ++d) s += sq[d] * kr[d];
    float e = __expf(s);
    red[j] = e;
    __syncthreads();
    for (int off = 128; off > 0; off >>= 1) {
        if (j < off) red[j] += red[j + off];
        __syncthreads();
    }
    a[((size_t)h * NL + i) * NL + j] = e / red[0];
}

// ------------------------------------------------------------------
// pinv init
// ------------------------------------------------------------------
__global__ void pinv_norms(const float* __restrict__ a, float* __restrict__ part)
{
    const int h = blockIdx.x & 7;
    const int mode = blockIdx.x >> 3;
    const int tid = threadIdx.x;
    const float* ah = a + (size_t)h * NL * NL;
    float s = 0.f;
    if (mode == 0) { for (int j = 0; j < NL; ++j) s += fabsf(ah[tid * NL + j]); }
    else           { for (int i = 0; i < NL; ++i) s += fabsf(ah[i * NL + tid]); }
    __shared__ float red[256];
    red[tid] = s;
    __syncthreads();
    for (int off = 128; off > 0; off >>= 1) {
        if (tid < off) red[tid] = fmaxf(red[tid], red[tid + off]);
        __syncthreads();
    }
    if (tid == 0) part[mode * 8 + h] = red[0];
}

__global__ void z0_init(const float* __restrict__ a, const float* __restrict__ part,
                        float* __restrict__ z)
{
    float s1 = part[0], s2 = part[8];
    #pragma unroll
    for (int h = 1; h < 8; ++h) { s1 = fmaxf(s1, part[h]); s2 = fmaxf(s2, part[8 + h]); }
    float inv = 1.f / (s1 * s2);
    int idx = blockIdx.x * 256 + threadIdx.x;
    int h = idx >> 16;
    int rem = idx & 65535;
    int i = rem >> 8, j = rem & 255;
    z[idx] = a[((size_t)h * NL + j) * NL + i] * inv;
}

// ------------------------------------------------------------------
// batched 256x256x256: D = A@B   grid (8,4,8)
// ------------------------------------------------------------------
__global__ void mm256(const float* __restrict__ A, const float* __restrict__ B,
                      float* __restrict__ D)
{
    const int h = blockIdx.z;
    const float* Ah = A + (size_t)h * NL * NL;
    const float* Bh = B + (size_t)h * NL * NL;
    float* Dh = D + (size_t)h * NL * NL;
    __shared__ __align__(16) float As[16][36];
    __shared__ __align__(16) float Bs[16][68];
    const int tid = threadIdx.x;
    const int tx = tid & 15, ty = tid >> 4;
    const int row0 = blockIdx.x * 32;
    const int col0 = blockIdx.y * 64;
    float acc[2][4] = {};
    const int ar = tid >> 3;
    const int ak = (tid & 7) * 2;
    const int bk = tid >> 4;
    const int bj = (tid & 15) * 4;
    for (int k0 = 0; k0 < NL; k0 += 16) {
        float2 av = *(const float2*)&Ah[(size_t)(row0 + ar) * NL + k0 + ak];
        As[ak][ar] = av.x; As[ak + 1][ar] = av.y;
        *(float4*)&Bs[bk][bj] = *(const float4*)&Bh[(size_t)(k0 + bk) * NL + col0 + bj];
        __syncthreads();
        #pragma unroll
        for (int k = 0; k < 16; ++k) {
            float2 a = *(const float2*)&As[k][ty * 2];
            float4 b = *(const float4*)&Bs[k][tx * 4];
            acc[0][0] += a.x * b.x; acc[0][1] += a.x * b.y; acc[0][2] += a.x * b.z; acc[0][3] += a.x * b.w;
            acc[1][0] += a.y * b.x; acc[1][1] += a.y * b.y; acc[1][2] += a.y * b.z; acc[1][3] += a.y * b.w;
        }
        __syncthreads();
    }
    #pragma unroll
    for (int r = 0; r < 2; ++r) {
        int gr = row0 + ty * 2 + r;
        #pragma unroll
        for (int c = 0; c < 4; ++c)
            Dh[(size_t)gr * NL + col0 + tx * 4 + c] = acc[r][c];
    }
}

// ------------------------------------------------------------------
// fused T=S@w, U=S@S, w' = 0.25*(13w - 15S + 7T - U)   grid (8,4,8)
// ------------------------------------------------------------------
__global__ void tu_mm(const float* __restrict__ S, const float* __restrict__ w,
                      float* __restrict__ wn)
{
    const int h = blockIdx.z;
    const float* Sh = S + (size_t)h * NL * NL;
    const float* wh = w + (size_t)h * NL * NL;
    float* Dh = wn + (size_t)h * NL * NL;
    __shared__ __align__(16) float As[16][36];
    __shared__ __align__(16) float Bw[16][68];
    __shared__ __align__(16) float Bu[16][68];
    const int tid = threadIdx.x;
    const int tx = tid & 15, ty = tid >> 4;
    const int row0 = blockIdx.x * 32;
    const int col0 = blockIdx.y * 64;
    float aT[2][4] = {}, aU[2][4] = {};
    const int ar = tid >> 3;
    const int ak = (tid & 7) * 2;
    const int bk = tid >> 4;
    const int bj = (tid & 15) * 4;
    for (int k0 = 0; k0 < NL; k0 += 16) {
        float2 av = *(const float2*)&Sh[(size_t)(row0 + ar) * NL + k0 + ak];
        As[ak][ar] = av.x; As[ak + 1][ar] = av.y;
        *(float4*)&Bw[bk][bj] = *(const float4*)&wh[(size_t)(k0 + bk) * NL + col0 + bj];
        *(float4*)&Bu[bk][bj] = *(const float4*)&Sh[(size_t)(k0 + bk) * NL + col0 + bj];
        __syncthreads();
        #pragma unroll
        for (int k = 0; k < 16; ++k) {
            float2 a = *(const float2*)&As[k][ty * 2];
            float4 b1 = *(const float4*)&Bw[k][tx * 4];
            float4 b2 = *(const float4*)&Bu[k][tx * 4];
            aT[0][0] += a.x * b1.x; aT[0][1] += a.x * b1.y; aT[0][2] += a.x * b1.z; aT[0][3] += a.x * b1.w;
            aT[1][0] += a.y * b1.x; aT[1][1] += a.y * b1.y; aT[1][2] += a.y * b1.z; aT[1][3] += a.y * b1.w;
            aU[0][0] += a.x * b2.x; aU[0][1] += a.x * b2.y; aU[0][2] += a.x * b2.z; aU[0][3] += a.x * b2.w;
            aU[1][0] += a.y * b2.x; aU[1][1] += a.y * b2.y; aU[1][2] += a.y * b2.z; aU[1][3] += a.y * b2.w;
        }
        __syncthreads();
    }
    #pragma unroll
    for (int r = 0; r < 2; ++r) {
        int gr = row0 + ty * 2 + r;
        #pragma unroll
        for (int c = 0; c < 4; ++c) {
            int gc = col0 + tx * 4 + c;
            size_t o = (size_t)gr * NL + gc;
            Dh[o] = 0.25f * (13.f * wh[o] - 15.f * Sh[o] + 7.f * aT[r][c] - aU[r][c]);
        }
    }
}

// ------------------------------------------------------------------
// y' = P(w)y = 13y - 15*t1 + S@(7y - t1), t1 = w@y.
// grid (8 slices, 8 heads): phase A computes full t1 (redundant per slice,
// 64-block parallelism); phase B does the block's 32-row slice.
// ------------------------------------------------------------------
__global__ __launch_bounds__(256) void yiter(const float* __restrict__ w,
                                             const float* __restrict__ S,
                                             const float* __restrict__ yin,
                                             float* __restrict__ yout)
{
    const int s = blockIdx.x, h = blockIdx.y, tid = threadIdx.x;
    __shared__ float yL[NL * 9];
    __shared__ float tL[NL * 9];
    __shared__ float uL[NL * 9];
    const float* yh = yin + (size_t)h * NL * DH;
    #pragma unroll
    for (int i = 0; i < 8; ++i) {
        int idx = tid + 256 * i;
        yL[(idx >> 3) * 9 + (idx & 7)] = yh[idx];
    }
    __syncthreads();
    const float* wr = w + ((size_t)h * NL + tid) * NL;
    float t1[8] = {};
    for (int j = 0; j < NL; j += 4) {
        float4 wv = *(const float4*)&wr[j];
        #pragma unroll
        for (int d = 0; d < 8; ++d)
            t1[d] += wv.x * yL[j * 9 + d] + wv.y * yL[(j + 1) * 9 + d]
                   + wv.z * yL[(j + 2) * 9 + d] + wv.w * yL[(j + 3) * 9 + d];
    }
    #pragma unroll
    for (int d = 0; d < 8; ++d) {
        tL[tid * 9 + d] = t1[d];
        uL[tid * 9 + d] = 7.f * yL[tid * 9 + d] - t1[d];
    }
    __syncthreads();
    const int r = s * 32 + (tid >> 3), d = tid & 7;
    const float* Sr = S + ((size_t)h * NL + r) * NL;
    float acc = 13.f * yL[r * 9 + d] - 15.f * tL[r * 9 + d];
    for (int j = 0; j < NL; j += 4) {
        float4 sv = *(const float4*)&Sr[j];
        acc += sv.x * uL[j * 9 + d] + sv.y * uL[(j + 1) * 9 + d]
             + sv.z * uL[(j + 2) * 9 + d] + sv.w * uL[(j + 3) * 9 + d];
    }
    yout[((size_t)h * NL + r) * DH + d] = acc;
}

// ------------------------------------------------------------------
// vout[h] = scale * M[h] @ vin[h];  M: [8][256][256], v: [8][256][8]
// ------------------------------------------------------------------
__global__ void polyv(const float* __restrict__ M, const float* __restrict__ vin,
                      float* __restrict__ vout, float scale)
{
    const int h = blockIdx.y;
    __shared__ float vs[NL * DH];
    const int tid = threadIdx.x;
    const float* vh = vin + (size_t)h * NL * DH;
    #pragma unroll
    for (int i = 0; i < 8; ++i) vs[tid + 256 * i] = vh[tid + 256 * i];
    __syncthreads();
    const int row = blockIdx.x * 32 + (tid >> 3);
    const int d = tid & 7;
    const float* Mr = M + ((size_t)h * NL + row) * NL;
    float acc = 0.f;
    #pragma unroll 4
    for (int j = 0; j < NL; j += 4) {
        float4 m = *(const float4*)&Mr[j];
        acc += m.x * vs[j * 8 + d]      + m.y * vs[j * 8 + 8 + d]
             + m.z * vs[j * 8 + 16 + d] + m.w * vs[j * 8 + 24 + d];
    }
    vout[((size_t)h * NL + row) * DH + d] = acc * scale;
}

// ------------------------------------------------------------------
// attn3 @ v, single K/V pass: grid (77 chunks, 8 heads).
// ------------------------------------------------------------------
__global__ __launch_bounds__(256) void attn3v(const float* __restrict__ kh,
                                              const float* __restrict__ vh,
                                              const float* __restrict__ ql,
                                              float* __restrict__ part)
{
    const int ck = blockIdx.x, h = blockIdx.y, tid = threadIdx.x;
    __shared__ __align__(16) float4 kv[A3CHK][4];   // [t]: k0 k1 v0 v1
    const float* kb = kh + ((size_t)h * NP + (size_t)ck * A3CHK) * DH;
    const float* vb = vh + ((size_t)h * NP + (size_t)ck * A3CHK) * DH;
    #pragma unroll
    for (int i = 0; i < 2; ++i) {
        int idx = tid + 256 * i;          // 0..511
        int t = idx >> 1, p = idx & 1;
        kv[t][p]     = *(const float4*)&kb[t * 8 + p * 4];
        kv[t][2 + p] = *(const float4*)&vb[t * 8 + p * 4];
    }
    float q[8];
    const float* qp = ql + ((size_t)h * NL + tid) * DH;
    #pragma unroll
    for (int d = 0; d < 8; ++d) q[d] = qp[d];
    __syncthreads();
    float den = 0.f;
    float4 a0 = make_float4(0.f, 0.f, 0.f, 0.f);
    float4 a1 = make_float4(0.f, 0.f, 0.f, 0.f);
    #pragma unroll 4
    for (int t = 0; t < A3CHK; ++t) {
        float4 k0 = kv[t][0], k1 = kv[t][1];
        float s = q[0] * k0.x + q[1] * k0.y + q[2] * k0.z + q[3] * k0.w
                + q[4] * k1.x + q[5] * k1.y + q[6] * k1.z + q[7] * k1.w;
        float e = __expf(s);
        den += e;
        float4 v0 = kv[t][2], v1 = kv[t][3];
        F4MAD(a0, e, v0); F4MAD(a1, e, v1);
    }
    float* p = part + (((size_t)h * A3NB + ck) * NL + tid) * 9;
    p[0] = den;
    p[1] = a0.x; p[2] = a0.y; p[3] = a0.z; p[4] = a0.w;
    p[5] = a1.x; p[6] = a1.y; p[7] = a1.z; p[8] = a1.w;
}

// merge 77 chunks -> y0[h][i][d]; grid 8 (heads), thread = landmark
__global__ void attn3v_merge(const float* __restrict__ part, float* __restrict__ y)
{
    const int h = blockIdx.x, i = threadIdx.x;
    float den = 0.f;
    float acc[8] = {};
    for (int ck = 0; ck < A3NB; ++ck) {
        const float* p = part + (((size_t)h * A3NB + ck) * NL + i) * 9;
        den += p[0];
        #pragma unroll
        for (int d = 0; d < 8; ++d) acc[d] += p[1 + d];
    }
    float inv = 1.f / den;
    #pragma unroll
    for (int d = 0; d < 8; ++d) y[((size_t)h * NL + i) * DH + d] = acc[d] * inv;
}

// ------------------------------------------------------------------
// attn1 fused + dwconv33(v): 1 lane = 1 token; kl/zw broadcast from LDS
// (wave-uniform addr -> conflict-free). grid (77, 8), 256 threads.
// ------------------------------------------------------------------
__global__ __launch_bounds__(256) void attn1_conv(const float* __restrict__ qh,
                                                  const float* __restrict__ vh,
                                                  const float* __restrict__ klg,
                                                  const float* __restrict__ zwg,
                                                  const float* __restrict__ rw,
                                                  float* __restrict__ aout)
{
    const int h = blockIdx.y;
    __shared__ __align__(16) float kl[NL * DH];
    __shared__ __align__(16) float zw[NL * DH];
    const int tid = threadIdx.x;
    #pragma unroll
    for (int q = 0; q < 8; ++q) {
        kl[tid + 256 * q] = klg[(size_t)h * NL * DH + tid + 256 * q];
        zw[tid + 256 * q] = zwg[(size_t)h * NL * DH + tid + 256 * q];
    }
    __syncthreads();
    const int r = blockIdx.x * 256 + tid;
    if (r >= NT) return;
    const int t = r + PADR;
    const float* qp = qh + ((size_t)h * NP + t) * DH;
    float4 q0 = *(const float4*)qp;
    float4 q1 = *(const float4*)(qp + 4);
    float den = 0.f;
    float4 acc0 = make_float4(0.f, 0.f, 0.f, 0.f);
    float4 acc1 = make_float4(0.f, 0.f, 0.f, 0.f);
    #pragma unroll 4
    for (int i = 0; i < NL; ++i) {
        float4 k0 = *(const float4*)&kl[i * 8];
        float4 k1 = *(const float4*)&kl[i * 8 + 4];
        float s = q0.x * k0.x + q0.y * k0.y + q0.z * k0.z + q0.w * k0.w
                + q1.x * k1.x + q1.y * k1.y + q1.z * k1.z + q1.w * k1.w;
        float e = __expf(s);
        den += e;
        float4 z0 = *(const float4*)&zw[i * 8];
        float4 z1 = *(const float4*)&zw[i * 8 + 4];
        F4MAD(acc0, e, z0); F4MAD(acc1, e, z1);
    }
    float inv = 1.f / den;
    const float* vb = vh + (size_t)h * NP * DH;
    float4 c0 = make_float4(0.f, 0.f, 0.f, 0.f);
    float4 c1 = make_float4(0.f, 0.f, 0.f, 0.f);
    #pragma unroll
    for (int j = 0; j < 33; ++j) {
        int tp = t - 16 + j;
        if (tp >= NP) continue;
        float wv = rw[h * 33 + j];
        float4 v0 = *(const float4*)&vb[(size_t)tp * 8];
        float4 v1 = *(const float4*)&vb[(size_t)tp * 8 + 4];
        F4MAD(c0, wv, v0); F4MAD(c1, wv, v1);
    }
    float* op = aout + (size_t)r * 64 + h * 8;
    *(float4*)op = make_float4(acc0.x * inv + c0.x, acc0.y * inv + c0.y,
                               acc0.z * inv + c0.z, acc0.w * inv + c0.w);
    *(float4*)(op + 4) = make_float4(acc1.x * inv + c1.x, acc1.y * inv + c1.y,
                                     acc1.z * inv + c1.z, acc1.w * inv + c1.w);
}

// ------------------------------------------------------------------
// out-proj + residual: 16 rows/block
// ------------------------------------------------------------------
__global__ void outproj(const float* __restrict__ aout, const float* __restrict__ W,
                        const float* __restrict__ bias, float* __restrict__ h)
{
    const int r0 = blockIdx.x * 16;
    const int tid = threadIdx.x;   // 512
    __shared__ float ao[16][64];
    #pragma unroll
    for (int s = 0; s < 2; ++s) {
        int idx = tid + s * 512;
        int rr = idx >> 6, kk = idx & 63;
        int gr = r0 + rr;
        ao[rr][kk] = (gr < NT) ? aout[(size_t)gr * 64 + kk] : 0.f;
    }
    __syncthreads();
    float acc[16] = {};
    for (int k = 0; k < 64; ++k) {
        float wv = W[(size_t)k * HD + tid];
        #pragma unroll
        for (int r = 0; r < 16; ++r) acc[r] += ao[r][k] * wv;
    }
    float bv = bias[tid];
    #pragma unroll
    for (int r = 0; r < 16; ++r) {
        int gr = r0 + r;
        if (gr < NT) h[(size_t)gr * HD + tid] += acc[r] + bv;
    }
}

// ------------------------------------------------------------------
// PPEG
// ------------------------------------------------------------------
__global__ void ppeg_wprep(const float* __restrict__ w7, const float* __restrict__ b7,
                           const float* __restrict__ w5, const float* __restrict__ b5,
                           const float* __restrict__ w3, const float* __restrict__ b3,
                           float* __restrict__ wc, float* __restrict__ bsum)
{
    int idx = blockIdx.x * 256 + threadIdx.x;
    if (idx < HD * 49) {
        int c = idx / 49, t = idx - c * 49;
        int dy = t / 7 - 3, dx = t % 7 - 3;
        float v = w7[idx];
        if (dy >= -2 && dy <= 2 && dx >= -2 && dx <= 2) v += w5[c * 25 + (dy + 2) * 5 + (dx + 2)];
        if (dy >= -1 && dy <= 1 && dx >= -1 && dx <= 1) v += w3[c * 9 + (dy + 1) * 3 + (dx + 1)];
        if (t == 24) v += 1.f;
        wc[idx] = v;
    } else if (idx < HD * 49 + HD) {
        int c = idx - HD * 49;
        bsum[c] = b7[c] + b5[c] + b3[c];
    }
}

__global__ void ppeg_t1(const float* __restrict__ hin, float* __restrict__ plan, int ch0)
{
    __shared__ float tile[32][33];
    const int tx = threadIdx.x & 31, ty = threadIdx.x >> 5;
    const int p0 = blockIdx.x * 32;
    const int c0 = ch0 + blockIdx.y * 32;
    #pragma unroll
    for (int j = 0; j < 4; ++j) {
        int p = p0 + ty + j * 8;
        tile[ty + j * 8][tx] = (p < NPIX) ? hin[(size_t)(1 + p) * HD + c0 + tx] : 0.f;
    }
    __syncthreads();
    #pragma unroll
    for (int j = 0; j < 4; ++j) {
        int p = p0 + tx;
        int cc = ty + j * 8;
        if (p < NPIX) plan[(size_t)(blockIdx.y * 32 + cc) * NPIX + p] = tile[tx][cc];
    }
}

__global__ __launch_bounds__(256) void ppeg_conv(const float* __restrict__ plan,
                                                 const float* __restrict__ wc,
                                                 float* __restrict__ plan2, int ch0)
{
    __shared__ __align__(16) float img[41 * PW];
    const int tid = threadIdx.x;
    const int cl = blockIdx.x;
    const int yq = blockIdx.y;
    for (int i = tid; i < 41 * PW; i += 256) img[i] = 0.f;
    __syncthreads();
    const float* src = plan + (size_t)cl * NPIX;
    for (int i = tid; i < 41 * SIDE; i += 256) {
        int ly = i / SIDE, x = i - ly * SIDE;
        int y = yq * 35 - 3 + ly;
        if (y >= 0 && y < SIDE) img[ly * PW + x + 3] = src[y * SIDE + x];
    }
    const float* w = wc + (size_t)(ch0 + cl) * 49;
    float wr[49];
    #pragma unroll
    for (int t = 0; t < 49; ++t) wr[t] = w[t];
    __syncthreads();
    float* dst = plan2 + (size_t)cl * NPIX;
    for (int g = tid; g < 35 * 35; g += 256) {
        int yl = g / 35, x0 = (g - yl * 35) * 4;
        float acc0 = 0.f, acc1 = 0.f, acc2 = 0.f, acc3 = 0.f;
        #pragma unroll
        for (int a = 0; a < 7; ++a) {
            const float* row = &img[(yl + a) * PW + x0];
            float4 A = *(const float4*)(row);
            float4 B = *(const float4*)(row + 4);
            float4 C = *(const float4*)(row + 8);
            float e0 = A.x, e1 = A.y, e2 = A.z, e3 = A.w;
            float e4 = B.x, e5 = B.y, e6 = B.z, e7 = B.w;
            float e8 = C.x, e9 = C.y;
            const float w0 = wr[a*7+0], w1 = wr[a*7+1], w2 = wr[a*7+2], w3v = wr[a*7+3];
            const float w4 = wr[a*7+4], w5v = wr[a*7+5], w6 = wr[a*7+6];
            acc0 += w0*e0 + w1*e1 + w2*e2 + w3v*e3 + w4*e4 + w5v*e5 + w6*e6;
            acc1 += w0*e1 + w1*e2 + w2*e3 + w3v*e4 + w4*e5 + w5v*e6 + w6*e7;
            acc2 += w0*e2 + w1*e3 + w2*e4 + w3v*e5 + w4*e6 + w5v*e7 + w6*e8;
            acc3 += w0*e3 + w1*e4 + w2*e5 + w3v*e6 + w4*e7 + w5v*e8 + w6*e9;
        }
        *(float4*)&dst[(yq * 35 + yl) * SIDE + x0] = make_float4(acc0, acc1, acc2, acc3);
    }
}

__global__ void ppeg_t2(const float* __restrict__ plan2, const float* __restrict__ bsum,
                        float* __restrict__ hout, int ch0)
{
    __shared__ float tile[32][33];
    const int tx = threadIdx.x & 31, ty = threadIdx.x >> 5;
    const int p0 = blockIdx.x * 32;
    #pragma unroll
    for (int j = 0; j < 4; ++j) {
        int p = p0 + tx;
        int cc = ty + j * 8;
        tile[tx][cc] = (p < NPIX) ? plan2[(size_t)(blockIdx.y * 32 + cc) * NPIX + p] : 0.f;
    }
    __syncthreads();
    const int c0 = ch0 + blockIdx.y * 32;
    float bv = bsum[c0 + tx];
    #pragma unroll
    for (int j = 0; j < 4; ++j) {
        int p = p0 + ty + j * 8;
        if (p < NPIX) hout[(size_t)(1 + p) * HD + c0 + tx] = tile[ty + j * 8][tx] + bv;
    }
}

// ------------------------------------------------------------------
// final layernorm of row 0
// ------------------------------------------------------------------
__global__ void final_ln(const float* __restrict__ h, const float* __restrict__ g,
                         const float* __restrict__ b, float* __restrict__ out)
{
    const int tid = threadIdx.x;
    float v0 = h[tid], v1 = h[tid + 256];
    __shared__ float red[256];
    red[tid] = v0 + v1;
    __syncthreads();
    for (int off = 128; off > 0; off >>= 1) {
        if (tid < off) red[tid] += red[tid + off];
        __syncthreads();
    }
    float mu = red[0] * (1.f / HD);
    __syncthreads();
    float d0 = v0 - mu, d1 = v1 - mu;
    red[tid] = d0 * d0 + d1 * d1;
    __syncthreads();
    for (int off = 128; off > 0; off >>= 1) {
        if (tid < off) red[tid] += red[tid + off];
        __syncthreads();
    }
    float inv = rsqrtf(red[0] * (1.f / HD) + 1e-5f);
    out[tid]       = d0 * inv * g[tid] + b[tid];
    out[tid + 256] = d1 * inv * g[tid + 256] + b[tid + 256];
}

} // namespace

extern "C" void kernel_launch(void* const* d_in, const int* in_sizes, int n_in,
                              void* d_out, int out_size, void* d_ws, size_t ws_size,
                              hipStream_t stream)
{
    const float* x      = (const float*)d_in[0];
    const float* fc1_w  = (const float*)d_in[1];
    const float* fc1_b  = (const float*)d_in[2];
    const float* cls    = (const float*)d_in[3];
    const float* l1_g   = (const float*)d_in[4];
    const float* l1_bb  = (const float*)d_in[5];
    const float* l1_qkv = (const float*)d_in[6];
    const float* l1_ow  = (const float*)d_in[7];
    const float* l1_ob  = (const float*)d_in[8];
    const float* l1_rw  = (const float*)d_in[9];
    const float* l2_g   = (const float*)d_in[10];
    const float* l2_bb  = (const float*)d_in[11];
    const float* l2_qkv = (const float*)d_in[12];
    const float* l2_ow  = (const float*)d_in[13];
    const float* l2_ob  = (const float*)d_in[14];
    const float* l2_rw  = (const float*)d_in[15];
    const float* p7w    = (const float*)d_in[16];
    const float* p7b    = (const float*)d_in[17];
    const float* p5w    = (const float*)d_in[18];
    const float* p5b    = (const float*)d_in[19];
    const float* p3w    = (const float*)d_in[20];
    const float* p3b    = (const float*)d_in[21];
    const float* ng     = (const float*)d_in[22];
    const float* nb     = (const float*)d_in[23];
    float* out = (float*)d_out;

    char* ws = (char*)d_ws;
    size_t off = 0;
    auto alloc = [&](size_t bytes) {
        char* p = ws + off;
        off += (bytes + 255) & ~(size_t)255;
        return (void*)p;
    };
    float* bufA = (float*)alloc((size_t)NP * HD * 4);
    float* bufB = (float*)alloc((size_t)NP * HD * 4);
    float* qh   = (float*)alloc((size_t)NH * NP * DH * 4);
    float* kh   = (float*)alloc((size_t)NH * NP * DH * 4);
    float* vh   = (float*)alloc((size_t)NH * NP * DH * 4);
    float* aout = (float*)alloc((size_t)NP * 64 * 4);
    float* ql   = (float*)alloc((size_t)NH * NL * DH * 4);
    float* klm  = (float*)alloc((size_t)NH * NL * DH * 4);
    float* ybuf = (float*)alloc((size_t)NH * NL * DH * 4);
    float* ybuf2= (float*)alloc((size_t)NH * NL * DH * 4);
    float* zwb  = (float*)alloc((size_t)NH * NL * DH * 4);
    float* a2   = (float*)alloc((size_t)NH * NL * NL * 4);
    float* zb0  = (float*)alloc((size_t)NH * NL * NL * 4);   // z0 (kept for final)
    float* azb  = (float*)alloc((size_t)NH * NL * NL * 4);   // w ping
    float* tb   = (float*)alloc((size_t)NH * NL * NL * 4);   // w pong
    float* ub   = (float*)alloc((size_t)NH * NL * NL * 4);   // S = w@w
    float* part = (float*)alloc(256);
    float* a3p  = (float*)alloc((size_t)NH * A3NB * NL * 9 * 4);
    float* plan  = (float*)alloc((size_t)CCH * NPIX * 4);
    float* plan2 = (float*)alloc((size_t)CCH * NPIX * 4);
    float* wcomb = (float*)alloc((size_t)HD * 49 * 4);
    float* bsum  = (float*)alloc((size_t)HD * 4);
    short* wt1   = (short*)alloc((size_t)HD * ID * 2);
    short* wtq   = (short*)alloc((size_t)192 * HD * 2);
    short* xb    = (short*)alloc((size_t)NP * ID * 2);   // NP rows: fc1 A-tiles may read past NPIX
    short* xpB   = (short*)alloc((size_t)NP * HD * 2);
    (void)ws_size; (void)in_sizes; (void)n_in; (void)out_size;

    castX<<<(NPIX * ID / 8) / 256, 256, 0, stream>>>(x, xb);
    castT<<<dim3(HD / 32, ID / 32), 256, 0, stream>>>(fc1_w, wt1, ID, HD);
    gemm_fc1<<<dim3(8, 80), 256, 0, stream>>>(xb, wt1, fc1_b, bufA);
    cls_init<<<2, 256, 0, stream>>>(cls, bufA);

    auto attention = [&](float* hbuf, const float* lg, const float* lb,
                         const float* qkvw, const float* ow, const float* ob,
                         const float* rw) {
        ln_pad<<<NP / 4, 256, 0, stream>>>(hbuf, lg, lb, xpB);
        castT<<<dim3(192 / 32, HD / 32), 256, 0, stream>>>(qkvw, wtq, HD, 192);
        gemm_qkv<<<dim3(3, 154), 256, 0, stream>>>(xpB, wtq, qh, kh, vh);
        landmarks<<<128, 256, 0, stream>>>(qh, kh, ql, klm);
        attn2_softmax<<<dim3(NL, NH), 256, 0, stream>>>(ql, klm, a2);
        pinv_norms<<<16, 256, 0, stream>>>(a2, part);
        z0_init<<<2048, 256, 0, stream>>>(a2, part, zb0);
        // y0 = attn3 @ v (single K/V pass + merge)
        attn3v<<<dim3(A3NB, NH), 256, 0, stream>>>(kh, vh, ql, a3p);
        attn3v_merge<<<NH, 256, 0, stream>>>(a3p, ybuf);
        // w-space Newton-Schulz, w0 = a@z0.
        mm256<<<dim3(8, 4, 8), 256, 0, stream>>>(a2, zb0, azb);
        float* wc = azb;
        float* wn = tb;
        float* yc = ybuf;
        float* yn = ybuf2;
        for (int it = 0; it < 6; ++it) {
            mm256<<<dim3(8, 4, 8), 256, 0, stream>>>(wc, wc, ub);       // S
            if (it < 5) tu_mm<<<dim3(8, 4, 8), 256, 0, stream>>>(ub, wc, wn);
            yiter<<<dim3(8, 8), 256, 0, stream>>>(wc, ub, yc, yn);
            { float* t = yc; yc = yn; yn = t; }
            if (it < 5) { float* t = wc; wc = wn; wn = t; }
        }
        // zw = 4^-6 * z0 @ y6
        polyv<<<dim3(8, NH), 256, 0, stream>>>(zb0, yc, zwb, 2.44140625e-4f);
        attn1_conv<<<dim3(77, NH), 256, 0, stream>>>(qh, vh, klm, zwb, rw, aout);
        outproj<<<(NT + 15) / 16, 512, 0, stream>>>(aout, ow, ob, hbuf);
    };

    attention(bufA, l1_g, l1_bb, l1_qkv, l1_ow, l1_ob, l1_rw);

    ppeg_wprep<<<(HD * 49 + HD + 255) / 256, 256, 0, stream>>>(p7w, p7b, p5w, p5b, p3w, p3b,
                                                               wcomb, bsum);
    copy512<<<1, 512, 0, stream>>>(bufA, bufB);
    constexpr int PTILES = (NPIX + 31) / 32;
    for (int ch0 = 0; ch0 < HD; ch0 += CCH) {
        ppeg_t1<<<dim3(PTILES, CCH / 32), 256, 0, stream>>>(bufA, plan, ch0);
        ppeg_conv<<<dim3(CCH, 4), 256, 0, stream>>>(plan, wcomb, plan2, ch0);
        ppeg_t2<<<dim3(PTILES, CCH / 32), 256, 0, stream>>>(plan2, bsum, bufB, ch0);
    }

    attention(bufB, l2_g, l2_bb, l2_qkv, l2_ow, l2_ob, l2_rw);
    final_ln<<<1, 256, 0, stream>>>(bufB, ng, nb, out);
}

// Round 5
// 1158.236 us; speedup vs baseline: 1.2017x; 1.1093x over previous
//
#include <hip/hip_runtime.h>

namespace {

constexpr int NP   = 19712;   // padded tokens (Nystrom)
constexpr int NT   = 19601;   // tokens incl cls
constexpr int NPIX = 19600;   // feature tokens (140x140)
constexpr int HD   = 512;     // hidden dim
constexpr int ID   = 1024;    // input dim
constexpr int NH   = 8;       // heads
constexpr int DH   = 8;       // dim per head
constexpr int NL   = 256;     // landmarks
constexpr int PADR = 111;     // left zero-pad rows
constexpr int SIDE = 140;
constexpr int CCH  = 128;     // ppeg channel chunk
constexpr int PW   = 148;     // padded image row stride (floats)
constexpr int A3CHK = 256;    // attn3v tokens per block
constexpr int A3NB  = NP / A3CHK;   // 77 chunks

typedef __attribute__((ext_vector_type(8))) short bf16x8;
typedef __attribute__((ext_vector_type(4))) float f32x4;

#define F4MAD(a, s, v) { (a).x += (s)*(v).x; (a).y += (s)*(v).y; (a).z += (s)*(v).z; (a).w += (s)*(v).w; }

// async global->LDS, 16B per lane; LDS dest must be wave-uniform base + lane*16
#define GLOAD16(gptr, lptr) \
    __builtin_amdgcn_global_load_lds((const __attribute__((address_space(1))) void*)(gptr), \
                                     (__attribute__((address_space(3))) void*)(lptr), 16, 0, 0)

__device__ inline short f2bf(float f) {
    union { float f; unsigned u; } v; v.f = f;
    unsigned r = v.u + 0x7fffu + ((v.u >> 16) & 1u);
    return (short)(r >> 16);
}

// ------------------------------------------------------------------
// cast X fp32 -> bf16 elementwise
// ------------------------------------------------------------------
__global__ void castX(const float* __restrict__ src, short* __restrict__ dst)
{
    size_t c = (size_t)blockIdx.x * 256 + threadIdx.x;
    const float4 x0 = *(const float4*)&src[c * 8];
    const float4 x1 = *(const float4*)&src[c * 8 + 4];
    bf16x8 p;
    p[0] = f2bf(x0.x); p[1] = f2bf(x0.y); p[2] = f2bf(x0.z); p[3] = f2bf(x0.w);
    p[4] = f2bf(x1.x); p[5] = f2bf(x1.y); p[6] = f2bf(x1.z); p[7] = f2bf(x1.w);
    *(bf16x8*)&dst[c * 8] = p;
}

// ------------------------------------------------------------------
// cast+transpose: dst[c][r] = bf16(src[r][c]); grid (C/32, R/32)
// ------------------------------------------------------------------
__global__ void castT(const float* __restrict__ src, short* __restrict__ dst, int R, int C)
{
    __shared__ float t[32][33];
    const int tx = threadIdx.x & 31, ty = threadIdx.x >> 5;
    const int c0 = blockIdx.x * 32, r0 = blockIdx.y * 32;
    #pragma unroll
    for (int j = 0; j < 4; ++j)
        t[ty + 8 * j][tx] = src[(size_t)(r0 + ty + 8 * j) * C + c0 + tx];
    __syncthreads();
    #pragma unroll
    for (int j = 0; j < 4; ++j)
        dst[(size_t)(c0 + ty + 8 * j) * R + r0 + tx] = f2bf(t[tx][ty + 8 * j]);
}

// ------------------------------------------------------------------
// fc1 MFMA: 128x128 tile, BK=32, 2-phase dbuf global_load_lds.
// grid (4, 154) -- measured-best mapping (R3: 54us, 0 conflicts).
// XCD remap (R4) cut FETCH 80->24MB but cost +19us: not HBM-bound.
// ------------------------------------------------------------------
__global__ __launch_bounds__(256) void gemm_fc1(const short* __restrict__ Xb,
                                                const short* __restrict__ Wt,
                                                const float* __restrict__ bias,
                                                float* __restrict__ out)
{
    __shared__ __align__(16) short As[2][128 * 32];
    __shared__ __align__(16) short Bs[2][128 * 32];
    const int tid  = threadIdx.x;
    const int col0 = blockIdx.x * 128;
    const int row0 = blockIdx.y * 128;
    const int wave = tid >> 6, lane = tid & 63;
    const int quad = lane >> 4, l16 = lane & 15;
    const int m_base = (wave >> 1) * 64, n_base = (wave & 1) * 64;
    const int kch = (quad ^ ((l16 >> 1) & 3)) * 8;   // swizzled k-chunk (shorts)
    f32x4 acc[4][4] = {};

    int    aldo[2];
    size_t agoff[2], bgoff[2];
    #pragma unroll
    for (int i = 0; i < 2; ++i) {
        int slot = i * 256 + wave * 64 + lane;
        int row  = slot >> 2;
        int g    = (slot & 3) ^ ((slot >> 3) & 3);
        aldo[i]  = slot * 8;
        agoff[i] = (size_t)(row0 + row) * ID + g * 8;
        bgoff[i] = (size_t)(col0 + row) * ID + g * 8;
    }
    auto stage = [&](int b, int k0) {
        #pragma unroll
        for (int i = 0; i < 2; ++i) {
            GLOAD16(&Xb[agoff[i] + k0], &As[b][aldo[i]]);
            GLOAD16(&Wt[bgoff[i] + k0], &Bs[b][aldo[i]]);
        }
    };

    stage(0, 0);
    __syncthreads();
    #pragma unroll 1
    for (int t = 0; t < 32; ++t) {
        const int cur = t & 1;
        if (t < 31) stage(cur ^ 1, (t + 1) * 32);
        bf16x8 af[4], bfr[4];
        #pragma unroll
        for (int i = 0; i < 4; ++i) {
            af[i]  = *(const bf16x8*)&As[cur][(m_base + i * 16 + l16) * 32 + kch];
            bfr[i] = *(const bf16x8*)&Bs[cur][(n_base + i * 16 + l16) * 32 + kch];
        }
        #pragma unroll
        for (int mi = 0; mi < 4; ++mi)
            #pragma unroll
            for (int ni = 0; ni < 4; ++ni)
                acc[mi][ni] = __builtin_amdgcn_mfma_f32_16x16x32_bf16(af[mi], bfr[ni], acc[mi][ni], 0, 0, 0);
        __syncthreads();
    }
    #pragma unroll
    for (int mi = 0; mi < 4; ++mi) {
        #pragma unroll
        for (int r = 0; r < 4; ++r) {
            int gr = row0 + m_base + mi * 16 + quad * 4 + r;
            if (gr >= NPIX) continue;
            #pragma unroll
            for (int ni = 0; ni < 4; ++ni) {
                int gc = col0 + n_base + ni * 16 + l16;
                float v = acc[mi][ni][r] + bias[gc];
                v = 0.5f * v * (1.f + erff(v * 0.70710678118654752f));
                out[(size_t)(gr + 1) * HD + gc] = v;
            }
        }
    }
}

// ------------------------------------------------------------------
// qkv MFMA: 128x64 tile, BK=32, same 2-phase dbuf + fixed swizzle.
// grid (3 colblocks, 154 rowblocks)
// ------------------------------------------------------------------
__global__ __launch_bounds__(256) void gemm_qkv(const short* __restrict__ xpB,
                                                const short* __restrict__ Wt,
                                                float* __restrict__ qh,
                                                float* __restrict__ kh,
                                                float* __restrict__ vh)
{
    __shared__ __align__(16) short As[2][128 * 32];
    __shared__ __align__(16) short Bs[2][64 * 32];
    const int tid  = threadIdx.x;
    const int col0 = blockIdx.x * 64;
    const int row0 = blockIdx.y * 128;
    const int wave = tid >> 6, lane = tid & 63;
    const int quad = lane >> 4, l16 = lane & 15;
    const int m_base = (wave >> 1) * 64, n_base = (wave & 1) * 32;
    const int kch = (quad ^ ((l16 >> 1) & 3)) * 8;
    f32x4 acc[4][2] = {};

    int    aldo[2];
    size_t agoff[2];
    #pragma unroll
    for (int i = 0; i < 2; ++i) {
        int slot = i * 256 + wave * 64 + lane;
        int row  = slot >> 2;
        int g    = (slot & 3) ^ ((slot >> 3) & 3);
        aldo[i]  = slot * 8;
        agoff[i] = (size_t)(row0 + row) * HD + g * 8;
    }
    int bldo; size_t bgoff;
    {
        int slot = wave * 64 + lane;
        int row  = slot >> 2;
        int g    = (slot & 3) ^ ((slot >> 3) & 3);
        bldo  = slot * 8;
        bgoff = (size_t)(col0 + row) * HD + g * 8;
    }
    auto stage = [&](int b, int k0) {
        #pragma unroll
        for (int i = 0; i < 2; ++i)
            GLOAD16(&xpB[agoff[i] + k0], &As[b][aldo[i]]);
        GLOAD16(&Wt[bgoff + k0], &Bs[b][bldo]);
    };

    stage(0, 0);
    __syncthreads();
    #pragma unroll 1
    for (int t = 0; t < 16; ++t) {
        const int cur = t & 1;
        if (t < 15) stage(cur ^ 1, (t + 1) * 32);
        bf16x8 af[4], bfr[2];
        #pragma unroll
        for (int i = 0; i < 4; ++i)
            af[i] = *(const bf16x8*)&As[cur][(m_base + i * 16 + l16) * 32 + kch];
        #pragma unroll
        for (int i = 0; i < 2; ++i)
            bfr[i] = *(const bf16x8*)&Bs[cur][(n_base + i * 16 + l16) * 32 + kch];
        #pragma unroll
        for (int mi = 0; mi < 4; ++mi)
            #pragma unroll
            for (int ni = 0; ni < 2; ++ni)
                acc[mi][ni] = __builtin_amdgcn_mfma_f32_16x16x32_bf16(af[mi], bfr[ni], acc[mi][ni], 0, 0, 0);
        __syncthreads();
    }
    const int which = blockIdx.x;
    float* dst = (which == 0) ? qh : (which == 1) ? kh : vh;
    const float scale = (which == 0) ? 0.35355339059327373f : 1.f;
    #pragma unroll
    for (int mi = 0; mi < 4; ++mi) {
        #pragma unroll
        for (int r = 0; r < 4; ++r) {
            int gr = row0 + m_base + mi * 16 + quad * 4 + r;
            #pragma unroll
            for (int ni = 0; ni < 2; ++ni) {
                int n = n_base + ni * 16 + l16;
                int hh = n >> 3, d = n & 7;
                dst[((size_t)hh * NP + gr) * DH + d] = acc[mi][ni][r] * scale;
            }
        }
    }
}

__global__ void cls_init(const float* __restrict__ cls, float* __restrict__ h)
{
    int t = blockIdx.x * 256 + threadIdx.x;
    if (t < HD) h[t] = cls[t];
}

__global__ void copy512(const float* __restrict__ src, float* __restrict__ dst)
{
    dst[threadIdx.x] = src[threadIdx.x];
}

// ------------------------------------------------------------------
// layernorm rows of h into xp (bf16): wave-per-row, shfl reduce.
// grid NP/4, 256 threads (4 waves = 4 rows)
// ------------------------------------------------------------------
__global__ __launch_bounds__(256) void ln_pad(const float* __restrict__ h,
                                              const float* __restrict__ g,
                                              const float* __restrict__ b,
                                              short* __restrict__ xp)
{
    const int wave = threadIdx.x >> 6, lane = threadIdx.x & 63;
    const int row = blockIdx.x * 4 + wave;
    short* dst = xp + (size_t)row * HD + lane * 8;
    if (row < PADR) {
        bf16x8 z = {};
        *(bf16x8*)dst = z;
        return;
    }
    const float* src = h + (size_t)(row - PADR) * HD + lane * 8;
    float4 v0 = *(const float4*)src;
    float4 v1 = *(const float4*)(src + 4);
    float v[8] = {v0.x, v0.y, v0.z, v0.w, v1.x, v1.y, v1.z, v1.w};
    float s = 0.f;
    #pragma unroll
    for (int i = 0; i < 8; ++i) s += v[i];
    #pragma unroll
    for (int o = 1; o < 64; o <<= 1) s += __shfl_xor(s, o);
    float mu = s * (1.f / HD);
    float ss = 0.f;
    #pragma unroll
    for (int i = 0; i < 8; ++i) { float d = v[i] - mu; ss += d * d; }
    #pragma unroll
    for (int o = 1; o < 64; o <<= 1) ss += __shfl_xor(ss, o);
    float inv = rsqrtf(ss * (1.f / HD) + 1e-5f);
    float4 g0 = *(const float4*)&g[lane * 8];
    float4 g1 = *(const float4*)&g[lane * 8 + 4];
    float4 b0 = *(const float4*)&b[lane * 8];
    float4 b1 = *(const float4*)&b[lane * 8 + 4];
    float gg[8] = {g0.x, g0.y, g0.z, g0.w, g1.x, g1.y, g1.z, g1.w};
    float bb[8] = {b0.x, b0.y, b0.z, b0.w, b1.x, b1.y, b1.z, b1.w};
    bf16x8 o;
    #pragma unroll
    for (int i = 0; i < 8; ++i) o[i] = f2bf((v[i] - mu) * inv * gg[i] + bb[i]);
    *(bf16x8*)dst = o;
}

// ------------------------------------------------------------------
// landmark means
// ------------------------------------------------------------------
__global__ void landmarks(const float* __restrict__ qh, const float* __restrict__ kh,
                          float* __restrict__ ql, float* __restrict__ kl)
{
    int idx = blockIdx.x * 256 + threadIdx.x;
    int sel = idx >> 14;
    int rem = idx & 16383;
    int h = rem >> 11;
    int i = (rem >> 3) & 255;
    int d = rem & 7;
    const float* src = sel ? kh : qh;
    size_t base = ((size_t)h * NP + (size_t)i * 77) * DH + d;
    float s = 0.f;
    for (int j = 0; j < 77; ++j) s += src[base + (size_t)j * DH];
    (sel ? kl : ql)[((size_t)h * NL + i) * DH + d] = s * (1.f / 77.f);
}

// ------------------------------------------------------------------
// attn2 = softmax(q_l @ k_l^T); scores are O(1) -> no max subtraction
// ------------------------------------------------------------------
__global__ void attn2_softmax(const float* __restrict__ ql, const float* __restrict__ kl,
                              float* __restrict__ a)
{
    const int i = blockIdx.x, h = blockIdx.y, j = threadIdx.x;
    __shared__ float sq[8];
    __shared__ float red[256];
    if (j < 8) sq[j] = ql[((size_t)h * NL + i) * DH + j];
    __syncthreads();
    const float* kr = kl + ((size_t)h * NL + j) * DH;
    float s = 0.f;
    #pragma unroll
    for (int d = 0; d < 8; ++d) s += sq[d] * kr[d];
    float e = __expf(s);
    red[j] = e;
    __syncthreads();
    for (int off = 128; off > 0; off >>= 1) {
        if (j < off) red[j] += red[j + off];
        __syncthreads();
    }
    a[((size_t)h * NL + i) * NL + j] = e / red[0];
}

// ------------------------------------------------------------------
// pinv init
// ------------------------------------------------------------------
__global__ void pinv_norms(const float* __restrict__ a, float* __restrict__ part)
{
    const int h = blockIdx.x & 7;
    const int mode = blockIdx.x >> 3;
    const int tid = threadIdx.x;
    const float* ah = a + (size_t)h * NL * NL;
    float s = 0.f;
    if (mode == 0) { for (int j = 0; j < NL; ++j) s += fabsf(ah[tid * NL + j]); }
    else           { for (int i = 0; i < NL; ++i) s += fabsf(ah[i * NL + tid]); }
    __shared__ float red[256];
    red[tid] = s;
    __syncthreads();
    for (int off = 128; off > 0; off >>= 1) {
        if (tid < off) red[tid] = fmaxf(red[tid], red[tid + off]);
        __syncthreads();
    }
    if (tid == 0) part[mode * 8 + h] = red[0];
}

__global__ void z0_init(const float* __restrict__ a, const float* __restrict__ part,
                        float* __restrict__ z)
{
    float s1 = part[0], s2 = part[8];
    #pragma unroll
    for (int h = 1; h < 8; ++h) { s1 = fmaxf(s1, part[h]); s2 = fmaxf(s2, part[8 + h]); }
    float inv = 1.f / (s1 * s2);
    int idx = blockIdx.x * 256 + threadIdx.x;
    int h = idx >> 16;
    int rem = idx & 65535;
    int i = rem >> 8, j = rem & 255;
    z[idx] = a[((size_t)h * NL + j) * NL + i] * inv;
}

// ------------------------------------------------------------------
// batched 256x256x256: D = A@B   grid (8,4,8)
// ------------------------------------------------------------------
__global__ void mm256(const float* __restrict__ A, const float* __restrict__ B,
                      float* __restrict__ D)
{
    const int h = blockIdx.z;
    const float* Ah = A + (size_t)h * NL * NL;
    const float* Bh = B + (size_t)h * NL * NL;
    float* Dh = D + (size_t)h * NL * NL;
    __shared__ __align__(16) float As[16][36];
    __shared__ __align__(16) float Bs[16][68];
    const int tid = threadIdx.x;
    const int tx = tid & 15, ty = tid >> 4;
    const int row0 = blockIdx.x * 32;
    const int col0 = blockIdx.y * 64;
    float acc[2][4] = {};
    const int ar = tid >> 3;
    const int ak = (tid & 7) * 2;
    const int bk = tid >> 4;
    const int bj = (tid & 15) * 4;
    for (int k0 = 0; k0 < NL; k0 += 16) {
        float2 av = *(const float2*)&Ah[(size_t)(row0 + ar) * NL + k0 + ak];
        As[ak][ar] = av.x; As[ak + 1][ar] = av.y;
        *(float4*)&Bs[bk][bj] = *(const float4*)&Bh[(size_t)(k0 + bk) * NL + col0 + bj];
        __syncthreads();
        #pragma unroll
        for (int k = 0; k < 16; ++k) {
            float2 a = *(const float2*)&As[k][ty * 2];
            float4 b = *(const float4*)&Bs[k][tx * 4];
            acc[0][0] += a.x * b.x; acc[0][1] += a.x * b.y; acc[0][2] += a.x * b.z; acc[0][3] += a.x * b.w;
            acc[1][0] += a.y * b.x; acc[1][1] += a.y * b.y; acc[1][2] += a.y * b.z; acc[1][3] += a.y * b.w;
        }
        __syncthreads();
    }
    #pragma unroll
    for (int r = 0; r < 2; ++r) {
        int gr = row0 + ty * 2 + r;
        #pragma unroll
        for (int c = 0; c < 4; ++c)
            Dh[(size_t)gr * NL + col0 + tx * 4 + c] = acc[r][c];
    }
}

// ------------------------------------------------------------------
// mmF: Paterson-Stockmeyer step + fused y-update (role-split).
// GEMM blocks (blockIdx.y<4):  wn = 0.25*(13w - 15S) + 0.25*S@(7w - S)
//   (== 0.25*(13w -15S +7S@w - S@S) since all iterates commute)
// y blocks (blockIdx.y==4):    y' = 13y - 15t + S@(7y - t), t = w@y
// grid (8, 5, 8)
// ------------------------------------------------------------------
__global__ __launch_bounds__(256) void mmF(const float* __restrict__ S,
                                           const float* __restrict__ w,
                                           float* __restrict__ wn,
                                           const float* __restrict__ yin,
                                           float* __restrict__ yout)
{
    const int h = blockIdx.z;
    const int tid = threadIdx.x;
    if (blockIdx.y == 4) {
        // ---- y-update role (s = blockIdx.x slice) ----
        __shared__ float yL[NL * 9];
        __shared__ float tL[NL * 9];
        __shared__ float uL[NL * 9];
        const int s = blockIdx.x;
        const float* yh = yin + (size_t)h * NL * DH;
        #pragma unroll
        for (int i = 0; i < 8; ++i) {
            int idx = tid + 256 * i;
            yL[(idx >> 3) * 9 + (idx & 7)] = yh[idx];
        }
        __syncthreads();
        const float* wr = w + ((size_t)h * NL + tid) * NL;
        float t1[8] = {};
        for (int j = 0; j < NL; j += 4) {
            float4 wv = *(const float4*)&wr[j];
            #pragma unroll
            for (int d = 0; d < 8; ++d)
                t1[d] += wv.x * yL[j * 9 + d] + wv.y * yL[(j + 1) * 9 + d]
                       + wv.z * yL[(j + 2) * 9 + d] + wv.w * yL[(j + 3) * 9 + d];
        }
        #pragma unroll
        for (int d = 0; d < 8; ++d) {
            tL[tid * 9 + d] = t1[d];
            uL[tid * 9 + d] = 7.f * yL[tid * 9 + d] - t1[d];
        }
        __syncthreads();
        const int r = s * 32 + (tid >> 3), d = tid & 7;
        const float* Sr = S + ((size_t)h * NL + r) * NL;
        float acc = 13.f * yL[r * 9 + d] - 15.f * tL[r * 9 + d];
        for (int j = 0; j < NL; j += 4) {
            float4 sv = *(const float4*)&Sr[j];
            acc += sv.x * uL[j * 9 + d] + sv.y * uL[(j + 1) * 9 + d]
                 + sv.z * uL[(j + 2) * 9 + d] + sv.w * uL[(j + 3) * 9 + d];
        }
        yout[((size_t)h * NL + r) * DH + d] = acc;
        return;
    }
    // ---- GEMM role ----
    const float* Sh = S + (size_t)h * NL * NL;
    const float* wh = w + (size_t)h * NL * NL;
    float* Dh = wn + (size_t)h * NL * NL;
    __shared__ __align__(16) float As[16][36];
    __shared__ __align__(16) float Bs[16][68];
    const int tx = tid & 15, ty = tid >> 4;
    const int row0 = blockIdx.x * 32;
    const int col0 = blockIdx.y * 64;
    float acc[2][4] = {};
    const int ar = tid >> 3;
    const int ak = (tid & 7) * 2;
    const int bk = tid >> 4;
    const int bj = (tid & 15) * 4;
    for (int k0 = 0; k0 < NL; k0 += 16) {
        float2 av = *(const float2*)&Sh[(size_t)(row0 + ar) * NL + k0 + ak];
        As[ak][ar] = av.x; As[ak + 1][ar] = av.y;
        size_t bo = (size_t)(k0 + bk) * NL + col0 + bj;
        float4 bw = *(const float4*)&wh[bo];
        float4 bs = *(const float4*)&Sh[bo];
        Bs[bk][bj]     = 7.f * bw.x - bs.x;
        Bs[bk][bj + 1] = 7.f * bw.y - bs.y;
        Bs[bk][bj + 2] = 7.f * bw.z - bs.z;
        Bs[bk][bj + 3] = 7.f * bw.w - bs.w;
        __syncthreads();
        #pragma unroll
        for (int k = 0; k < 16; ++k) {
            float2 a = *(const float2*)&As[k][ty * 2];
            float4 b = *(const float4*)&Bs[k][tx * 4];
            acc[0][0] += a.x * b.x; acc[0][1] += a.x * b.y; acc[0][2] += a.x * b.z; acc[0][3] += a.x * b.w;
            acc[1][0] += a.y * b.x; acc[1][1] += a.y * b.y; acc[1][2] += a.y * b.z; acc[1][3] += a.y * b.w;
        }
        __syncthreads();
    }
    #pragma unroll
    for (int r = 0; r < 2; ++r) {
        int gr = row0 + ty * 2 + r;
        #pragma unroll
        for (int c = 0; c < 4; ++c) {
            int gc = col0 + tx * 4 + c;
            size_t o = (size_t)gr * NL + gc;
            Dh[o] = 0.25f * (13.f * wh[o] - 15.f * Sh[o] + acc[r][c]);
        }
    }
}

// ------------------------------------------------------------------
// y' = P(w)y = 13y - 15*t1 + S@(7y - t1), t1 = w@y.  (last iteration)
// grid (8 slices, 8 heads)
// ------------------------------------------------------------------
__global__ __launch_bounds__(256) void yiter(const float* __restrict__ w,
                                             const float* __restrict__ S,
                                             const float* __restrict__ yin,
                                             float* __restrict__ yout)
{
    const int s = blockIdx.x, h = blockIdx.y, tid = threadIdx.x;
    __shared__ float yL[NL * 9];
    __shared__ float tL[NL * 9];
    __shared__ float uL[NL * 9];
    const float* yh = yin + (size_t)h * NL * DH;
    #pragma unroll
    for (int i = 0; i < 8; ++i) {
        int idx = tid + 256 * i;
        yL[(idx >> 3) * 9 + (idx & 7)] = yh[idx];
    }
    __syncthreads();
    const float* wr = w + ((size_t)h * NL + tid) * NL;
    float t1[8] = {};
    for (int j = 0; j < NL; j += 4) {
        float4 wv = *(const float4*)&wr[j];
        #pragma unroll
        for (int d = 0; d < 8; ++d)
            t1[d] += wv.x * yL[j * 9 + d] + wv.y * yL[(j + 1) * 9 + d]
                   + wv.z * yL[(j + 2) * 9 + d] + wv.w * yL[(j + 3) * 9 + d];
    }
    #pragma unroll
    for (int d = 0; d < 8; ++d) {
        tL[tid * 9 + d] = t1[d];
        uL[tid * 9 + d] = 7.f * yL[tid * 9 + d] - t1[d];
    }
    __syncthreads();
    const int r = s * 32 + (tid >> 3), d = tid & 7;
    const float* Sr = S + ((size_t)h * NL + r) * NL;
    float acc = 13.f * yL[r * 9 + d] - 15.f * tL[r * 9 + d];
    for (int j = 0; j < NL; j += 4) {
        float4 sv = *(const float4*)&Sr[j];
        acc += sv.x * uL[j * 9 + d] + sv.y * uL[(j + 1) * 9 + d]
             + sv.z * uL[(j + 2) * 9 + d] + sv.w * uL[(j + 3) * 9 + d];
    }
    yout[((size_t)h * NL + r) * DH + d] = acc;
}

// ------------------------------------------------------------------
// vout[h] = scale * M[h] @ vin[h];  M: [8][256][256], v: [8][256][8]
// ------------------------------------------------------------------
__global__ void polyv(const float* __restrict__ M, const float* __restrict__ vin,
                      float* __restrict__ vout, float scale)
{
    const int h = blockIdx.y;
    __shared__ float vs[NL * DH];
    const int tid = threadIdx.x;
    const float* vh = vin + (size_t)h * NL * DH;
    #pragma unroll
    for (int i = 0; i < 8; ++i) vs[tid + 256 * i] = vh[tid + 256 * i];
    __syncthreads();
    const int row = blockIdx.x * 32 + (tid >> 3);
    const int d = tid & 7;
    const float* Mr = M + ((size_t)h * NL + row) * NL;
    float acc = 0.f;
    #pragma unroll 4
    for (int j = 0; j < NL; j += 4) {
        float4 m = *(const float4*)&Mr[j];
        acc += m.x * vs[j * 8 + d]      + m.y * vs[j * 8 + 8 + d]
             + m.z * vs[j * 8 + 16 + d] + m.w * vs[j * 8 + 24 + d];
    }
    vout[((size_t)h * NL + row) * DH + d] = acc * scale;
}

// ------------------------------------------------------------------
// attn3 @ v, single K/V pass: grid (77 chunks, 8 heads).
// ------------------------------------------------------------------
__global__ __launch_bounds__(256) void attn3v(const float* __restrict__ kh,
                                              const float* __restrict__ vh,
                                              const float* __restrict__ ql,
                                              float* __restrict__ part)
{
    const int ck = blockIdx.x, h = blockIdx.y, tid = threadIdx.x;
    __shared__ __align__(16) float4 kv[A3CHK][4];   // [t]: k0 k1 v0 v1
    const float* kb = kh + ((size_t)h * NP + (size_t)ck * A3CHK) * DH;
    const float* vb = vh + ((size_t)h * NP + (size_t)ck * A3CHK) * DH;
    #pragma unroll
    for (int i = 0; i < 2; ++i) {
        int idx = tid + 256 * i;          // 0..511
        int t = idx >> 1, p = idx & 1;
        kv[t][p]     = *(const float4*)&kb[t * 8 + p * 4];
        kv[t][2 + p] = *(const float4*)&vb[t * 8 + p * 4];
    }
    float q[8];
    const float* qp = ql + ((size_t)h * NL + tid) * DH;
    #pragma unroll
    for (int d = 0; d < 8; ++d) q[d] = qp[d];
    __syncthreads();
    float den = 0.f;
    float4 a0 = make_float4(0.f, 0.f, 0.f, 0.f);
    float4 a1 = make_float4(0.f, 0.f, 0.f, 0.f);
    #pragma unroll 4
    for (int t = 0; t < A3CHK; ++t) {
        float4 k0 = kv[t][0], k1 = kv[t][1];
        float s = q[0] * k0.x + q[1] * k0.y + q[2] * k0.z + q[3] * k0.w
                + q[4] * k1.x + q[5] * k1.y + q[6] * k1.z + q[7] * k1.w;
        float e = __expf(s);
        den += e;
        float4 v0 = kv[t][2], v1 = kv[t][3];
        F4MAD(a0, e, v0); F4MAD(a1, e, v1);
    }
    float* p = part + (((size_t)h * A3NB + ck) * NL + tid) * 9;
    p[0] = den;
    p[1] = a0.x; p[2] = a0.y; p[3] = a0.z; p[4] = a0.w;
    p[5] = a1.x; p[6] = a1.y; p[7] = a1.z; p[8] = a1.w;
}

// merge 77 chunks -> y0[h][i][d]; grid 8 (heads), thread = landmark
__global__ void attn3v_merge(const float* __restrict__ part, float* __restrict__ y)
{
    const int h = blockIdx.x, i = threadIdx.x;
    float den = 0.f;
    float acc[8] = {};
    for (int ck = 0; ck < A3NB; ++ck) {
        const float* p = part + (((size_t)h * A3NB + ck) * NL + i) * 9;
        den += p[0];
        #pragma unroll
        for (int d = 0; d < 8; ++d) acc[d] += p[1 + d];
    }
    float inv = 1.f / den;
    #pragma unroll
    for (int d = 0; d < 8; ++d) y[((size_t)h * NL + i) * DH + d] = acc[d] * inv;
}

// ------------------------------------------------------------------
// attn1 fused + dwconv33(v): 1 lane = 1 token; kl/zw broadcast from LDS
// (wave-uniform addr -> conflict-free). grid (77, 8), 256 threads.
// ------------------------------------------------------------------
__global__ __launch_bounds__(256) void attn1_conv(const float* __restrict__ qh,
                                                  const float* __restrict__ vh,
                                                  const float* __restrict__ klg,
                                                  const float* __restrict__ zwg,
                                                  const float* __restrict__ rw,
                                                  float* __restrict__ aout)
{
    const int h = blockIdx.y;
    __shared__ __align__(16) float kl[NL * DH];
    __shared__ __align__(16) float zw[NL * DH];
    const int tid = threadIdx.x;
    #pragma unroll
    for (int q = 0; q < 8; ++q) {
        kl[tid + 256 * q] = klg[(size_t)h * NL * DH + tid + 256 * q];
        zw[tid + 256 * q] = zwg[(size_t)h * NL * DH + tid + 256 * q];
    }
    __syncthreads();
    const int r = blockIdx.x * 256 + tid;
    if (r >= NT) return;
    const int t = r + PADR;
    const float* qp = qh + ((size_t)h * NP + t) * DH;
    float4 q0 = *(const float4*)qp;
    float4 q1 = *(const float4*)(qp + 4);
    float den = 0.f;
    float4 acc0 = make_float4(0.f, 0.f, 0.f, 0.f);
    float4 acc1 = make_float4(0.f, 0.f, 0.f, 0.f);
    #pragma unroll 4
    for (int i = 0; i < NL; ++i) {
        float4 k0 = *(const float4*)&kl[i * 8];
        float4 k1 = *(const float4*)&kl[i * 8 + 4];
        float s = q0.x * k0.x + q0.y * k0.y + q0.z * k0.z + q0.w * k0.w
                + q1.x * k1.x + q1.y * k1.y + q1.z * k1.z + q1.w * k1.w;
        float e = __expf(s);
        den += e;
        float4 z0 = *(const float4*)&zw[i * 8];
        float4 z1 = *(const float4*)&zw[i * 8 + 4];
        F4MAD(acc0, e, z0); F4MAD(acc1, e, z1);
    }
    float inv = 1.f / den;
    const float* vb = vh + (size_t)h * NP * DH;
    float4 c0 = make_float4(0.f, 0.f, 0.f, 0.f);
    float4 c1 = make_float4(0.f, 0.f, 0.f, 0.f);
    #pragma unroll
    for (int j = 0; j < 33; ++j) {
        int tp = t - 16 + j;
        if (tp >= NP) continue;
        float wv = rw[h * 33 + j];
        float4 v0 = *(const float4*)&vb[(size_t)tp * 8];
        float4 v1 = *(const float4*)&vb[(size_t)tp * 8 + 4];
        F4MAD(c0, wv, v0); F4MAD(c1, wv, v1);
    }
    float* op = aout + (size_t)r * 64 + h * 8;
    *(float4*)op = make_float4(acc0.x * inv + c0.x, acc0.y * inv + c0.y,
                               acc0.z * inv + c0.z, acc0.w * inv + c0.w);
    *(float4*)(op + 4) = make_float4(acc1.x * inv + c1.x, acc1.y * inv + c1.y,
                                     acc1.z * inv + c1.z, acc1.w * inv + c1.w);
}

// ------------------------------------------------------------------
// out-proj + residual: 16 rows/block
// ------------------------------------------------------------------
__global__ void outproj(const float* __restrict__ aout, const float* __restrict__ W,
                        const float* __restrict__ bias, float* __restrict__ h)
{
    const int r0 = blockIdx.x * 16;
    const int tid = threadIdx.x;   // 512
    __shared__ float ao[16][64];
    #pragma unroll
    for (int s = 0; s < 2; ++s) {
        int idx = tid + s * 512;
        int rr = idx >> 6, kk = idx & 63;
        int gr = r0 + rr;
        ao[rr][kk] = (gr < NT) ? aout[(size_t)gr * 64 + kk] : 0.f;
    }
    __syncthreads();
    float acc[16] = {};
    for (int k = 0; k < 64; ++k) {
        float wv = W[(size_t)k * HD + tid];
        #pragma unroll
        for (int r = 0; r < 16; ++r) acc[r] += ao[r][k] * wv;
    }
    float bv = bias[tid];
    #pragma unroll
    for (int r = 0; r < 16; ++r) {
        int gr = r0 + r;
        if (gr < NT) h[(size_t)gr * HD + tid] += acc[r] + bv;
    }
}

// ------------------------------------------------------------------
// PPEG
// ------------------------------------------------------------------
__global__ void ppeg_wprep(const float* __restrict__ w7, const float* __restrict__ b7,
                           const float* __restrict__ w5, const float* __restrict__ b5,
                           const float* __restrict__ w3, const float* __restrict__ b3,
                           float* __restrict__ wc, float* __restrict__ bsum)
{
    int idx = blockIdx.x * 256 + threadIdx.x;
    if (idx < HD * 49) {
        int c = idx / 49, t = idx - c * 49;
        int dy = t / 7 - 3, dx = t % 7 - 3;
        float v = w7[idx];
        if (dy >= -2 && dy <= 2 && dx >= -2 && dx <= 2) v += w5[c * 25 + (dy + 2) * 5 + (dx + 2)];
        if (dy >= -1 && dy <= 1 && dx >= -1 && dx <= 1) v += w3[c * 9 + (dy + 1) * 3 + (dx + 1)];
        if (t == 24) v += 1.f;
        wc[idx] = v;
    } else if (idx < HD * 49 + HD) {
        int c = idx - HD * 49;
        bsum[c] = b7[c] + b5[c] + b3[c];
    }
}

__global__ void ppeg_t1(const float* __restrict__ hin, float* __restrict__ plan, int ch0)
{
    __shared__ float tile[32][33];
    const int tx = threadIdx.x & 31, ty = threadIdx.x >> 5;
    const int p0 = blockIdx.x * 32;
    const int c0 = ch0 + blockIdx.y * 32;
    #pragma unroll
    for (int j = 0; j < 4; ++j) {
        int p = p0 + ty + j * 8;
        tile[ty + j * 8][tx] = (p < NPIX) ? hin[(size_t)(1 + p) * HD + c0 + tx] : 0.f;
    }
    __syncthreads();
    #pragma unroll
    for (int j = 0; j < 4; ++j) {
        int p = p0 + tx;
        int cc = ty + j * 8;
        if (p < NPIX) plan[(size_t)(blockIdx.y * 32 + cc) * NPIX + p] = tile[tx][cc];
    }
}

__global__ __launch_bounds__(256) void ppeg_conv(const float* __restrict__ plan,
                                                 const float* __restrict__ wc,
                                                 float* __restrict__ plan2, int ch0)
{
    __shared__ __align__(16) float img[41 * PW];
    const int tid = threadIdx.x;
    const int cl = blockIdx.x;
    const int yq = blockIdx.y;
    for (int i = tid; i < 41 * PW; i += 256) img[i] = 0.f;
    __syncthreads();
    const float* src = plan + (size_t)cl * NPIX;
    for (int i = tid; i < 41 * SIDE; i += 256) {
        int ly = i / SIDE, x = i - ly * SIDE;
        int y = yq * 35 - 3 + ly;
        if (y >= 0 && y < SIDE) img[ly * PW + x + 3] = src[y * SIDE + x];
    }
    const float* w = wc + (size_t)(ch0 + cl) * 49;
    float wr[49];
    #pragma unroll
    for (int t = 0; t < 49; ++t) wr[t] = w[t];
    __syncthreads();
    float* dst = plan2 + (size_t)cl * NPIX;
    for (int g = tid; g < 35 * 35; g += 256) {
        int yl = g / 35, x0 = (g - yl * 35) * 4;
        float acc0 = 0.f, acc1 = 0.f, acc2 = 0.f, acc3 = 0.f;
        #pragma unroll
        for (int a = 0; a < 7; ++a) {
            const float* row = &img[(yl + a) * PW + x0];
            float4 A = *(const float4*)(row);
            float4 B = *(const float4*)(row + 4);
            float4 C = *(const float4*)(row + 8);
            float e0 = A.x, e1 = A.y, e2 = A.z, e3 = A.w;
            float e4 = B.x, e5 = B.y, e6 = B.z, e7 = B.w;
            float e8 = C.x, e9 = C.y;
            const float w0 = wr[a*7+0], w1 = wr[a*7+1], w2 = wr[a*7+2], w3v = wr[a*7+3];
            const float w4 = wr[a*7+4], w5v = wr[a*7+5], w6 = wr[a*7+6];
            acc0 += w0*e0 + w1*e1 + w2*e2 + w3v*e3 + w4*e4 + w5v*e5 + w6*e6;
            acc1 += w0*e1 + w1*e2 + w2*e3 + w3v*e4 + w4*e5 + w5v*e6 + w6*e7;
            acc2 += w0*e2 + w1*e3 + w2*e4 + w3v*e5 + w4*e6 + w5v*e7 + w6*e8;
            acc3 += w0*e3 + w1*e4 + w2*e5 + w3v*e6 + w4*e7 + w5v*e8 + w6*e9;
        }
        *(float4*)&dst[(yq * 35 + yl) * SIDE + x0] = make_float4(acc0, acc1, acc2, acc3);
    }
}

__global__ void ppeg_t2(const float* __restrict__ plan2, const float* __restrict__ bsum,
                        float* __restrict__ hout, int ch0)
{
    __shared__ float tile[32][33];
    const int tx = threadIdx.x & 31, ty = threadIdx.x >> 5;
    const int p0 = blockIdx.x * 32;
    #pragma unroll
    for (int j = 0; j < 4; ++j) {
        int p = p0 + tx;
        int cc = ty + j * 8;
        tile[tx][cc] = (p < NPIX) ? plan2[(size_t)(blockIdx.y * 32 + cc) * NPIX + p] : 0.f;
    }
    __syncthreads();
    const int c0 = ch0 + blockIdx.y * 32;
    float bv = bsum[c0 + tx];
    #pragma unroll
    for (int j = 0; j < 4; ++j) {
        int p = p0 + ty + j * 8;
        if (p < NPIX) hout[(size_t)(1 + p) * HD + c0 + tx] = tile[ty + j * 8][tx] + bv;
    }
}

// ------------------------------------------------------------------
// final layernorm of row 0
// ------------------------------------------------------------------
__global__ void final_ln(const float* __restrict__ h, const float* __restrict__ g,
                         const float* __restrict__ b, float* __restrict__ out)
{
    const int tid = threadIdx.x;
    float v0 = h[tid], v1 = h[tid + 256];
    __shared__ float red[256];
    red[tid] = v0 + v1;
    __syncthreads();
    for (int off = 128; off > 0; off >>= 1) {
        if (tid < off) red[tid] += red[tid + off];
        __syncthreads();
    }
    float mu = red[0] * (1.f / HD);
    __syncthreads();
    float d0 = v0 - mu, d1 = v1 - mu;
    red[tid] = d0 * d0 + d1 * d1;
    __syncthreads();
    for (int off = 128; off > 0; off >>= 1) {
        if (tid < off) red[tid] += red[tid + off];
        __syncthreads();
    }
    float inv = rsqrtf(red[0] * (1.f / HD) + 1e-5f);
    out[tid]       = d0 * inv * g[tid] + b[tid];
    out[tid + 256] = d1 * inv * g[tid + 256] + b[tid + 256];
}

} // namespace

extern "C" void kernel_launch(void* const* d_in, const int* in_sizes, int n_in,
                              void* d_out, int out_size, void* d_ws, size_t ws_size,
                              hipStream_t stream)
{
    const float* x      = (const float*)d_in[0];
    const float* fc1_w  = (const float*)d_in[1];
    const float* fc1_b  = (const float*)d_in[2];
    const float* cls    = (const float*)d_in[3];
    const float* l1_g   = (const float*)d_in[4];
    const float* l1_bb  = (const float*)d_in[5];
    const float* l1_qkv = (const float*)d_in[6];
    const float* l1_ow  = (const float*)d_in[7];
    const float* l1_ob  = (const float*)d_in[8];
    const float* l1_rw  = (const float*)d_in[9];
    const float* l2_g   = (const float*)d_in[10];
    const float* l2_bb  = (const float*)d_in[11];
    const float* l2_qkv = (const float*)d_in[12];
    const float* l2_ow  = (const float*)d_in[13];
    const float* l2_ob  = (const float*)d_in[14];
    const float* l2_rw  = (const float*)d_in[15];
    const float* p7w    = (const float*)d_in[16];
    const float* p7b    = (const float*)d_in[17];
    const float* p5w    = (const float*)d_in[18];
    const float* p5b    = (const float*)d_in[19];
    const float* p3w    = (const float*)d_in[20];
    const float* p3b    = (const float*)d_in[21];
    const float* ng     = (const float*)d_in[22];
    const float* nb     = (const float*)d_in[23];
    float* out = (float*)d_out;

    char* ws = (char*)d_ws;
    size_t off = 0;
    auto alloc = [&](size_t bytes) {
        char* p = ws + off;
        off += (bytes + 255) & ~(size_t)255;
        return (void*)p;
    };
    float* bufA = (float*)alloc((size_t)NP * HD * 4);
    float* bufB = (float*)alloc((size_t)NP * HD * 4);
    float* qh   = (float*)alloc((size_t)NH * NP * DH * 4);
    float* kh   = (float*)alloc((size_t)NH * NP * DH * 4);
    float* vh   = (float*)alloc((size_t)NH * NP * DH * 4);
    float* aout = (float*)alloc((size_t)NP * 64 * 4);
    float* ql   = (float*)alloc((size_t)NH * NL * DH * 4);
    float* klm  = (float*)alloc((size_t)NH * NL * DH * 4);
    float* ybuf = (float*)alloc((size_t)NH * NL * DH * 4);
    float* ybuf2= (float*)alloc((size_t)NH * NL * DH * 4);
    float* zwb  = (float*)alloc((size_t)NH * NL * DH * 4);
    float* a2   = (float*)alloc((size_t)NH * NL * NL * 4);
    float* zb0  = (float*)alloc((size_t)NH * NL * NL * 4);   // z0 (kept for final)
    float* azb  = (float*)alloc((size_t)NH * NL * NL * 4);   // w ping
    float* tb   = (float*)alloc((size_t)NH * NL * NL * 4);   // w pong
    float* ub   = (float*)alloc((size_t)NH * NL * NL * 4);   // S = w@w
    float* part = (float*)alloc(256);
    float* a3p  = (float*)alloc((size_t)NH * A3NB * NL * 9 * 4);
    float* plan  = (float*)alloc((size_t)CCH * NPIX * 4);
    float* plan2 = (float*)alloc((size_t)CCH * NPIX * 4);
    float* wcomb = (float*)alloc((size_t)HD * 49 * 4);
    float* bsum  = (float*)alloc((size_t)HD * 4);
    short* wt1   = (short*)alloc((size_t)HD * ID * 2);
    short* wtq   = (short*)alloc((size_t)192 * HD * 2);
    short* xb    = (short*)alloc((size_t)NP * ID * 2);   // NP rows: fc1 A-tiles may read past NPIX
    short* xpB   = (short*)alloc((size_t)NP * HD * 2);
    (void)ws_size; (void)in_sizes; (void)n_in; (void)out_size;

    castX<<<(NPIX * ID / 8) / 256, 256, 0, stream>>>(x, xb);
    castT<<<dim3(HD / 32, ID / 32), 256, 0, stream>>>(fc1_w, wt1, ID, HD);
    gemm_fc1<<<dim3(4, 154), 256, 0, stream>>>(xb, wt1, fc1_b, bufA);
    cls_init<<<2, 256, 0, stream>>>(cls, bufA);

    auto attention = [&](float* hbuf, const float* lg, const float* lb,
                         const float* qkvw, const float* ow, const float* ob,
                         const float* rw) {
        ln_pad<<<NP / 4, 256, 0, stream>>>(hbuf, lg, lb, xpB);
        castT<<<dim3(192 / 32, HD / 32), 256, 0, stream>>>(qkvw, wtq, HD, 192);
        gemm_qkv<<<dim3(3, 154), 256, 0, stream>>>(xpB, wtq, qh, kh, vh);
        landmarks<<<128, 256, 0, stream>>>(qh, kh, ql, klm);
        attn2_softmax<<<dim3(NL, NH), 256, 0, stream>>>(ql, klm, a2);
        pinv_norms<<<16, 256, 0, stream>>>(a2, part);
        z0_init<<<2048, 256, 0, stream>>>(a2, part, zb0);
        // y0 = attn3 @ v (single K/V pass + merge)
        attn3v<<<dim3(A3NB, NH), 256, 0, stream>>>(kh, vh, ql, a3p);
        attn3v_merge<<<NH, 256, 0, stream>>>(a3p, ybuf);
        // w-space Newton-Schulz, w0 = a@z0; Paterson-Stockmeyer:
        //   S = w@w;  w' = 0.25(13w - 15S) + 0.25 S@(7w - S)  [mmF, fused y role]
        // y <- P_it @ y (P's commute: polynomials of shared w0).
        mm256<<<dim3(8, 4, 8), 256, 0, stream>>>(a2, zb0, azb);
        float* wc = azb;
        float* wn = tb;
        float* yc = ybuf;
        float* yn = ybuf2;
        for (int it = 0; it < 6; ++it) {
            mm256<<<dim3(8, 4, 8), 256, 0, stream>>>(wc, wc, ub);       // S
            if (it < 5) {
                mmF<<<dim3(8, 5, 8), 256, 0, stream>>>(ub, wc, wn, yc, yn);
                { float* t = yc; yc = yn; yn = t; }
                { float* t = wc; wc = wn; wn = t; }
            } else {
                yiter<<<dim3(8, 8), 256, 0, stream>>>(wc, ub, yc, yn);
                { float* t = yc; yc = yn; yn = t; }
            }
        }
        // zw = 4^-6 * z0 @ y6
        polyv<<<dim3(8, NH), 256, 0, stream>>>(zb0, yc, zwb, 2.44140625e-4f);
        attn1_conv<<<dim3(77, NH), 256, 0, stream>>>(qh, vh, klm, zwb, rw, aout);
        outproj<<<(NT + 15) / 16, 512, 0, stream>>>(aout, ow, ob, hbuf);
    };

    attention(bufA, l1_g, l1_bb, l1_qkv, l1_ow, l1_ob, l1_rw);

    ppeg_wprep<<<(HD * 49 + HD + 255) / 256, 256, 0, stream>>>(p7w, p7b, p5w, p5b, p3w, p3b,
                                                               wcomb, bsum);
    copy512<<<1, 512, 0, stream>>>(bufA, bufB);
    constexpr int PTILES = (NPIX + 31) / 32;
    for (int ch0 = 0; ch0 < HD; ch0 += CCH) {
        ppeg_t1<<<dim3(PTILES, CCH / 32), 256, 0, stream>>>(bufA, plan, ch0);
        ppeg_conv<<<dim3(CCH, 4), 256, 0, stream>>>(plan, wcomb, plan2, ch0);
        ppeg_t2<<<dim3(PTILES, CCH / 32), 256, 0, stream>>>(plan2, bsum, bufB, ch0);
    }

    attention(bufB, l2_g, l2_bb, l2_qkv, l2_ow, l2_ob, l2_rw);
    final_ln<<<1, 256, 0, stream>>>(bufB, ng, nb, out);
}

// Round 9
// 1031.961 us; speedup vs baseline: 1.3488x; 1.1224x over previous
//
#include <hip/hip_runtime.h>

namespace {

constexpr int NP   = 19712;   // padded tokens (Nystrom)
constexpr int NT   = 19601;   // tokens incl cls
constexpr int NPIX = 19600;   // feature tokens (140x140)
constexpr int HD   = 512;     // hidden dim
constexpr int ID   = 1024;    // input dim
constexpr int NH   = 8;       // heads
constexpr int DH   = 8;       // dim per head
constexpr int NL   = 256;     // landmarks
constexpr int PADR = 111;     // left zero-pad rows
constexpr int SIDE = 140;
constexpr int A3CHK = 256;    // attn3v tokens per block
constexpr int A3NB  = NP / A3CHK;   // 77 chunks

// ppeg_direct tiling
constexpr int PTW = 16, PTH = 16, PCC = 16;   // tile w, h, channels
constexpr int PHW = PTW + 6, PHH = PTH + 6;   // 22x22 incl halo
constexpr int PSLOT = 20;                     // floats per (y,x) slot (16 used; 16B-aligned pad)

typedef __attribute__((ext_vector_type(8))) short bf16x8;
typedef __attribute__((ext_vector_type(4))) float f32x4;

#define F4MAD(a, s, v) { (a).x += (s)*(v).x; (a).y += (s)*(v).y; (a).z += (s)*(v).z; (a).w += (s)*(v).w; }
// NOTE: param must NOT be named 'w' -- macro substitution would capture the .w field (R6 compile bug)
#define F4FMA(a, ww, v) { (a).x += (ww).x*(v).x; (a).y += (ww).y*(v).y; (a).z += (ww).z*(v).z; (a).w += (ww).w*(v).w; }

// async global->LDS, 16B per lane; LDS dest must be wave-uniform base + lane*16
#define GLOAD16(gptr, lptr) \
    __builtin_amdgcn_global_load_lds((const __attribute__((address_space(1))) void*)(gptr), \
                                     (__attribute__((address_space(3))) void*)(lptr), 16, 0, 0)

__device__ inline short f2bf(float f) {
    union { float f; unsigned u; } v; v.f = f;
    unsigned r = v.u + 0x7fffu + ((v.u >> 16) & 1u);
    return (short)(r >> 16);
}

// ------------------------------------------------------------------
// cast X fp32 -> bf16 elementwise
// ------------------------------------------------------------------
__global__ void castX(const float* __restrict__ src, short* __restrict__ dst)
{
    size_t c = (size_t)blockIdx.x * 256 + threadIdx.x;
    const float4 x0 = *(const float4*)&src[c * 8];
    const float4 x1 = *(const float4*)&src[c * 8 + 4];
    bf16x8 p;
    p[0] = f2bf(x0.x); p[1] = f2bf(x0.y); p[2] = f2bf(x0.z); p[3] = f2bf(x0.w);
    p[4] = f2bf(x1.x); p[5] = f2bf(x1.y); p[6] = f2bf(x1.z); p[7] = f2bf(x1.w);
    *(bf16x8*)&dst[c * 8] = p;
}

// ------------------------------------------------------------------
// cast+transpose: dst[c][r] = bf16(src[r][c]); grid (C/32, R/32)
// ------------------------------------------------------------------
__global__ void castT(const float* __restrict__ src, short* __restrict__ dst, int R, int C)
{
    __shared__ float t[32][33];
    const int tx = threadIdx.x & 31, ty = threadIdx.x >> 5;
    const int c0 = blockIdx.x * 32, r0 = blockIdx.y * 32;
    #pragma unroll
    for (int j = 0; j < 4; ++j)
        t[ty + 8 * j][tx] = src[(size_t)(r0 + ty + 8 * j) * C + c0 + tx];
    __syncthreads();
    #pragma unroll
    for (int j = 0; j < 4; ++j)
        dst[(size_t)(c0 + ty + 8 * j) * R + r0 + tx] = f2bf(t[tx][ty + 8 * j]);
}

// ------------------------------------------------------------------
// fc1 MFMA: 128x128 tile, BK=32, 2-phase dbuf global_load_lds.
// grid (4, 154) -- measured-best mapping (R3/R5: ~53us, 0 conflicts).
// ------------------------------------------------------------------
__global__ __launch_bounds__(256) void gemm_fc1(const short* __restrict__ Xb,
                                                const short* __restrict__ Wt,
                                                const float* __restrict__ bias,
                                                float* __restrict__ out)
{
    __shared__ __align__(16) short As[2][128 * 32];
    __shared__ __align__(16) short Bs[2][128 * 32];
    const int tid  = threadIdx.x;
    const int col0 = blockIdx.x * 128;
    const int row0 = blockIdx.y * 128;
    const int wave = tid >> 6, lane = tid & 63;
    const int quad = lane >> 4, l16 = lane & 15;
    const int m_base = (wave >> 1) * 64, n_base = (wave & 1) * 64;
    const int kch = (quad ^ ((l16 >> 1) & 3)) * 8;   // swizzled k-chunk (shorts)
    f32x4 acc[4][4] = {};

    int    aldo[2];
    size_t agoff[2], bgoff[2];
    #pragma unroll
    for (int i = 0; i < 2; ++i) {
        int slot = i * 256 + wave * 64 + lane;
        int row  = slot >> 2;
        int g    = (slot & 3) ^ ((slot >> 3) & 3);
        aldo[i]  = slot * 8;
        agoff[i] = (size_t)(row0 + row) * ID + g * 8;
        bgoff[i] = (size_t)(col0 + row) * ID + g * 8;
    }
    auto stage = [&](int b, int k0) {
        #pragma unroll
        for (int i = 0; i < 2; ++i) {
            GLOAD16(&Xb[agoff[i] + k0], &As[b][aldo[i]]);
            GLOAD16(&Wt[bgoff[i] + k0], &Bs[b][aldo[i]]);
        }
    };

    stage(0, 0);
    __syncthreads();
    #pragma unroll 1
    for (int t = 0; t < 32; ++t) {
        const int cur = t & 1;
        if (t < 31) stage(cur ^ 1, (t + 1) * 32);
        bf16x8 af[4], bfr[4];
        #pragma unroll
        for (int i = 0; i < 4; ++i) {
            af[i]  = *(const bf16x8*)&As[cur][(m_base + i * 16 + l16) * 32 + kch];
            bfr[i] = *(const bf16x8*)&Bs[cur][(n_base + i * 16 + l16) * 32 + kch];
        }
        #pragma unroll
        for (int mi = 0; mi < 4; ++mi)
            #pragma unroll
            for (int ni = 0; ni < 4; ++ni)
                acc[mi][ni] = __builtin_amdgcn_mfma_f32_16x16x32_bf16(af[mi], bfr[ni], acc[mi][ni], 0, 0, 0);
        __syncthreads();
    }
    #pragma unroll
    for (int mi = 0; mi < 4; ++mi) {
        #pragma unroll
        for (int r = 0; r < 4; ++r) {
            int gr = row0 + m_base + mi * 16 + quad * 4 + r;
            if (gr >= NPIX) continue;
            #pragma unroll
            for (int ni = 0; ni < 4; ++ni) {
                int gc = col0 + n_base + ni * 16 + l16;
                float v = acc[mi][ni][r] + bias[gc];
                v = 0.5f * v * (1.f + erff(v * 0.70710678118654752f));
                out[(size_t)(gr + 1) * HD + gc] = v;
            }
        }
    }
}

// ------------------------------------------------------------------
// qkv MFMA: 128x64 tile, BK=32, same 2-phase dbuf + fixed swizzle.
// grid (3 colblocks, 154 rowblocks)
// ------------------------------------------------------------------
__global__ __launch_bounds__(256) void gemm_qkv(const short* __restrict__ xpB,
                                                const short* __restrict__ Wt,
                                                float* __restrict__ qh,
                                                float* __restrict__ kh,
                                                float* __restrict__ vh)
{
    __shared__ __align__(16) short As[2][128 * 32];
    __shared__ __align__(16) short Bs[2][64 * 32];
    const int tid  = threadIdx.x;
    const int col0 = blockIdx.x * 64;
    const int row0 = blockIdx.y * 128;
    const int wave = tid >> 6, lane = tid & 63;
    const int quad = lane >> 4, l16 = lane & 15;
    const int m_base = (wave >> 1) * 64, n_base = (wave & 1) * 32;
    const int kch = (quad ^ ((l16 >> 1) & 3)) * 8;
    f32x4 acc[4][2] = {};

    int    aldo[2];
    size_t agoff[2];
    #pragma unroll
    for (int i = 0; i < 2; ++i) {
        int slot = i * 256 + wave * 64 + lane;
        int row  = slot >> 2;
        int g    = (slot & 3) ^ ((slot >> 3) & 3);
        aldo[i]  = slot * 8;
        agoff[i] = (size_t)(row0 + row) * HD + g * 8;
    }
    int bldo; size_t bgoff;
    {
        int slot = wave * 64 + lane;
        int row  = slot >> 2;
        int g    = (slot & 3) ^ ((slot >> 3) & 3);
        bldo  = slot * 8;
        bgoff = (size_t)(col0 + row) * HD + g * 8;
    }
    auto stage = [&](int b, int k0) {
        #pragma unroll
        for (int i = 0; i < 2; ++i)
            GLOAD16(&xpB[agoff[i] + k0], &As[b][aldo[i]]);
        GLOAD16(&Wt[bgoff + k0], &Bs[b][bldo]);
    };

    stage(0, 0);
    __syncthreads();
    #pragma unroll 1
    for (int t = 0; t < 16; ++t) {
        const int cur = t & 1;
        if (t < 15) stage(cur ^ 1, (t + 1) * 32);
        bf16x8 af[4], bfr[2];
        #pragma unroll
        for (int i = 0; i < 4; ++i)
            af[i] = *(const bf16x8*)&As[cur][(m_base + i * 16 + l16) * 32 + kch];
        #pragma unroll
        for (int i = 0; i < 2; ++i)
            bfr[i] = *(const bf16x8*)&Bs[cur][(n_base + i * 16 + l16) * 32 + kch];
        #pragma unroll
        for (int mi = 0; mi < 4; ++mi)
            #pragma unroll
            for (int ni = 0; ni < 2; ++ni)
                acc[mi][ni] = __builtin_amdgcn_mfma_f32_16x16x32_bf16(af[mi], bfr[ni], acc[mi][ni], 0, 0, 0);
        __syncthreads();
    }
    const int which = blockIdx.x;
    float* dst = (which == 0) ? qh : (which == 1) ? kh : vh;
    const float scale = (which == 0) ? 0.35355339059327373f : 1.f;
    #pragma unroll
    for (int mi = 0; mi < 4; ++mi) {
        #pragma unroll
        for (int r = 0; r < 4; ++r) {
            int gr = row0 + m_base + mi * 16 + quad * 4 + r;
            #pragma unroll
            for (int ni = 0; ni < 2; ++ni) {
                int n = n_base + ni * 16 + l16;
                int hh = n >> 3, d = n & 7;
                dst[((size_t)hh * NP + gr) * DH + d] = acc[mi][ni][r] * scale;
            }
        }
    }
}

__global__ void cls_init(const float* __restrict__ cls, float* __restrict__ h)
{
    int t = blockIdx.x * 256 + threadIdx.x;
    if (t < HD) h[t] = cls[t];
}

__global__ void copy512(const float* __restrict__ src, float* __restrict__ dst)
{
    dst[threadIdx.x] = src[threadIdx.x];
}

// ------------------------------------------------------------------
// layernorm rows of h into xp (bf16): wave-per-row, shfl reduce.
// grid NP/4, 256 threads (4 waves = 4 rows)
// ------------------------------------------------------------------
__global__ __launch_bounds__(256) void ln_pad(const float* __restrict__ h,
                                              const float* __restrict__ g,
                                              const float* __restrict__ b,
                                              short* __restrict__ xp)
{
    const int wave = threadIdx.x >> 6, lane = threadIdx.x & 63;
    const int row = blockIdx.x * 4 + wave;
    short* dst = xp + (size_t)row * HD + lane * 8;
    if (row < PADR) {
        bf16x8 z = {};
        *(bf16x8*)dst = z;
        return;
    }
    const float* src = h + (size_t)(row - PADR) * HD + lane * 8;
    float4 v0 = *(const float4*)src;
    float4 v1 = *(const float4*)(src + 4);
    float v[8] = {v0.x, v0.y, v0.z, v0.w, v1.x, v1.y, v1.z, v1.w};
    float s = 0.f;
    #pragma unroll
    for (int i = 0; i < 8; ++i) s += v[i];
    #pragma unroll
    for (int o = 1; o < 64; o <<= 1) s += __shfl_xor(s, o);
    float mu = s * (1.f / HD);
    float ss = 0.f;
    #pragma unroll
    for (int i = 0; i < 8; ++i) { float d = v[i] - mu; ss += d * d; }
    #pragma unroll
    for (int o = 1; o < 64; o <<= 1) ss += __shfl_xor(ss, o);
    float inv = rsqrtf(ss * (1.f / HD) + 1e-5f);
    float4 g0 = *(const float4*)&g[lane * 8];
    float4 g1 = *(const float4*)&g[lane * 8 + 4];
    float4 b0 = *(const float4*)&b[lane * 8];
    float4 b1 = *(const float4*)&b[lane * 8 + 4];
    float gg[8] = {g0.x, g0.y, g0.z, g0.w, g1.x, g1.y, g1.z, g1.w};
    float bb[8] = {b0.x, b0.y, b0.z, b0.w, b1.x, b1.y, b1.z, b1.w};
    bf16x8 o;
    #pragma unroll
    for (int i = 0; i < 8; ++i) o[i] = f2bf((v[i] - mu) * inv * gg[i] + bb[i]);
    *(bf16x8*)dst = o;
}

// ------------------------------------------------------------------
// landmark means
// ------------------------------------------------------------------
__global__ void landmarks(const float* __restrict__ qh, const float* __restrict__ kh,
                          float* __restrict__ ql, float* __restrict__ kl)
{
    int idx = blockIdx.x * 256 + threadIdx.x;
    int sel = idx >> 14;
    int rem = idx & 16383;
    int h = rem >> 11;
    int i = (rem >> 3) & 255;
    int d = rem & 7;
    const float* src = sel ? kh : qh;
    size_t base = ((size_t)h * NP + (size_t)i * 77) * DH + d;
    float s = 0.f;
    for (int j = 0; j < 77; ++j) s += src[base + (size_t)j * DH];
    (sel ? kl : ql)[((size_t)h * NL + i) * DH + d] = s * (1.f / 77.f);
}

// ------------------------------------------------------------------
// attn2 = softmax(q_l @ k_l^T); scores are O(1) -> no max subtraction
// ------------------------------------------------------------------
__global__ void attn2_softmax(const float* __restrict__ ql, const float* __restrict__ kl,
                              float* __restrict__ a)
{
    const int i = blockIdx.x, h = blockIdx.y, j = threadIdx.x;
    __shared__ float sq[8];
    __shared__ float red[256];
    if (j < 8) sq[j] = ql[((size_t)h * NL + i) * DH + j];
    __syncthreads();
    const float* kr = kl + ((size_t)h * NL + j) * DH;
    float s = 0.f;
    #pragma unroll
    for (int d = 0; d < 8; ++d) s += sq[d] * kr[d];
    float e = __expf(s);
    red[j] = e;
    __syncthreads();
    for (int off = 128; off > 0; off >>= 1) {
        if (j < off) red[j] += red[j + off];
        __syncthreads();
    }
    a[((size_t)h * NL + i) * NL + j] = e / red[0];
}

// ------------------------------------------------------------------
// pinv init
// ------------------------------------------------------------------
__global__ void pinv_norms(const float* __restrict__ a, float* __restrict__ part)
{
    const int h = blockIdx.x & 7;
    const int mode = blockIdx.x >> 3;
    const int tid = threadIdx.x;
    const float* ah = a + (size_t)h * NL * NL;
    float s = 0.f;
    if (mode == 0) { for (int j = 0; j < NL; ++j) s += fabsf(ah[tid * NL + j]); }
    else           { for (int i = 0; i < NL; ++i) s += fabsf(ah[i * NL + tid]); }
    __shared__ float red[256];
    red[tid] = s;
    __syncthreads();
    for (int off = 128; off > 0; off >>= 1) {
        if (tid < off) red[tid] = fmaxf(red[tid], red[tid + off]);
        __syncthreads();
    }
    if (tid == 0) part[mode * 8 + h] = red[0];
}

__global__ void z0_init(const float* __restrict__ a, const float* __restrict__ part,
                        float* __restrict__ z)
{
    float s1 = part[0], s2 = part[8];
    #pragma unroll
    for (int h = 1; h < 8; ++h) { s1 = fmaxf(s1, part[h]); s2 = fmaxf(s2, part[8 + h]); }
    float inv = 1.f / (s1 * s2);
    int idx = blockIdx.x * 256 + threadIdx.x;
    int h = idx >> 16;
    int rem = idx & 65535;
    int i = rem >> 8, j = rem & 255;
    z[idx] = a[((size_t)h * NL + j) * NL + i] * inv;
}

// ------------------------------------------------------------------
// batched 256x256x256: D = A@B   grid (8,4,8)
// ------------------------------------------------------------------
__global__ void mm256(const float* __restrict__ A, const float* __restrict__ B,
                      float* __restrict__ D)
{
    const int h = blockIdx.z;
    const float* Ah = A + (size_t)h * NL * NL;
    const float* Bh = B + (size_t)h * NL * NL;
    float* Dh = D + (size_t)h * NL * NL;
    __shared__ __align__(16) float As[16][36];
    __shared__ __align__(16) float Bs[16][68];
    const int tid = threadIdx.x;
    const int tx = tid & 15, ty = tid >> 4;
    const int row0 = blockIdx.x * 32;
    const int col0 = blockIdx.y * 64;
    float acc[2][4] = {};
    const int ar = tid >> 3;
    const int ak = (tid & 7) * 2;
    const int bk = tid >> 4;
    const int bj = (tid & 15) * 4;
    for (int k0 = 0; k0 < NL; k0 += 16) {
        float2 av = *(const float2*)&Ah[(size_t)(row0 + ar) * NL + k0 + ak];
        As[ak][ar] = av.x; As[ak + 1][ar] = av.y;
        *(float4*)&Bs[bk][bj] = *(const float4*)&Bh[(size_t)(k0 + bk) * NL + col0 + bj];
        __syncthreads();
        #pragma unroll
        for (int k = 0; k < 16; ++k) {
            float2 a = *(const float2*)&As[k][ty * 2];
            float4 b = *(const float4*)&Bs[k][tx * 4];
            acc[0][0] += a.x * b.x; acc[0][1] += a.x * b.y; acc[0][2] += a.x * b.z; acc[0][3] += a.x * b.w;
            acc[1][0] += a.y * b.x; acc[1][1] += a.y * b.y; acc[1][2] += a.y * b.z; acc[1][3] += a.y * b.w;
        }
        __syncthreads();
    }
    #pragma unroll
    for (int r = 0; r < 2; ++r) {
        int gr = row0 + ty * 2 + r;
        #pragma unroll
        for (int c = 0; c < 4; ++c)
            Dh[(size_t)gr * NL + col0 + tx * 4 + c] = acc[r][c];
    }
}

// ------------------------------------------------------------------
// mmF: Paterson-Stockmeyer step + fused y-update (role-split).
// GEMM blocks (blockIdx.y<4):  wn = 0.25*(13w - 15S) + 0.25*S@(7w - S)
// y blocks (blockIdx.y==4):    y' = 13y - 15t + S@(7y - t), t = w@y
// grid (8, 5, 8)
// ------------------------------------------------------------------
__global__ __launch_bounds__(256) void mmF(const float* __restrict__ S,
                                           const float* __restrict__ w,
                                           float* __restrict__ wn,
                                           const float* __restrict__ yin,
                                           float* __restrict__ yout)
{
    const int h = blockIdx.z;
    const int tid = threadIdx.x;
    if (blockIdx.y == 4) {
        __shared__ float yL[NL * 9];
        __shared__ float tL[NL * 9];
        __shared__ float uL[NL * 9];
        const int s = blockIdx.x;
        const float* yh = yin + (size_t)h * NL * DH;
        #pragma unroll
        for (int i = 0; i < 8; ++i) {
            int idx = tid + 256 * i;
            yL[(idx >> 3) * 9 + (idx & 7)] = yh[idx];
        }
        __syncthreads();
        const float* wr = w + ((size_t)h * NL + tid) * NL;
        float t1[8] = {};
        for (int j = 0; j < NL; j += 4) {
            float4 wv = *(const float4*)&wr[j];
            #pragma unroll
            for (int d = 0; d < 8; ++d)
                t1[d] += wv.x * yL[j * 9 + d] + wv.y * yL[(j + 1) * 9 + d]
                       + wv.z * yL[(j + 2) * 9 + d] + wv.w * yL[(j + 3) * 9 + d];
        }
        #pragma unroll
        for (int d = 0; d < 8; ++d) {
            tL[tid * 9 + d] = t1[d];
            uL[tid * 9 + d] = 7.f * yL[tid * 9 + d] - t1[d];
        }
        __syncthreads();
        const int r = s * 32 + (tid >> 3), d = tid & 7;
        const float* Sr = S + ((size_t)h * NL + r) * NL;
        float acc = 13.f * yL[r * 9 + d] - 15.f * tL[r * 9 + d];
        for (int j = 0; j < NL; j += 4) {
            float4 sv = *(const float4*)&Sr[j];
            acc += sv.x * uL[j * 9 + d] + sv.y * uL[(j + 1) * 9 + d]
                 + sv.z * uL[(j + 2) * 9 + d] + sv.w * uL[(j + 3) * 9 + d];
        }
        yout[((size_t)h * NL + r) * DH + d] = acc;
        return;
    }
    const float* Sh = S + (size_t)h * NL * NL;
    const float* wh = w + (size_t)h * NL * NL;
    float* Dh = wn + (size_t)h * NL * NL;
    __shared__ __align__(16) float As[16][36];
    __shared__ __align__(16) float Bs[16][68];
    const int tx = tid & 15, ty = tid >> 4;
    const int row0 = blockIdx.x * 32;
    const int col0 = blockIdx.y * 64;
    float acc[2][4] = {};
    const int ar = tid >> 3;
    const int ak = (tid & 7) * 2;
    const int bk = tid >> 4;
    const int bj = (tid & 15) * 4;
    for (int k0 = 0; k0 < NL; k0 += 16) {
        float2 av = *(const float2*)&Sh[(size_t)(row0 + ar) * NL + k0 + ak];
        As[ak][ar] = av.x; As[ak + 1][ar] = av.y;
        size_t bo = (size_t)(k0 + bk) * NL + col0 + bj;
        float4 bw = *(const float4*)&wh[bo];
        float4 bs = *(const float4*)&Sh[bo];
        Bs[bk][bj]     = 7.f * bw.x - bs.x;
        Bs[bk][bj + 1] = 7.f * bw.y - bs.y;
        Bs[bk][bj + 2] = 7.f * bw.z - bs.z;
        Bs[bk][bj + 3] = 7.f * bw.w - bs.w;
        __syncthreads();
        #pragma unroll
        for (int k = 0; k < 16; ++k) {
            float2 a = *(const float2*)&As[k][ty * 2];
            float4 b = *(const float4*)&Bs[k][tx * 4];
            acc[0][0] += a.x * b.x; acc[0][1] += a.x * b.y; acc[0][2] += a.x * b.z; acc[0][3] += a.x * b.w;
            acc[1][0] += a.y * b.x; acc[1][1] += a.y * b.y; acc[1][2] += a.y * b.z; acc[1][3] += a.y * b.w;
        }
        __syncthreads();
    }
    #pragma unroll
    for (int r = 0; r < 2; ++r) {
        int gr = row0 + ty * 2 + r;
        #pragma unroll
        for (int c = 0; c < 4; ++c) {
            int gc = col0 + tx * 4 + c;
            size_t o = (size_t)gr * NL + gc;
            Dh[o] = 0.25f * (13.f * wh[o] - 15.f * Sh[o] + acc[r][c]);
        }
    }
}

// ------------------------------------------------------------------
// y' = P(w)y = 13y - 15*t1 + S@(7y - t1), t1 = w@y.  (last iteration)
// grid (8 slices, 8 heads)
// ------------------------------------------------------------------
__global__ __launch_bounds__(256) void yiter(const float* __restrict__ w,
                                             const float* __restrict__ S,
                                             const float* __restrict__ yin,
                                             float* __restrict__ yout)
{
    const int s = blockIdx.x, h = blockIdx.y, tid = threadIdx.x;
    __shared__ float yL[NL * 9];
    __shared__ float tL[NL * 9];
    __shared__ float uL[NL * 9];
    const float* yh = yin + (size_t)h * NL * DH;
    #pragma unroll
    for (int i = 0; i < 8; ++i) {
        int idx = tid + 256 * i;
        yL[(idx >> 3) * 9 + (idx & 7)] = yh[idx];
    }
    __syncthreads();
    const float* wr = w + ((size_t)h * NL + tid) * NL;
    float t1[8] = {};
    for (int j = 0; j < NL; j += 4) {
        float4 wv = *(const float4*)&wr[j];
        #pragma unroll
        for (int d = 0; d < 8; ++d)
            t1[d] += wv.x * yL[j * 9 + d] + wv.y * yL[(j + 1) * 9 + d]
                   + wv.z * yL[(j + 2) * 9 + d] + wv.w * yL[(j + 3) * 9 + d];
    }
    #pragma unroll
    for (int d = 0; d < 8; ++d) {
        tL[tid * 9 + d] = t1[d];
        uL[tid * 9 + d] = 7.f * yL[tid * 9 + d] - t1[d];
    }
    __syncthreads();
    const int r = s * 32 + (tid >> 3), d = tid & 7;
    const float* Sr = S + ((size_t)h * NL + r) * NL;
    float acc = 13.f * yL[r * 9 + d] - 15.f * tL[r * 9 + d];
    for (int j = 0; j < NL; j += 4) {
        float4 sv = *(const float4*)&Sr[j];
        acc += sv.x * uL[j * 9 + d] + sv.y * uL[(j + 1) * 9 + d]
             + sv.z * uL[(j + 2) * 9 + d] + sv.w * uL[(j + 3) * 9 + d];
    }
    yout[((size_t)h * NL + r) * DH + d] = acc;
}

// ------------------------------------------------------------------
// vout[h] = scale * M[h] @ vin[h];  M: [8][256][256], v: [8][256][8]
// ------------------------------------------------------------------
__global__ void polyv(const float* __restrict__ M, const float* __restrict__ vin,
                      float* __restrict__ vout, float scale)
{
    const int h = blockIdx.y;
    __shared__ float vs[NL * DH];
    const int tid = threadIdx.x;
    const float* vh = vin + (size_t)h * NL * DH;
    #pragma unroll
    for (int i = 0; i < 8; ++i) vs[tid + 256 * i] = vh[tid + 256 * i];
    __syncthreads();
    const int row = blockIdx.x * 32 + (tid >> 3);
    const int d = tid & 7;
    const float* Mr = M + ((size_t)h * NL + row) * NL;
    float acc = 0.f;
    #pragma unroll 4
    for (int j = 0; j < NL; j += 4) {
        float4 m = *(const float4*)&Mr[j];
        acc += m.x * vs[j * 8 + d]      + m.y * vs[j * 8 + 8 + d]
             + m.z * vs[j * 8 + 16 + d] + m.w * vs[j * 8 + 24 + d];
    }
    vout[((size_t)h * NL + row) * DH + d] = acc * scale;
}

// ------------------------------------------------------------------
// attn3 @ v, single K/V pass: grid (77 chunks, 8 heads).
// ------------------------------------------------------------------
__global__ __launch_bounds__(256) void attn3v(const float* __restrict__ kh,
                                              const float* __restrict__ vh,
                                              const float* __restrict__ ql,
                                              float* __restrict__ part)
{
    const int ck = blockIdx.x, h = blockIdx.y, tid = threadIdx.x;
    __shared__ __align__(16) float4 kv[A3CHK][4];   // [t]: k0 k1 v0 v1
    const float* kb = kh + ((size_t)h * NP + (size_t)ck * A3CHK) * DH;
    const float* vb = vh + ((size_t)h * NP + (size_t)ck * A3CHK) * DH;
    #pragma unroll
    for (int i = 0; i < 2; ++i) {
        int idx = tid + 256 * i;          // 0..511
        int t = idx >> 1, p = idx & 1;
        kv[t][p]     = *(const float4*)&kb[t * 8 + p * 4];
        kv[t][2 + p] = *(const float4*)&vb[t * 8 + p * 4];
    }
    float q[8];
    const float* qp = ql + ((size_t)h * NL + tid) * DH;
    #pragma unroll
    for (int d = 0; d < 8; ++d) q[d] = qp[d];
    __syncthreads();
    float den = 0.f;
    float4 a0 = make_float4(0.f, 0.f, 0.f, 0.f);
    float4 a1 = make_float4(0.f, 0.f, 0.f, 0.f);
    #pragma unroll 4
    for (int t = 0; t < A3CHK; ++t) {
        float4 k0 = kv[t][0], k1 = kv[t][1];
        float s = q[0] * k0.x + q[1] * k0.y + q[2] * k0.z + q[3] * k0.w
                + q[4] * k1.x + q[5] * k1.y + q[6] * k1.z + q[7] * k1.w;
        float e = __expf(s);
        den += e;
        float4 v0 = kv[t][2], v1 = kv[t][3];
        F4MAD(a0, e, v0); F4MAD(a1, e, v1);
    }
    float* p = part + (((size_t)h * A3NB + ck) * NL + tid) * 9;
    p[0] = den;
    p[1] = a0.x; p[2] = a0.y; p[3] = a0.z; p[4] = a0.w;
    p[5] = a1.x; p[6] = a1.y; p[7] = a1.z; p[8] = a1.w;
}

// merge 77 chunks -> y0[h][i][d]; grid (8 heads, 8 i-slices), thread=(i,d)
__global__ void attn3v_merge(const float* __restrict__ part, float* __restrict__ y)
{
    const int h = blockIdx.x;
    const int i = blockIdx.y * 32 + (threadIdx.x >> 3);
    const int d = threadIdx.x & 7;
    float acc = 0.f, den = 0.f;
    const float* p = part + ((size_t)h * A3NB * NL + i) * 9;
    for (int ck = 0; ck < A3NB; ++ck) {
        const float* q = p + (size_t)ck * NL * 9;
        den += q[0];
        acc += q[1 + d];
    }
    y[((size_t)h * NL + i) * DH + d] = acc / den;
}

// ------------------------------------------------------------------
// attn1 fused + dwconv33(v): 1 lane = 1 token; kl/zw broadcast from LDS
// (wave-uniform addr -> conflict-free). grid (77, 8), 256 threads.
// ------------------------------------------------------------------
__global__ __launch_bounds__(256) void attn1_conv(const float* __restrict__ qh,
                                                  const float* __restrict__ vh,
                                                  const float* __restrict__ klg,
                                                  const float* __restrict__ zwg,
                                                  const float* __restrict__ rw,
                                                  float* __restrict__ aout)
{
    const int h = blockIdx.y;
    __shared__ __align__(16) float kl[NL * DH];
    __shared__ __align__(16) float zw[NL * DH];
    const int tid = threadIdx.x;
    #pragma unroll
    for (int q = 0; q < 8; ++q) {
        kl[tid + 256 * q] = klg[(size_t)h * NL * DH + tid + 256 * q];
        zw[tid + 256 * q] = zwg[(size_t)h * NL * DH + tid + 256 * q];
    }
    __syncthreads();
    const int r = blockIdx.x * 256 + tid;
    if (r >= NT) return;
    const int t = r + PADR;
    const float* qp = qh + ((size_t)h * NP + t) * DH;
    float4 q0 = *(const float4*)qp;
    float4 q1 = *(const float4*)(qp + 4);
    float den = 0.f;
    float4 acc0 = make_float4(0.f, 0.f, 0.f, 0.f);
    float4 acc1 = make_float4(0.f, 0.f, 0.f, 0.f);
    #pragma unroll 4
    for (int i = 0; i < NL; ++i) {
        float4 k0 = *(const float4*)&kl[i * 8];
        float4 k1 = *(const float4*)&kl[i * 8 + 4];
        float s = q0.x * k0.x + q0.y * k0.y + q0.z * k0.z + q0.w * k0.w
                + q1.x * k1.x + q1.y * k1.y + q1.z * k1.z + q1.w * k1.w;
        float e = __expf(s);
        den += e;
        float4 z0 = *(const float4*)&zw[i * 8];
        float4 z1 = *(const float4*)&zw[i * 8 + 4];
        F4MAD(acc0, e, z0); F4MAD(acc1, e, z1);
    }
    float inv = 1.f / den;
    const float* vb = vh + (size_t)h * NP * DH;
    float4 c0 = make_float4(0.f, 0.f, 0.f, 0.f);
    float4 c1 = make_float4(0.f, 0.f, 0.f, 0.f);
    #pragma unroll
    for (int j = 0; j < 33; ++j) {
        int tp = t - 16 + j;
        if (tp >= NP) continue;
        float wv = rw[h * 33 + j];
        float4 v0 = *(const float4*)&vb[(size_t)tp * 8];
        float4 v1 = *(const float4*)&vb[(size_t)tp * 8 + 4];
        F4MAD(c0, wv, v0); F4MAD(c1, wv, v1);
    }
    float* op = aout + (size_t)r * 64 + h * 8;
    *(float4*)op = make_float4(acc0.x * inv + c0.x, acc0.y * inv + c0.y,
                               acc0.z * inv + c0.z, acc0.w * inv + c0.w);
    *(float4*)(op + 4) = make_float4(acc1.x * inv + c1.x, acc1.y * inv + c1.y,
                                     acc1.z * inv + c1.z, acc1.w * inv + c1.w);
}

// ------------------------------------------------------------------
// out-proj + residual: 16 rows/block
// ------------------------------------------------------------------
__global__ void outproj(const float* __restrict__ aout, const float* __restrict__ W,
                        const float* __restrict__ bias, float* __restrict__ h)
{
    const int r0 = blockIdx.x * 16;
    const int tid = threadIdx.x;   // 512
    __shared__ float ao[16][64];
    #pragma unroll
    for (int s = 0; s < 2; ++s) {
        int idx = tid + s * 512;
        int rr = idx >> 6, kk = idx & 63;
        int gr = r0 + rr;
        ao[rr][kk] = (gr < NT) ? aout[(size_t)gr * 64 + kk] : 0.f;
    }
    __syncthreads();
    float acc[16] = {};
    for (int k = 0; k < 64; ++k) {
        float wv = W[(size_t)k * HD + tid];
        #pragma unroll
        for (int r = 0; r < 16; ++r) acc[r] += ao[r][k] * wv;
    }
    float bv = bias[tid];
    #pragma unroll
    for (int r = 0; r < 16; ++r) {
        int gr = r0 + r;
        if (gr < NT) h[(size_t)gr * HD + tid] += acc[r] + bv;
    }
}

// ------------------------------------------------------------------
// PPEG weight prep (identity tap folded at center)
// ------------------------------------------------------------------
__global__ void ppeg_wprep(const float* __restrict__ w7, const float* __restrict__ b7,
                           const float* __restrict__ w5, const float* __restrict__ b5,
                           const float* __restrict__ w3, const float* __restrict__ b3,
                           float* __restrict__ wc, float* __restrict__ bsum)
{
    int idx = blockIdx.x * 256 + threadIdx.x;
    if (idx < HD * 49) {
        int c = idx / 49, t = idx - c * 49;
        int dy = t / 7 - 3, dx = t % 7 - 3;
        float v = w7[idx];
        if (dy >= -2 && dy <= 2 && dx >= -2 && dx <= 2) v += w5[c * 25 + (dy + 2) * 5 + (dx + 2)];
        if (dy >= -1 && dy <= 1 && dx >= -1 && dx <= 1) v += w3[c * 9 + (dy + 1) * 3 + (dx + 1)];
        if (t == 24) v += 1.f;
        wc[idx] = v;
    } else if (idx < HD * 49 + HD) {
        int c = idx - HD * 49;
        bsum[c] = b7[c] + b5[c] + b3[c];
    }
}

// ------------------------------------------------------------------
// ppeg_direct: fused dwconv 7x7 in token-major layout (replaces
// t1/conv/t2 x 4 chunks = 12 launches). Block = 16x16 spatial x 16 ch.
// LDS tile 22x22 halo, 20-float slots (16B-aligned, ~2-way banks).
// out(gy,gx,c) = bsum[c] + sum_{dy,dx} wc[c][dy*7+dx] * in(gy-3+dy, gx-3+dx, c)
// grid (9, 9, 32), 256 threads.
// ------------------------------------------------------------------
__global__ __launch_bounds__(256) void ppeg_direct(const float* __restrict__ hin,
                                                   const float* __restrict__ wc,
                                                   const float* __restrict__ bsum,
                                                   float* __restrict__ hout)
{
    __shared__ __align__(16) float in_sh[PHH * PHW * PSLOT];   // 38.7 KB
    __shared__ float wL[49 * PCC];                             // [tap][c]
    const int tid = threadIdx.x;
    const int tx0 = blockIdx.x * PTW;
    const int ty0 = blockIdx.y * PTH;
    const int c0  = blockIdx.z * PCC;
    for (int i = tid; i < 49 * PCC; i += 256) {
        int c = i / 49, tap = i - c * 49;
        wL[tap * PCC + c] = wc[(size_t)(c0 + c) * 49 + tap];
    }
    for (int idx = tid; idx < PHH * PHW * 4; idx += 256) {
        int pos = idx >> 2, q = idx & 3;
        int ly = pos / PHW, lx = pos - ly * PHW;
        int gy = ty0 - 3 + ly, gx = tx0 - 3 + lx;
        float4 v = make_float4(0.f, 0.f, 0.f, 0.f);
        if (gy >= 0 && gy < SIDE && gx >= 0 && gx < SIDE)
            v = *(const float4*)&hin[(size_t)(1 + gy * SIDE + gx) * HD + c0 + q * 4];
        *(float4*)&in_sh[pos * PSLOT + q * 4] = v;
    }
    __syncthreads();
    const int y  = tid >> 4;         // 0..15
    const int x4 = (tid >> 2) & 3;   // 0..3
    const int c4 = tid & 3;          // 0..3
    const int xb = x4 * 4;
    float4 acc[4] = {make_float4(0.f,0.f,0.f,0.f), make_float4(0.f,0.f,0.f,0.f),
                     make_float4(0.f,0.f,0.f,0.f), make_float4(0.f,0.f,0.f,0.f)};
    #pragma unroll 1
    for (int dy = 0; dy < 7; ++dy) {
        float4 row[10];
        #pragma unroll
        for (int k = 0; k < 10; ++k)
            row[k] = *(const float4*)&in_sh[((y + dy) * PHW + xb + k) * PSLOT + c4 * 4];
        #pragma unroll
        for (int dx = 0; dx < 7; ++dx) {
            float4 wv = *(const float4*)&wL[(dy * 7 + dx) * PCC + c4 * 4];
            #pragma unroll
            for (int xi = 0; xi < 4; ++xi) F4FMA(acc[xi], wv, row[xi + dx]);
        }
    }
    const int gy = ty0 + y;
    if (gy >= SIDE) return;
    float4 bv = *(const float4*)&bsum[c0 + c4 * 4];
    #pragma unroll
    for (int xi = 0; xi < 4; ++xi) {
        int gx = tx0 + xb + xi;
        if (gx >= SIDE) continue;
        float4 o = make_float4(acc[xi].x + bv.x, acc[xi].y + bv.y,
                               acc[xi].z + bv.z, acc[xi].w + bv.w);
        *(float4*)&hout[(size_t)(1 + gy * SIDE + gx) * HD + c0 + c4 * 4] = o;
    }
}

// ------------------------------------------------------------------
// final layernorm of row 0
// ------------------------------------------------------------------
__global__ void final_ln(const float* __restrict__ h, const float* __restrict__ g,
                         const float* __restrict__ b, float* __restrict__ out)
{
    const int tid = threadIdx.x;
    float v0 = h[tid], v1 = h[tid + 256];
    __shared__ float red[256];
    red[tid] = v0 + v1;
    __syncthreads();
    for (int off = 128; off > 0; off >>= 1) {
        if (tid < off) red[tid] += red[tid + off];
        __syncthreads();
    }
    float mu = red[0] * (1.f / HD);
    __syncthreads();
    float d0 = v0 - mu, d1 = v1 - mu;
    red[tid] = d0 * d0 + d1 * d1;
    __syncthreads();
    for (int off = 128; off > 0; off >>= 1) {
        if (tid < off) red[tid] += red[tid + off];
        __syncthreads();
    }
    float inv = rsqrtf(red[0] * (1.f / HD) + 1e-5f);
    out[tid]       = d0 * inv * g[tid] + b[tid];
    out[tid + 256] = d1 * inv * g[tid + 256] + b[tid + 256];
}

} // namespace

extern "C" void kernel_launch(void* const* d_in, const int* in_sizes, int n_in,
                              void* d_out, int out_size, void* d_ws, size_t ws_size,
                              hipStream_t stream)
{
    const float* x      = (const float*)d_in[0];
    const float* fc1_w  = (const float*)d_in[1];
    const float* fc1_b  = (const float*)d_in[2];
    const float* cls    = (const float*)d_in[3];
    const float* l1_g   = (const float*)d_in[4];
    const float* l1_bb  = (const float*)d_in[5];
    const float* l1_qkv = (const float*)d_in[6];
    const float* l1_ow  = (const float*)d_in[7];
    const float* l1_ob  = (const float*)d_in[8];
    const float* l1_rw  = (const float*)d_in[9];
    const float* l2_g   = (const float*)d_in[10];
    const float* l2_bb  = (const float*)d_in[11];
    const float* l2_qkv = (const float*)d_in[12];
    const float* l2_ow  = (const float*)d_in[13];
    const float* l2_ob  = (const float*)d_in[14];
    const float* l2_rw  = (const float*)d_in[15];
    const float* p7w    = (const float*)d_in[16];
    const float* p7b    = (const float*)d_in[17];
    const float* p5w    = (const float*)d_in[18];
    const float* p5b    = (const float*)d_in[19];
    const float* p3w    = (const float*)d_in[20];
    const float* p3b    = (const float*)d_in[21];
    const float* ng     = (const float*)d_in[22];
    const float* nb     = (const float*)d_in[23];
    float* out = (float*)d_out;

    char* ws = (char*)d_ws;
    size_t off = 0;
    auto alloc = [&](size_t bytes) {
        char* p = ws + off;
        off += (bytes + 255) & ~(size_t)255;
        return (void*)p;
    };
    float* bufA = (float*)alloc((size_t)NP * HD * 4);
    float* bufB = (float*)alloc((size_t)NP * HD * 4);
    float* qh   = (float*)alloc((size_t)NH * NP * DH * 4);
    float* kh   = (float*)alloc((size_t)NH * NP * DH * 4);
    float* vh   = (float*)alloc((size_t)NH * NP * DH * 4);
    float* aout = (float*)alloc((size_t)NP * 64 * 4);
    float* ql   = (float*)alloc((size_t)NH * NL * DH * 4);
    float* klm  = (float*)alloc((size_t)NH * NL * DH * 4);
    float* ybuf = (float*)alloc((size_t)NH * NL * DH * 4);
    float* ybuf2= (float*)alloc((size_t)NH * NL * DH * 4);
    float* zwb  = (float*)alloc((size_t)NH * NL * DH * 4);
    float* a2   = (float*)alloc((size_t)NH * NL * NL * 4);
    float* zb0  = (float*)alloc((size_t)NH * NL * NL * 4);   // z0 (kept for final)
    float* azb  = (float*)alloc((size_t)NH * NL * NL * 4);   // w ping
    float* tb   = (float*)alloc((size_t)NH * NL * NL * 4);   // w pong
    float* ub   = (float*)alloc((size_t)NH * NL * NL * 4);   // S = w@w
    float* part = (float*)alloc(256);
    float* a3p  = (float*)alloc((size_t)NH * A3NB * NL * 9 * 4);
    float* wcomb = (float*)alloc((size_t)HD * 49 * 4);
    float* bsum  = (float*)alloc((size_t)HD * 4);
    short* wt1   = (short*)alloc((size_t)HD * ID * 2);
    short* wtq   = (short*)alloc((size_t)192 * HD * 2);
    short* xb    = (short*)alloc((size_t)NP * ID * 2);   // NP rows: fc1 A-tiles may read past NPIX
    short* xpB   = (short*)alloc((size_t)NP * HD * 2);
    (void)ws_size; (void)in_sizes; (void)n_in; (void)out_size;

    castX<<<(NPIX * ID / 8) / 256, 256, 0, stream>>>(x, xb);
    castT<<<dim3(HD / 32, ID / 32), 256, 0, stream>>>(fc1_w, wt1, ID, HD);
    gemm_fc1<<<dim3(4, 154), 256, 0, stream>>>(xb, wt1, fc1_b, bufA);
    cls_init<<<2, 256, 0, stream>>>(cls, bufA);

    auto attention = [&](float* hbuf, const float* lg, const float* lb,
                         const float* qkvw, const float* ow, const float* ob,
                         const float* rw) {
        ln_pad<<<NP / 4, 256, 0, stream>>>(hbuf, lg, lb, xpB);
        castT<<<dim3(192 / 32, HD / 32), 256, 0, stream>>>(qkvw, wtq, HD, 192);
        gemm_qkv<<<dim3(3, 154), 256, 0, stream>>>(xpB, wtq, qh, kh, vh);
        landmarks<<<128, 256, 0, stream>>>(qh, kh, ql, klm);
        attn2_softmax<<<dim3(NL, NH), 256, 0, stream>>>(ql, klm, a2);
        pinv_norms<<<16, 256, 0, stream>>>(a2, part);
        z0_init<<<2048, 256, 0, stream>>>(a2, part, zb0);
        // y0 = attn3 @ v (single K/V pass + parallel merge)
        attn3v<<<dim3(A3NB, NH), 256, 0, stream>>>(kh, vh, ql, a3p);
        attn3v_merge<<<dim3(NH, 8), 256, 0, stream>>>(a3p, ybuf);
        // w-space Newton-Schulz, w0 = a@z0; Paterson-Stockmeyer:
        //   S = w@w;  w' = 0.25(13w - 15S) + 0.25 S@(7w - S)  [mmF, fused y role]
        mm256<<<dim3(8, 4, 8), 256, 0, stream>>>(a2, zb0, azb);
        float* wc = azb;
        float* wn = tb;
        float* yc = ybuf;
        float* yn = ybuf2;
        for (int it = 0; it < 6; ++it) {
            mm256<<<dim3(8, 4, 8), 256, 0, stream>>>(wc, wc, ub);       // S
            if (it < 5) {
                mmF<<<dim3(8, 5, 8), 256, 0, stream>>>(ub, wc, wn, yc, yn);
                { float* t = yc; yc = yn; yn = t; }
                { float* t = wc; wc = wn; wn = t; }
            } else {
                yiter<<<dim3(8, 8), 256, 0, stream>>>(wc, ub, yc, yn);
                { float* t = yc; yc = yn; yn = t; }
            }
        }
        // zw = 4^-6 * z0 @ y6
        polyv<<<dim3(8, NH), 256, 0, stream>>>(zb0, yc, zwb, 2.44140625e-4f);
        attn1_conv<<<dim3(77, NH), 256, 0, stream>>>(qh, vh, klm, zwb, rw, aout);
        outproj<<<(NT + 15) / 16, 512, 0, stream>>>(aout, ow, ob, hbuf);
    };

    attention(bufA, l1_g, l1_bb, l1_qkv, l1_ow, l1_ob, l1_rw);

    ppeg_wprep<<<(HD * 49 + HD + 255) / 256, 256, 0, stream>>>(p7w, p7b, p5w, p5b, p3w, p3b,
                                                               wcomb, bsum);
    copy512<<<1, 512, 0, stream>>>(bufA, bufB);
    ppeg_direct<<<dim3((SIDE + PTW - 1) / PTW, (SIDE + PTH - 1) / PTH, HD / PCC),
                  256, 0, stream>>>(bufA, wcomb, bsum, bufB);

    attention(bufB, l2_g, l2_bb, l2_qkv, l2_ow, l2_ob, l2_rw);
    final_ln<<<1, 256, 0, stream>>>(bufB, ng, nb, out);
}

// Round 10
// 1021.325 us; speedup vs baseline: 1.3628x; 1.0104x over previous
//
#include <hip/hip_runtime.h>

namespace {

constexpr int NP   = 19712;   // padded tokens (Nystrom)
constexpr int NT   = 19601;   // tokens incl cls
constexpr int NPIX = 19600;   // feature tokens (140x140)
constexpr int HD   = 512;     // hidden dim
constexpr int ID   = 1024;    // input dim
constexpr int NH   = 8;       // heads
constexpr int DH   = 8;       // dim per head
constexpr int NL   = 256;     // landmarks
constexpr int PADR = 111;     // left zero-pad rows
constexpr int SIDE = 140;
constexpr int A3CHK = 256;    // attn3v tokens per block
constexpr int A3NB  = NP / A3CHK;   // 77 chunks

// ppeg_direct tiling
constexpr int PTW = 16, PTH = 16, PCC = 16;   // tile w, h, channels
constexpr int PHW = PTW + 6, PHH = PTH + 6;   // 22x22 incl halo
constexpr int PSLOT = 20;                     // floats per (y,x) slot (16 used; 16B-aligned pad)

typedef __attribute__((ext_vector_type(8))) short bf16x8;
typedef __attribute__((ext_vector_type(4))) float f32x4;

#define F4MAD(a, s, v) { (a).x += (s)*(v).x; (a).y += (s)*(v).y; (a).z += (s)*(v).z; (a).w += (s)*(v).w; }
// NOTE: param must NOT be named 'w' -- macro substitution would capture the .w field (R6 compile bug)
#define F4FMA(a, ww, v) { (a).x += (ww).x*(v).x; (a).y += (ww).y*(v).y; (a).z += (ww).z*(v).z; (a).w += (ww).w*(v).w; }

// async global->LDS, 16B per lane; LDS dest must be wave-uniform base + lane*16
#define GLOAD16(gptr, lptr) \
    __builtin_amdgcn_global_load_lds((const __attribute__((address_space(1))) void*)(gptr), \
                                     (__attribute__((address_space(3))) void*)(lptr), 16, 0, 0)

__device__ inline short f2bf(float f) {
    union { float f; unsigned u; } v; v.f = f;
    unsigned r = v.u + 0x7fffu + ((v.u >> 16) & 1u);
    return (short)(r >> 16);
}

// ------------------------------------------------------------------
// cast X fp32 -> bf16 elementwise
// ------------------------------------------------------------------
__global__ void castX(const float* __restrict__ src, short* __restrict__ dst)
{
    size_t c = (size_t)blockIdx.x * 256 + threadIdx.x;
    const float4 x0 = *(const float4*)&src[c * 8];
    const float4 x1 = *(const float4*)&src[c * 8 + 4];
    bf16x8 p;
    p[0] = f2bf(x0.x); p[1] = f2bf(x0.y); p[2] = f2bf(x0.z); p[3] = f2bf(x0.w);
    p[4] = f2bf(x1.x); p[5] = f2bf(x1.y); p[6] = f2bf(x1.z); p[7] = f2bf(x1.w);
    *(bf16x8*)&dst[c * 8] = p;
}

// ------------------------------------------------------------------
// cast+transpose: dst[c][r] = bf16(src[r][c]); grid (C/32, R/32)
// ------------------------------------------------------------------
__global__ void castT(const float* __restrict__ src, short* __restrict__ dst, int R, int C)
{
    __shared__ float t[32][33];
    const int tx = threadIdx.x & 31, ty = threadIdx.x >> 5;
    const int c0 = blockIdx.x * 32, r0 = blockIdx.y * 32;
    #pragma unroll
    for (int j = 0; j < 4; ++j)
        t[ty + 8 * j][tx] = src[(size_t)(r0 + ty + 8 * j) * C + c0 + tx];
    __syncthreads();
    #pragma unroll
    for (int j = 0; j < 4; ++j)
        dst[(size_t)(c0 + ty + 8 * j) * R + r0 + tx] = f2bf(t[tx][ty + 8 * j]);
}

// ------------------------------------------------------------------
// fc1 MFMA: 128x128 tile, BK=32, 2-phase dbuf global_load_lds.
// grid (4, 154) -- measured-best mapping (R3/R5: ~53us, 0 conflicts).
// ------------------------------------------------------------------
__global__ __launch_bounds__(256) void gemm_fc1(const short* __restrict__ Xb,
                                                const short* __restrict__ Wt,
                                                const float* __restrict__ bias,
                                                float* __restrict__ out)
{
    __shared__ __align__(16) short As[2][128 * 32];
    __shared__ __align__(16) short Bs[2][128 * 32];
    const int tid  = threadIdx.x;
    const int col0 = blockIdx.x * 128;
    const int row0 = blockIdx.y * 128;
    const int wave = tid >> 6, lane = tid & 63;
    const int quad = lane >> 4, l16 = lane & 15;
    const int m_base = (wave >> 1) * 64, n_base = (wave & 1) * 64;
    const int kch = (quad ^ ((l16 >> 1) & 3)) * 8;   // swizzled k-chunk (shorts)
    f32x4 acc[4][4] = {};

    int    aldo[2];
    size_t agoff[2], bgoff[2];
    #pragma unroll
    for (int i = 0; i < 2; ++i) {
        int slot = i * 256 + wave * 64 + lane;
        int row  = slot >> 2;
        int g    = (slot & 3) ^ ((slot >> 3) & 3);
        aldo[i]  = slot * 8;
        agoff[i] = (size_t)(row0 + row) * ID + g * 8;
        bgoff[i] = (size_t)(col0 + row) * ID + g * 8;
    }
    auto stage = [&](int b, int k0) {
        #pragma unroll
        for (int i = 0; i < 2; ++i) {
            GLOAD16(&Xb[agoff[i] + k0], &As[b][aldo[i]]);
            GLOAD16(&Wt[bgoff[i] + k0], &Bs[b][aldo[i]]);
        }
    };

    stage(0, 0);
    __syncthreads();
    #pragma unroll 1
    for (int t = 0; t < 32; ++t) {
        const int cur = t & 1;
        if (t < 31) stage(cur ^ 1, (t + 1) * 32);
        bf16x8 af[4], bfr[4];
        #pragma unroll
        for (int i = 0; i < 4; ++i) {
            af[i]  = *(const bf16x8*)&As[cur][(m_base + i * 16 + l16) * 32 + kch];
            bfr[i] = *(const bf16x8*)&Bs[cur][(n_base + i * 16 + l16) * 32 + kch];
        }
        #pragma unroll
        for (int mi = 0; mi < 4; ++mi)
            #pragma unroll
            for (int ni = 0; ni < 4; ++ni)
                acc[mi][ni] = __builtin_amdgcn_mfma_f32_16x16x32_bf16(af[mi], bfr[ni], acc[mi][ni], 0, 0, 0);
        __syncthreads();
    }
    #pragma unroll
    for (int mi = 0; mi < 4; ++mi) {
        #pragma unroll
        for (int r = 0; r < 4; ++r) {
            int gr = row0 + m_base + mi * 16 + quad * 4 + r;
            if (gr >= NPIX) continue;
            #pragma unroll
            for (int ni = 0; ni < 4; ++ni) {
                int gc = col0 + n_base + ni * 16 + l16;
                float v = acc[mi][ni][r] + bias[gc];
                v = 0.5f * v * (1.f + erff(v * 0.70710678118654752f));
                out[(size_t)(gr + 1) * HD + gc] = v;
            }
        }
    }
}

// ------------------------------------------------------------------
// qkv MFMA fused-N: one pass over X, all 192 output cols per block.
// M-tile 64, BK=32, 2-phase dbuf, grid (308). X fetched once (~21MB
// vs 60MB for the 3-panel split).
// ------------------------------------------------------------------
__global__ __launch_bounds__(256) void gemm_qkv(const short* __restrict__ xpB,
                                                const short* __restrict__ Wt,
                                                float* __restrict__ qh,
                                                float* __restrict__ kh,
                                                float* __restrict__ vh)
{
    __shared__ __align__(16) short As[2][64 * 32];
    __shared__ __align__(16) short Bs[2][192 * 32];
    const int tid  = threadIdx.x;
    const int row0 = blockIdx.x * 64;
    const int wave = tid >> 6, lane = tid & 63;
    const int quad = lane >> 4, l16 = lane & 15;
    const int m_base = (wave & 1) * 32;
    const int n_base = (wave >> 1) * 96;
    const int kch = (quad ^ ((l16 >> 1) & 3)) * 8;
    f32x4 acc[2][6] = {};

    int aldo; size_t agoff;
    {
        int slot = tid;
        int row  = slot >> 2;
        int g    = (slot & 3) ^ ((slot >> 3) & 3);
        aldo  = slot * 8;
        agoff = (size_t)(row0 + row) * HD + g * 8;
    }
    int    bldo[3];
    size_t bgoff[3];
    #pragma unroll
    for (int i = 0; i < 3; ++i) {
        int slot = i * 256 + tid;
        int row  = slot >> 2;              // 0..191
        int g    = (slot & 3) ^ ((slot >> 3) & 3);
        bldo[i]  = slot * 8;
        bgoff[i] = (size_t)row * HD + g * 8;
    }
    auto stage = [&](int b, int k0) {
        GLOAD16(&xpB[agoff + k0], &As[b][aldo]);
        #pragma unroll
        for (int i = 0; i < 3; ++i)
            GLOAD16(&Wt[bgoff[i] + k0], &Bs[b][bldo[i]]);
    };

    stage(0, 0);
    __syncthreads();
    #pragma unroll 1
    for (int t = 0; t < 16; ++t) {
        const int cur = t & 1;
        if (t < 15) stage(cur ^ 1, (t + 1) * 32);
        bf16x8 af[2], bfr[6];
        #pragma unroll
        for (int i = 0; i < 2; ++i)
            af[i] = *(const bf16x8*)&As[cur][(m_base + i * 16 + l16) * 32 + kch];
        #pragma unroll
        for (int i = 0; i < 6; ++i)
            bfr[i] = *(const bf16x8*)&Bs[cur][(n_base + i * 16 + l16) * 32 + kch];
        #pragma unroll
        for (int mi = 0; mi < 2; ++mi)
            #pragma unroll
            for (int ni = 0; ni < 6; ++ni)
                acc[mi][ni] = __builtin_amdgcn_mfma_f32_16x16x32_bf16(af[mi], bfr[ni], acc[mi][ni], 0, 0, 0);
        __syncthreads();
    }
    #pragma unroll
    for (int mi = 0; mi < 2; ++mi) {
        #pragma unroll
        for (int r = 0; r < 4; ++r) {
            int gr = row0 + m_base + mi * 16 + quad * 4 + r;
            #pragma unroll
            for (int ni = 0; ni < 6; ++ni) {
                int n = n_base + ni * 16 + l16;      // 0..191
                int which = n >> 6;
                int nn = n & 63;
                int hh = nn >> 3, d = nn & 7;
                float* dst = (which == 0) ? qh : (which == 1) ? kh : vh;
                float scl  = (which == 0) ? 0.35355339059327373f : 1.f;
                dst[((size_t)hh * NP + gr) * DH + d] = acc[mi][ni][r] * scl;
            }
        }
    }
}

__global__ void cls_init(const float* __restrict__ cls, float* __restrict__ h)
{
    int t = blockIdx.x * 256 + threadIdx.x;
    if (t < HD) h[t] = cls[t];
}

__global__ void copy512(const float* __restrict__ src, float* __restrict__ dst)
{
    dst[threadIdx.x] = src[threadIdx.x];
}

// ------------------------------------------------------------------
// layernorm rows of h into xp (bf16): wave-per-row, shfl reduce.
// grid NP/4, 256 threads (4 waves = 4 rows)
// ------------------------------------------------------------------
__global__ __launch_bounds__(256) void ln_pad(const float* __restrict__ h,
                                              const float* __restrict__ g,
                                              const float* __restrict__ b,
                                              short* __restrict__ xp)
{
    const int wave = threadIdx.x >> 6, lane = threadIdx.x & 63;
    const int row = blockIdx.x * 4 + wave;
    short* dst = xp + (size_t)row * HD + lane * 8;
    if (row < PADR) {
        bf16x8 z = {};
        *(bf16x8*)dst = z;
        return;
    }
    const float* src = h + (size_t)(row - PADR) * HD + lane * 8;
    float4 v0 = *(const float4*)src;
    float4 v1 = *(const float4*)(src + 4);
    float v[8] = {v0.x, v0.y, v0.z, v0.w, v1.x, v1.y, v1.z, v1.w};
    float s = 0.f;
    #pragma unroll
    for (int i = 0; i < 8; ++i) s += v[i];
    #pragma unroll
    for (int o = 1; o < 64; o <<= 1) s += __shfl_xor(s, o);
    float mu = s * (1.f / HD);
    float ss = 0.f;
    #pragma unroll
    for (int i = 0; i < 8; ++i) { float d = v[i] - mu; ss += d * d; }
    #pragma unroll
    for (int o = 1; o < 64; o <<= 1) ss += __shfl_xor(ss, o);
    float inv = rsqrtf(ss * (1.f / HD) + 1e-5f);
    float4 g0 = *(const float4*)&g[lane * 8];
    float4 g1 = *(const float4*)&g[lane * 8 + 4];
    float4 b0 = *(const float4*)&b[lane * 8];
    float4 b1 = *(const float4*)&b[lane * 8 + 4];
    float gg[8] = {g0.x, g0.y, g0.z, g0.w, g1.x, g1.y, g1.z, g1.w};
    float bb[8] = {b0.x, b0.y, b0.z, b0.w, b1.x, b1.y, b1.z, b1.w};
    bf16x8 o;
    #pragma unroll
    for (int i = 0; i < 8; ++i) o[i] = f2bf((v[i] - mu) * inv * gg[i] + bb[i]);
    *(bf16x8*)dst = o;
}

// ------------------------------------------------------------------
// landmark means
// ------------------------------------------------------------------
__global__ void landmarks(const float* __restrict__ qh, const float* __restrict__ kh,
                          float* __restrict__ ql, float* __restrict__ kl)
{
    int idx = blockIdx.x * 256 + threadIdx.x;
    int sel = idx >> 14;
    int rem = idx & 16383;
    int h = rem >> 11;
    int i = (rem >> 3) & 255;
    int d = rem & 7;
    const float* src = sel ? kh : qh;
    size_t base = ((size_t)h * NP + (size_t)i * 77) * DH + d;
    float s = 0.f;
    for (int j = 0; j < 77; ++j) s += src[base + (size_t)j * DH];
    (sel ? kl : ql)[((size_t)h * NL + i) * DH + d] = s * (1.f / 77.f);
}

// ------------------------------------------------------------------
// attn2 = softmax(q_l @ k_l^T); scores are O(1) -> no max subtraction
// ------------------------------------------------------------------
__global__ void attn2_softmax(const float* __restrict__ ql, const float* __restrict__ kl,
                              float* __restrict__ a)
{
    const int i = blockIdx.x, h = blockIdx.y, j = threadIdx.x;
    __shared__ float sq[8];
    __shared__ float red[256];
    if (j < 8) sq[j] = ql[((size_t)h * NL + i) * DH + j];
    __syncthreads();
    const float* kr = kl + ((size_t)h * NL + j) * DH;
    float s = 0.f;
    #pragma unroll
    for (int d = 0; d < 8; ++d) s += sq[d] * kr[d];
    float e = __expf(s);
    red[j] = e;
    __syncthreads();
    for (int off = 128; off > 0; off >>= 1) {
        if (j < off) red[j] += red[j + off];
        __syncthreads();
    }
    a[((size_t)h * NL + i) * NL + j] = e / red[0];
}

// ------------------------------------------------------------------
// pinv init: col abs-sum max per head. Rows of softmax sum to 1
// exactly (positive, normalized) -> s1 == 1, only col sums needed.
// grid 8 (heads), thread = col.
// ------------------------------------------------------------------
__global__ void pinv_norms(const float* __restrict__ a, float* __restrict__ part)
{
    const int h = blockIdx.x;
    const int tid = threadIdx.x;
    const float* ah = a + (size_t)h * NL * NL;
    float s = 0.f;
    for (int i = 0; i < NL; ++i) s += ah[(size_t)i * NL + tid];
    __shared__ float red[256];
    red[tid] = s;
    __syncthreads();
    for (int off = 128; off > 0; off >>= 1) {
        if (tid < off) red[tid] = fmaxf(red[tid], red[tid + off]);
        __syncthreads();
    }
    if (tid == 0) part[h] = red[0];
}

// ------------------------------------------------------------------
// mm256T: D = inv * A @ A^T (w0 = a2 @ z0, z0 = inv*a2^T never
// materialized). grid (8,4,8). inv = 1/max_h(part[h]).
// ------------------------------------------------------------------
__global__ void mm256T(const float* __restrict__ A, const float* __restrict__ part,
                       float* __restrict__ D)
{
    const int h = blockIdx.z;
    const float* Ah = A + (size_t)h * NL * NL;
    float* Dh = D + (size_t)h * NL * NL;
    float mx = part[0];
    #pragma unroll
    for (int i = 1; i < 8; ++i) mx = fmaxf(mx, part[i]);
    const float inv = 1.f / mx;
    __shared__ __align__(16) float As[16][36];
    __shared__ __align__(16) float Bs[16][68];
    const int tid = threadIdx.x;
    const int tx = tid & 15, ty = tid >> 4;
    const int row0 = blockIdx.x * 32;
    const int col0 = blockIdx.y * 64;
    float acc[2][4] = {};
    const int ar = tid >> 3;
    const int ak = (tid & 7) * 2;
    const int jr = tid >> 2;           // 0..63  (B rows = A rows col0+jr)
    const int kc = (tid & 3) * 4;
    for (int k0 = 0; k0 < NL; k0 += 16) {
        float2 av = *(const float2*)&Ah[(size_t)(row0 + ar) * NL + k0 + ak];
        As[ak][ar] = av.x; As[ak + 1][ar] = av.y;
        float4 bv = *(const float4*)&Ah[(size_t)(col0 + jr) * NL + k0 + kc];
        Bs[kc][jr] = bv.x; Bs[kc + 1][jr] = bv.y;
        Bs[kc + 2][jr] = bv.z; Bs[kc + 3][jr] = bv.w;
        __syncthreads();
        #pragma unroll
        for (int k = 0; k < 16; ++k) {
            float2 a = *(const float2*)&As[k][ty * 2];
            float4 b = *(const float4*)&Bs[k][tx * 4];
            acc[0][0] += a.x * b.x; acc[0][1] += a.x * b.y; acc[0][2] += a.x * b.z; acc[0][3] += a.x * b.w;
            acc[1][0] += a.y * b.x; acc[1][1] += a.y * b.y; acc[1][2] += a.y * b.z; acc[1][3] += a.y * b.w;
        }
        __syncthreads();
    }
    #pragma unroll
    for (int r = 0; r < 2; ++r) {
        int gr = row0 + ty * 2 + r;
        #pragma unroll
        for (int c = 0; c < 4; ++c)
            Dh[(size_t)gr * NL + col0 + tx * 4 + c] = inv * acc[r][c];
    }
}

// ------------------------------------------------------------------
// batched 256x256x256: D = A@B   grid (8,4,8)
// ------------------------------------------------------------------
__global__ void mm256(const float* __restrict__ A, const float* __restrict__ B,
                      float* __restrict__ D)
{
    const int h = blockIdx.z;
    const float* Ah = A + (size_t)h * NL * NL;
    const float* Bh = B + (size_t)h * NL * NL;
    float* Dh = D + (size_t)h * NL * NL;
    __shared__ __align__(16) float As[16][36];
    __shared__ __align__(16) float Bs[16][68];
    const int tid = threadIdx.x;
    const int tx = tid & 15, ty = tid >> 4;
    const int row0 = blockIdx.x * 32;
    const int col0 = blockIdx.y * 64;
    float acc[2][4] = {};
    const int ar = tid >> 3;
    const int ak = (tid & 7) * 2;
    const int bk = tid >> 4;
    const int bj = (tid & 15) * 4;
    for (int k0 = 0; k0 < NL; k0 += 16) {
        float2 av = *(const float2*)&Ah[(size_t)(row0 + ar) * NL + k0 + ak];
        As[ak][ar] = av.x; As[ak + 1][ar] = av.y;
        *(float4*)&Bs[bk][bj] = *(const float4*)&Bh[(size_t)(k0 + bk) * NL + col0 + bj];
        __syncthreads();
        #pragma unroll
        for (int k = 0; k < 16; ++k) {
            float2 a = *(const float2*)&As[k][ty * 2];
            float4 b = *(const float4*)&Bs[k][tx * 4];
            acc[0][0] += a.x * b.x; acc[0][1] += a.x * b.y; acc[0][2] += a.x * b.z; acc[0][3] += a.x * b.w;
            acc[1][0] += a.y * b.x; acc[1][1] += a.y * b.y; acc[1][2] += a.y * b.z; acc[1][3] += a.y * b.w;
        }
        __syncthreads();
    }
    #pragma unroll
    for (int r = 0; r < 2; ++r) {
        int gr = row0 + ty * 2 + r;
        #pragma unroll
        for (int c = 0; c < 4; ++c)
            Dh[(size_t)gr * NL + col0 + tx * 4 + c] = acc[r][c];
    }
}

// ------------------------------------------------------------------
// mmF: Paterson-Stockmeyer step + fused y-update (role-split).
// GEMM blocks (blockIdx.y<4):  wn = 0.25*(13w - 15S) + 0.25*S@(7w - S)
// y blocks (blockIdx.y==4):    y' = 13y - 15t + S@(7y - t), t = w@y
// grid (8, 5, 8)
// ------------------------------------------------------------------
__global__ __launch_bounds__(256) void mmF(const float* __restrict__ S,
                                           const float* __restrict__ w,
                                           float* __restrict__ wn,
                                           const float* __restrict__ yin,
                                           float* __restrict__ yout)
{
    const int h = blockIdx.z;
    const int tid = threadIdx.x;
    if (blockIdx.y == 4) {
        __shared__ float yL[NL * 9];
        __shared__ float tL[NL * 9];
        __shared__ float uL[NL * 9];
        const int s = blockIdx.x;
        const float* yh = yin + (size_t)h * NL * DH;
        #pragma unroll
        for (int i = 0; i < 8; ++i) {
            int idx = tid + 256 * i;
            yL[(idx >> 3) * 9 + (idx & 7)] = yh[idx];
        }
        __syncthreads();
        const float* wr = w + ((size_t)h * NL + tid) * NL;
        float t1[8] = {};
        for (int j = 0; j < NL; j += 4) {
            float4 wv = *(const float4*)&wr[j];
            #pragma unroll
            for (int d = 0; d < 8; ++d)
                t1[d] += wv.x * yL[j * 9 + d] + wv.y * yL[(j + 1) * 9 + d]
                       + wv.z * yL[(j + 2) * 9 + d] + wv.w * yL[(j + 3) * 9 + d];
        }
        #pragma unroll
        for (int d = 0; d < 8; ++d) {
            tL[tid * 9 + d] = t1[d];
            uL[tid * 9 + d] = 7.f * yL[tid * 9 + d] - t1[d];
        }
        __syncthreads();
        const int r = s * 32 + (tid >> 3), d = tid & 7;
        const float* Sr = S + ((size_t)h * NL + r) * NL;
        float acc = 13.f * yL[r * 9 + d] - 15.f * tL[r * 9 + d];
        for (int j = 0; j < NL; j += 4) {
            float4 sv = *(const float4*)&Sr[j];
            acc += sv.x * uL[j * 9 + d] + sv.y * uL[(j + 1) * 9 + d]
                 + sv.z * uL[(j + 2) * 9 + d] + sv.w * uL[(j + 3) * 9 + d];
        }
        yout[((size_t)h * NL + r) * DH + d] = acc;
        return;
    }
    const float* Sh = S + (size_t)h * NL * NL;
    const float* wh = w + (size_t)h * NL * NL;
    float* Dh = wn + (size_t)h * NL * NL;
    __shared__ __align__(16) float As[16][36];
    __shared__ __align__(16) float Bs[16][68];
    const int tx = tid & 15, ty = tid >> 4;
    const int row0 = blockIdx.x * 32;
    const int col0 = blockIdx.y * 64;
    float acc[2][4] = {};
    const int ar = tid >> 3;
    const int ak = (tid & 7) * 2;
    const int bk = tid >> 4;
    const int bj = (tid & 15) * 4;
    for (int k0 = 0; k0 < NL; k0 += 16) {
        float2 av = *(const float2*)&Sh[(size_t)(row0 + ar) * NL + k0 + ak];
        As[ak][ar] = av.x; As[ak + 1][ar] = av.y;
        size_t bo = (size_t)(k0 + bk) * NL + col0 + bj;
        float4 bw = *(const float4*)&wh[bo];
        float4 bs = *(const float4*)&Sh[bo];
        Bs[bk][bj]     = 7.f * bw.x - bs.x;
        Bs[bk][bj + 1] = 7.f * bw.y - bs.y;
        Bs[bk][bj + 2] = 7.f * bw.z - bs.z;
        Bs[bk][bj + 3] = 7.f * bw.w - bs.w;
        __syncthreads();
        #pragma unroll
        for (int k = 0; k < 16; ++k) {
            float2 a = *(const float2*)&As[k][ty * 2];
            float4 b = *(const float4*)&Bs[k][tx * 4];
            acc[0][0] += a.x * b.x; acc[0][1] += a.x * b.y; acc[0][2] += a.x * b.z; acc[0][3] += a.x * b.w;
            acc[1][0] += a.y * b.x; acc[1][1] += a.y * b.y; acc[1][2] += a.y * b.z; acc[1][3] += a.y * b.w;
        }
        __syncthreads();
    }
    #pragma unroll
    for (int r = 0; r < 2; ++r) {
        int gr = row0 + ty * 2 + r;
        #pragma unroll
        for (int c = 0; c < 4; ++c) {
            int gc = col0 + tx * 4 + c;
            size_t o = (size_t)gr * NL + gc;
            Dh[o] = 0.25f * (13.f * wh[o] - 15.f * Sh[o] + acc[r][c]);
        }
    }
}

// ------------------------------------------------------------------
// y' = P(w)y = 13y - 15*t1 + S@(7y - t1), t1 = w@y.  (last iteration)
// grid (8 slices, 8 heads)
// ------------------------------------------------------------------
__global__ __launch_bounds__(256) void yiter(const float* __restrict__ w,
                                             const float* __restrict__ S,
                                             const float* __restrict__ yin,
                                             float* __restrict__ yout)
{
    const int s = blockIdx.x, h = blockIdx.y, tid = threadIdx.x;
    __shared__ float yL[NL * 9];
    __shared__ float tL[NL * 9];
    __shared__ float uL[NL * 9];
    const float* yh = yin + (size_t)h * NL * DH;
    #pragma unroll
    for (int i = 0; i < 8; ++i) {
        int idx = tid + 256 * i;
        yL[(idx >> 3) * 9 + (idx & 7)] = yh[idx];
    }
    __syncthreads();
    const float* wr = w + ((size_t)h * NL + tid) * NL;
    float t1[8] = {};
    for (int j = 0; j < NL; j += 4) {
        float4 wv = *(const float4*)&wr[j];
        #pragma unroll
        for (int d = 0; d < 8; ++d)
            t1[d] += wv.x * yL[j * 9 + d] + wv.y * yL[(j + 1) * 9 + d]
                   + wv.z * yL[(j + 2) * 9 + d] + wv.w * yL[(j + 3) * 9 + d];
    }
    #pragma unroll
    for (int d = 0; d < 8; ++d) {
        tL[tid * 9 + d] = t1[d];
        uL[tid * 9 + d] = 7.f * yL[tid * 9 + d] - t1[d];
    }
    __syncthreads();
    const int r = s * 32 + (tid >> 3), d = tid & 7;
    const float* Sr = S + ((size_t)h * NL + r) * NL;
    float acc = 13.f * yL[r * 9 + d] - 15.f * tL[r * 9 + d];
    for (int j = 0; j < NL; j += 4) {
        float4 sv = *(const float4*)&Sr[j];
        acc += sv.x * uL[j * 9 + d] + sv.y * uL[(j + 1) * 9 + d]
             + sv.z * uL[(j + 2) * 9 + d] + sv.w * uL[(j + 3) * 9 + d];
    }
    yout[((size_t)h * NL + r) * DH + d] = acc;
}

// ------------------------------------------------------------------
// polyvT: zw = (4^-6 * inv) * a2^T @ y6  (z0 never materialized)
// grid (8 rowchunks, 8 heads)
// ------------------------------------------------------------------
__global__ void polyvT(const float* __restrict__ A, const float* __restrict__ part,
                       const float* __restrict__ vin, float* __restrict__ vout)
{
    const int h = blockIdx.y;
    __shared__ float vs[NL * DH];
    const int tid = threadIdx.x;
    const float* vh = vin + (size_t)h * NL * DH;
    #pragma unroll
    for (int i = 0; i < 8; ++i) vs[tid + 256 * i] = vh[tid + 256 * i];
    __syncthreads();
    float mx = part[0];
    #pragma unroll
    for (int i = 1; i < 8; ++i) mx = fmaxf(mx, part[i]);
    const float scale = 2.44140625e-4f / mx;
    const int row = blockIdx.x * 32 + (tid >> 3);
    const int d = tid & 7;
    const float* Ah = A + (size_t)h * NL * NL;
    float acc = 0.f;
    for (int j = 0; j < NL; ++j)
        acc += Ah[(size_t)j * NL + row] * vs[j * 8 + d];
    vout[((size_t)h * NL + row) * DH + d] = acc * scale;
}

// ------------------------------------------------------------------
// attn3 @ v, single K/V pass: grid (77 chunks, 8 heads).
// ------------------------------------------------------------------
__global__ __launch_bounds__(256) void attn3v(const float* __restrict__ kh,
                                              const float* __restrict__ vh,
                                              const float* __restrict__ ql,
                                              float* __restrict__ part)
{
    const int ck = blockIdx.x, h = blockIdx.y, tid = threadIdx.x;
    __shared__ __align__(16) float4 kv[A3CHK][4];   // [t]: k0 k1 v0 v1
    const float* kb = kh + ((size_t)h * NP + (size_t)ck * A3CHK) * DH;
    const float* vb = vh + ((size_t)h * NP + (size_t)ck * A3CHK) * DH;
    #pragma unroll
    for (int i = 0; i < 2; ++i) {
        int idx = tid + 256 * i;          // 0..511
        int t = idx >> 1, p = idx & 1;
        kv[t][p]     = *(const float4*)&kb[t * 8 + p * 4];
        kv[t][2 + p] = *(const float4*)&vb[t * 8 + p * 4];
    }
    float q[8];
    const float* qp = ql + ((size_t)h * NL + tid) * DH;
    #pragma unroll
    for (int d = 0; d < 8; ++d) q[d] = qp[d];
    __syncthreads();
    float den = 0.f;
    float4 a0 = make_float4(0.f, 0.f, 0.f, 0.f);
    float4 a1 = make_float4(0.f, 0.f, 0.f, 0.f);
    #pragma unroll 4
    for (int t = 0; t < A3CHK; ++t) {
        float4 k0 = kv[t][0], k1 = kv[t][1];
        float s = q[0] * k0.x + q[1] * k0.y + q[2] * k0.z + q[3] * k0.w
                + q[4] * k1.x + q[5] * k1.y + q[6] * k1.z + q[7] * k1.w;
        float e = __expf(s);
        den += e;
        float4 v0 = kv[t][2], v1 = kv[t][3];
        F4MAD(a0, e, v0); F4MAD(a1, e, v1);
    }
    float* p = part + (((size_t)h * A3NB + ck) * NL + tid) * 9;
    p[0] = den;
    p[1] = a0.x; p[2] = a0.y; p[3] = a0.z; p[4] = a0.w;
    p[5] = a1.x; p[6] = a1.y; p[7] = a1.z; p[8] = a1.w;
}

// merge 77 chunks -> y0[h][i][d]; grid (8 heads, 8 i-slices), thread=(i,d)
__global__ void attn3v_merge(const float* __restrict__ part, float* __restrict__ y)
{
    const int h = blockIdx.x;
    const int i = blockIdx.y * 32 + (threadIdx.x >> 3);
    const int d = threadIdx.x & 7;
    float acc = 0.f, den = 0.f;
    const float* p = part + ((size_t)h * A3NB * NL + i) * 9;
    for (int ck = 0; ck < A3NB; ++ck) {
        const float* q = p + (size_t)ck * NL * 9;
        den += q[0];
        acc += q[1 + d];
    }
    y[((size_t)h * NL + i) * DH + d] = acc / den;
}

// ------------------------------------------------------------------
// attn1 fused + dwconv33(v): 1 lane = 1 token; kl/zw broadcast from LDS
// (wave-uniform addr -> conflict-free). grid (77, 8), 256 threads.
// ------------------------------------------------------------------
__global__ __launch_bounds__(256) void attn1_conv(const float* __restrict__ qh,
                                                  const float* __restrict__ vh,
                                                  const float* __restrict__ klg,
                                                  const float* __restrict__ zwg,
                                                  const float* __restrict__ rw,
                                                  float* __restrict__ aout)
{
    const int h = blockIdx.y;
    __shared__ __align__(16) float kl[NL * DH];
    __shared__ __align__(16) float zw[NL * DH];
    const int tid = threadIdx.x;
    #pragma unroll
    for (int q = 0; q < 8; ++q) {
        kl[tid + 256 * q] = klg[(size_t)h * NL * DH + tid + 256 * q];
        zw[tid + 256 * q] = zwg[(size_t)h * NL * DH + tid + 256 * q];
    }
    __syncthreads();
    const int r = blockIdx.x * 256 + tid;
    if (r >= NT) return;
    const int t = r + PADR;
    const float* qp = qh + ((size_t)h * NP + t) * DH;
    float4 q0 = *(const float4*)qp;
    float4 q1 = *(const float4*)(qp + 4);
    float den = 0.f;
    float4 acc0 = make_float4(0.f, 0.f, 0.f, 0.f);
    float4 acc1 = make_float4(0.f, 0.f, 0.f, 0.f);
    #pragma unroll 4
    for (int i = 0; i < NL; ++i) {
        float4 k0 = *(const float4*)&kl[i * 8];
        float4 k1 = *(const float4*)&kl[i * 8 + 4];
        float s = q0.x * k0.x + q0.y * k0.y + q0.z * k0.z + q0.w * k0.w
                + q1.x * k1.x + q1.y * k1.y + q1.z * k1.z + q1.w * k1.w;
        float e = __expf(s);
        den += e;
        float4 z0 = *(const float4*)&zw[i * 8];
        float4 z1 = *(const float4*)&zw[i * 8 + 4];
        F4MAD(acc0, e, z0); F4MAD(acc1, e, z1);
    }
    float inv = 1.f / den;
    const float* vb = vh + (size_t)h * NP * DH;
    float4 c0 = make_float4(0.f, 0.f, 0.f, 0.f);
    float4 c1 = make_float4(0.f, 0.f, 0.f, 0.f);
    #pragma unroll
    for (int j = 0; j < 33; ++j) {
        int tp = t - 16 + j;
        if (tp >= NP) continue;
        float wv = rw[h * 33 + j];
        float4 v0 = *(const float4*)&vb[(size_t)tp * 8];
        float4 v1 = *(const float4*)&vb[(size_t)tp * 8 + 4];
        F4MAD(c0, wv, v0); F4MAD(c1, wv, v1);
    }
    float* op = aout + (size_t)r * 64 + h * 8;
    *(float4*)op = make_float4(acc0.x * inv + c0.x, acc0.y * inv + c0.y,
                               acc0.z * inv + c0.z, acc0.w * inv + c0.w);
    *(float4*)(op + 4) = make_float4(acc1.x * inv + c1.x, acc1.y * inv + c1.y,
                                     acc1.z * inv + c1.z, acc1.w * inv + c1.w);
}

// ------------------------------------------------------------------
// out-proj + residual: 16 rows/block
// ------------------------------------------------------------------
__global__ void outproj(const float* __restrict__ aout, const float* __restrict__ W,
                        const float* __restrict__ bias, float* __restrict__ h)
{
    const int r0 = blockIdx.x * 16;
    const int tid = threadIdx.x;   // 512
    __shared__ float ao[16][64];
    #pragma unroll
    for (int s = 0; s < 2; ++s) {
        int idx = tid + s * 512;
        int rr = idx >> 6, kk = idx & 63;
        int gr = r0 + rr;
        ao[rr][kk] = (gr < NT) ? aout[(size_t)gr * 64 + kk] : 0.f;
    }
    __syncthreads();
    float acc[16] = {};
    for (int k = 0; k < 64; ++k) {
        float wv = W[(size_t)k * HD + tid];
        #pragma unroll
        for (int r = 0; r < 16; ++r) acc[r] += ao[r][k] * wv;
    }
    float bv = bias[tid];
    #pragma unroll
    for (int r = 0; r < 16; ++r) {
        int gr = r0 + r;
        if (gr < NT) h[(size_t)gr * HD + tid] += acc[r] + bv;
    }
}

// ------------------------------------------------------------------
// PPEG weight prep (identity tap folded at center)
// ------------------------------------------------------------------
__global__ void ppeg_wprep(const float* __restrict__ w7, const float* __restrict__ b7,
                           const float* __restrict__ w5, const float* __restrict__ b5,
                           const float* __restrict__ w3, const float* __restrict__ b3,
                           float* __restrict__ wc, float* __restrict__ bsum)
{
    int idx = blockIdx.x * 256 + threadIdx.x;
    if (idx < HD * 49) {
        int c = idx / 49, t = idx - c * 49;
        int dy = t / 7 - 3, dx = t % 7 - 3;
        float v = w7[idx];
        if (dy >= -2 && dy <= 2 && dx >= -2 && dx <= 2) v += w5[c * 25 + (dy + 2) * 5 + (dx + 2)];
        if (dy >= -1 && dy <= 1 && dx >= -1 && dx <= 1) v += w3[c * 9 + (dy + 1) * 3 + (dx + 1)];
        if (t == 24) v += 1.f;
        wc[idx] = v;
    } else if (idx < HD * 49 + HD) {
        int c = idx - HD * 49;
        bsum[c] = b7[c] + b5[c] + b3[c];
    }
}

// ------------------------------------------------------------------
// ppeg_direct: fused dwconv 7x7 in token-major layout.
// grid (9, 9, 32), 256 threads.
// ------------------------------------------------------------------
__global__ __launch_bounds__(256) void ppeg_direct(const float* __restrict__ hin,
                                                   const float* __restrict__ wc,
                                                   const float* __restrict__ bsum,
                                                   float* __restrict__ hout)
{
    __shared__ __align__(16) float in_sh[PHH * PHW * PSLOT];   // 38.7 KB
    __shared__ float wL[49 * PCC];                             // [tap][c]
    const int tid = threadIdx.x;
    const int tx0 = blockIdx.x * PTW;
    const int ty0 = blockIdx.y * PTH;
    const int c0  = blockIdx.z * PCC;
    for (int i = tid; i < 49 * PCC; i += 256) {
        int c = i / 49, tap = i - c * 49;
        wL[tap * PCC + c] = wc[(size_t)(c0 + c) * 49 + tap];
    }
    for (int idx = tid; idx < PHH * PHW * 4; idx += 256) {
        int pos = idx >> 2, q = idx & 3;
        int ly = pos / PHW, lx = pos - ly * PHW;
        int gy = ty0 - 3 + ly, gx = tx0 - 3 + lx;
        float4 v = make_float4(0.f, 0.f, 0.f, 0.f);
        if (gy >= 0 && gy < SIDE && gx >= 0 && gx < SIDE)
            v = *(const float4*)&hin[(size_t)(1 + gy * SIDE + gx) * HD + c0 + q * 4];
        *(float4*)&in_sh[pos * PSLOT + q * 4] = v;
    }
    __syncthreads();
    const int y  = tid >> 4;         // 0..15
    const int x4 = (tid >> 2) & 3;   // 0..3
    const int c4 = tid & 3;          // 0..3
    const int xb = x4 * 4;
    float4 acc[4] = {make_float4(0.f,0.f,0.f,0.f), make_float4(0.f,0.f,0.f,0.f),
                     make_float4(0.f,0.f,0.f,0.f), make_float4(0.f,0.f,0.f,0.f)};
    #pragma unroll 1
    for (int dy = 0; dy < 7; ++dy) {
        float4 row[10];
        #pragma unroll
        for (int k = 0; k < 10; ++k)
            row[k] = *(const float4*)&in_sh[((y + dy) * PHW + xb + k) * PSLOT + c4 * 4];
        #pragma unroll
        for (int dx = 0; dx < 7; ++dx) {
            float4 wv = *(const float4*)&wL[(dy * 7 + dx) * PCC + c4 * 4];
            #pragma unroll
            for (int xi = 0; xi < 4; ++xi) F4FMA(acc[xi], wv, row[xi + dx]);
        }
    }
    const int gy = ty0 + y;
    if (gy >= SIDE) return;
    float4 bv = *(const float4*)&bsum[c0 + c4 * 4];
    #pragma unroll
    for (int xi = 0; xi < 4; ++xi) {
        int gx = tx0 + xb + xi;
        if (gx >= SIDE) continue;
        float4 o = make_float4(acc[xi].x + bv.x, acc[xi].y + bv.y,
                               acc[xi].z + bv.z, acc[xi].w + bv.w);
        *(float4*)&hout[(size_t)(1 + gy * SIDE + gx) * HD + c0 + c4 * 4] = o;
    }
}

// ------------------------------------------------------------------
// final layernorm of row 0
// ------------------------------------------------------------------
__global__ void final_ln(const float* __restrict__ h, const float* __restrict__ g,
                         const float* __restrict__ b, float* __restrict__ out)
{
    const int tid = threadIdx.x;
    float v0 = h[tid], v1 = h[tid + 256];
    __shared__ float red[256];
    red[tid] = v0 + v1;
    __syncthreads();
    for (int off = 128; off > 0; off >>= 1) {
        if (tid < off) red[tid] += red[tid + off];
        __syncthreads();
    }
    float mu = red[0] * (1.f / HD);
    __syncthreads();
    float d0 = v0 - mu, d1 = v1 - mu;
    red[tid] = d0 * d0 + d1 * d1;
    __syncthreads();
    for (int off = 128; off > 0; off >>= 1) {
        if (tid < off) red[tid] += red[tid + off];
        __syncthreads();
    }
    float inv = rsqrtf(red[0] * (1.f / HD) + 1e-5f);
    out[tid]       = d0 * inv * g[tid] + b[tid];
    out[tid + 256] = d1 * inv * g[tid + 256] + b[tid + 256];
}

} // namespace

extern "C" void kernel_launch(void* const* d_in, const int* in_sizes, int n_in,
                              void* d_out, int out_size, void* d_ws, size_t ws_size,
                              hipStream_t stream)
{
    const float* x      = (const float*)d_in[0];
    const float* fc1_w  = (const float*)d_in[1];
    const float* fc1_b  = (const float*)d_in[2];
    const float* cls    = (const float*)d_in[3];
    const float* l1_g   = (const float*)d_in[4];
    const float* l1_bb  = (const float*)d_in[5];
    const float* l1_qkv = (const float*)d_in[6];
    const float* l1_ow  = (const float*)d_in[7];
    const float* l1_ob  = (const float*)d_in[8];
    const float* l1_rw  = (const float*)d_in[9];
    const float* l2_g   = (const float*)d_in[10];
    const float* l2_bb  = (const float*)d_in[11];
    const float* l2_qkv = (const float*)d_in[12];
    const float* l2_ow  = (const float*)d_in[13];
    const float* l2_ob  = (const float*)d_in[14];
    const float* l2_rw  = (const float*)d_in[15];
    const float* p7w    = (const float*)d_in[16];
    const float* p7b    = (const float*)d_in[17];
    const float* p5w    = (const float*)d_in[18];
    const float* p5b    = (const float*)d_in[19];
    const float* p3w    = (const float*)d_in[20];
    const float* p3b    = (const float*)d_in[21];
    const float* ng     = (const float*)d_in[22];
    const float* nb     = (const float*)d_in[23];
    float* out = (float*)d_out;

    char* ws = (char*)d_ws;
    size_t off = 0;
    auto alloc = [&](size_t bytes) {
        char* p = ws + off;
        off += (bytes + 255) & ~(size_t)255;
        return (void*)p;
    };
    float* bufA = (float*)alloc((size_t)NP * HD * 4);
    float* bufB = (float*)alloc((size_t)NP * HD * 4);
    float* qh   = (float*)alloc((size_t)NH * NP * DH * 4);
    float* kh   = (float*)alloc((size_t)NH * NP * DH * 4);
    float* vh   = (float*)alloc((size_t)NH * NP * DH * 4);
    float* aout = (float*)alloc((size_t)NP * 64 * 4);
    float* ql   = (float*)alloc((size_t)NH * NL * DH * 4);
    float* klm  = (float*)alloc((size_t)NH * NL * DH * 4);
    float* ybuf = (float*)alloc((size_t)NH * NL * DH * 4);
    float* ybuf2= (float*)alloc((size_t)NH * NL * DH * 4);
    float* zwb  = (float*)alloc((size_t)NH * NL * DH * 4);
    float* a2   = (float*)alloc((size_t)NH * NL * NL * 4);
    float* azb  = (float*)alloc((size_t)NH * NL * NL * 4);   // w ping
    float* tb   = (float*)alloc((size_t)NH * NL * NL * 4);   // w pong
    float* ub   = (float*)alloc((size_t)NH * NL * NL * 4);   // S = w@w
    float* part = (float*)alloc(256);
    float* a3p  = (float*)alloc((size_t)NH * A3NB * NL * 9 * 4);
    float* wcomb = (float*)alloc((size_t)HD * 49 * 4);
    float* bsum  = (float*)alloc((size_t)HD * 4);
    short* wt1   = (short*)alloc((size_t)HD * ID * 2);
    short* wtq   = (short*)alloc((size_t)192 * HD * 2);
    short* xb    = (short*)alloc((size_t)NP * ID * 2);   // NP rows: fc1 A-tiles may read past NPIX
    short* xpB   = (short*)alloc((size_t)NP * HD * 2);
    (void)ws_size; (void)in_sizes; (void)n_in; (void)out_size;

    castX<<<(NPIX * ID / 8) / 256, 256, 0, stream>>>(x, xb);
    castT<<<dim3(HD / 32, ID / 32), 256, 0, stream>>>(fc1_w, wt1, ID, HD);
    gemm_fc1<<<dim3(4, 154), 256, 0, stream>>>(xb, wt1, fc1_b, bufA);
    cls_init<<<2, 256, 0, stream>>>(cls, bufA);

    auto attention = [&](float* hbuf, const float* lg, const float* lb,
                         const float* qkvw, const float* ow, const float* ob,
                         const float* rw) {
        ln_pad<<<NP / 4, 256, 0, stream>>>(hbuf, lg, lb, xpB);
        castT<<<dim3(192 / 32, HD / 32), 256, 0, stream>>>(qkvw, wtq, HD, 192);
        gemm_qkv<<<NP / 64, 256, 0, stream>>>(xpB, wtq, qh, kh, vh);
        landmarks<<<128, 256, 0, stream>>>(qh, kh, ql, klm);
        attn2_softmax<<<dim3(NL, NH), 256, 0, stream>>>(ql, klm, a2);
        pinv_norms<<<8, 256, 0, stream>>>(a2, part);
        // y0 = attn3 @ v (single K/V pass + parallel merge)
        attn3v<<<dim3(A3NB, NH), 256, 0, stream>>>(kh, vh, ql, a3p);
        attn3v_merge<<<dim3(NH, 8), 256, 0, stream>>>(a3p, ybuf);
        // w-space Newton-Schulz; w0 = inv * a2@a2^T (z0 never built).
        //   S = w@w;  w' = 0.25(13w - 15S) + 0.25 S@(7w - S)  [mmF, fused y role]
        mm256T<<<dim3(8, 4, 8), 256, 0, stream>>>(a2, part, azb);
        float* wc = azb;
        float* wn = tb;
        float* yc = ybuf;
        float* yn = ybuf2;
        for (int it = 0; it < 6; ++it) {
            mm256<<<dim3(8, 4, 8), 256, 0, stream>>>(wc, wc, ub);       // S
            if (it < 5) {
                mmF<<<dim3(8, 5, 8), 256, 0, stream>>>(ub, wc, wn, yc, yn);
                { float* t = yc; yc = yn; yn = t; }
                { float* t = wc; wc = wn; wn = t; }
            } else {
                yiter<<<dim3(8, 8), 256, 0, stream>>>(wc, ub, yc, yn);
                { float* t = yc; yc = yn; yn = t; }
            }
        }
        // zw = (4^-6 * inv) * a2^T @ y6
        polyvT<<<dim3(8, NH), 256, 0, stream>>>(a2, part, yc, zwb);
        attn1_conv<<<dim3(77, NH), 256, 0, stream>>>(qh, vh, klm, zwb, rw, aout);
        outproj<<<(NT + 15) / 16, 512, 0, stream>>>(aout, ow, ob, hbuf);
    };

    attention(bufA, l1_g, l1_bb, l1_qkv, l1_ow, l1_ob, l1_rw);

    ppeg_wprep<<<(HD * 49 + HD + 255) / 256, 256, 0, stream>>>(p7w, p7b, p5w, p5b, p3w, p3b,
                                                               wcomb, bsum);
    copy512<<<1, 512, 0, stream>>>(bufA, bufB);
    ppeg_direct<<<dim3((SIDE + PTW - 1) / PTW, (SIDE + PTH - 1) / PTH, HD / PCC),
                  256, 0, stream>>>(bufA, wcomb, bsum, bufB);

    attention(bufB, l2_g, l2_bb, l2_qkv, l2_ow, l2_ob, l2_rw);
    final_ln<<<1, 256, 0, stream>>>(bufB, ng, nb, out);
}